// Round 9
// baseline (806.453 us; speedup 1.0000x reference)
//
#include <hip/hip_runtime.h>
#include <math.h>

#define Nn 20000
#define Ee 120000
#define EALLe 240000
#define Cc 150
#define Rr 1000
#define EHd 300
#define RHd 100
#define CHd 150
#define CB 128   // blocks for edge-pass kernels (per-thread ranks fit in 4)
#define XSPL 16  // splits per class for x_class accumulation

static inline int cdiv_h(int a, int b){ return (a + b - 1) / b; }

typedef __attribute__((ext_vector_type(8))) short short8;
typedef __attribute__((ext_vector_type(4))) float f32x4;

__device__ __forceinline__ float lrelu01(float x){ return x > 0.f ? x : 0.01f * x; }

__device__ __forceinline__ unsigned short f2b(float f){
  unsigned int u = __float_as_uint(f);
  unsigned int r = (u + 0x7FFFu + ((u >> 16) & 1u)) >> 16;
  return (unsigned short)r;
}
__device__ __forceinline__ float b2f(unsigned short u){
  return __uint_as_float(((unsigned int)u) << 16);
}

template<int Kq>
__device__ __forceinline__ void wredsumN(float* v){
#pragma unroll
  for (int m = 32; m >= 1; m >>= 1){
#pragma unroll
    for (int k = 0; k < Kq; k++) v[k] += __shfl_xor(v[k], m, 64);
  }
}

// f32 [rows, ncols] (ld ldsrc) -> bf16 [rows, ldp], zero-padded cols ncols..ldp
__global__ __launch_bounds__(64) void k_f2b(const float* __restrict__ src, int ncols,
    int ldsrc, unsigned short* __restrict__ dst, int ldp){
  int r = blockIdx.x, t = threadIdx.x;
  for (int c = t; c < ldp; c += 64)
    dst[(size_t)r * ldp + c] = (c < ncols) ? f2b(src[(size_t)r * ldsrc + c]) : (unsigned short)0;
}

__global__ __launch_bounds__(64) void k_rnorm(const float* __restrict__ rt,
    const float* __restrict__ arh, const float* __restrict__ are,
    float* __restrict__ ra1h, float* __restrict__ ra1e){
  int r = blockIdx.x, lane = threadIdx.x;
  bool m1 = (lane + 64 < RHd);
  float v0 = rt[r * RHd + lane];
  float v1 = m1 ? rt[r * RHd + lane + 64] : 0.f;
  float s[3];
  s[0] = v0 * v0 + v1 * v1;
  s[1] = v0 * arh[RHd + lane] + (m1 ? v1 * arh[RHd + lane + 64] : 0.f);
  s[2] = v0 * are[RHd + lane] + (m1 ? v1 * are[RHd + lane + 64] : 0.f);
  wredsumN<3>(s);
  float inv = 0.5f / fmaxf(sqrtf(s[0]), 1e-12f);
  if (!lane){
    ra1h[r] = s[1] * inv;
    ra1e[r] = s[2] * inv;
  }
}

__global__ void k_count(const int* __restrict__ dst, int* __restrict__ degi){
  int e = blockIdx.x * blockDim.x + threadIdx.x;
  if (e < EALLe) atomicAdd(&degi[dst[e]], 1);
}

__global__ void k_dis(const int* __restrict__ degi, float* __restrict__ dis){
  int n = blockIdx.x * blockDim.x + threadIdx.x;
  if (n < Nn) dis[n] = degi[n] > 0 ? rsqrtf((float)degi[n]) : 0.f;
}

__global__ __launch_bounds__(1024) void k_scan(const int* __restrict__ degi,
    int* __restrict__ ptr, int* __restrict__ cur){
  __shared__ int s[1024];
  int t = threadIdx.x;
  const int per = (Nn + 1023) / 1024;
  int b0 = t * per; if (b0 > Nn) b0 = Nn;
  int b1 = b0 + per; if (b1 > Nn) b1 = Nn;
  int sum = 0;
  for (int i = b0; i < b1; i++) sum += degi[i];
  s[t] = sum;
  __syncthreads();
  for (int off = 1; off < 1024; off <<= 1){
    int v = (t >= off) ? s[t - off] : 0;
    __syncthreads();
    s[t] += v;
    __syncthreads();
  }
  int run = (t > 0) ? s[t - 1] : 0;
  for (int i = b0; i < b1; i++){
    ptr[i] = run; cur[i] = run; run += degi[i];
  }
  if (t == 1023) ptr[Nn] = s[1023];
}

__global__ void k_scatter(const int* __restrict__ src, const int* __restrict__ dst,
    int* __restrict__ cur, int* __restrict__ csr_src){
  int e = blockIdx.x * blockDim.x + threadIdx.x;
  if (e >= EALLe) return;
  int pos = atomicAdd(&cur[dst[e]], 1);
  csr_src[pos] = src[e];
}

// GCN edge weights per CSR slot: wg[k] = dis[i]*dis[src[k]] (shared by both GCN layers)
__global__ __launch_bounds__(64) void k_wgcn(const int* __restrict__ ptr,
    const int* __restrict__ srcw, const float* __restrict__ dis, float* __restrict__ wg){
  int i = blockIdx.x, lane = threadIdx.x;
  int p0 = ptr[i], p1 = ptr[i + 1];
  float di = dis[i];
  for (int k = p0 + lane; k < p1; k += 64) wg[k] = di * dis[srcw[k]];
}

// GAT normalized edge weights per CSR slot: wdiv[k] = exp(lrelu(s1[i]+s2[j])) / den_i
__global__ __launch_bounds__(64) void k_wgat(const int* __restrict__ ptr,
    const int* __restrict__ srcw, const float* __restrict__ s1,
    const float* __restrict__ s2, float* __restrict__ wdiv){
  int i = blockIdx.x, lane = threadIdx.x;
  int p0 = ptr[i], p1 = ptr[i + 1];
  float s1i = s1[i];
  float den = 0.f;
  for (int k = p0 + lane; k < p1; k += 64){
    float w = expf(lrelu01(s1i + s2[srcw[k]]));
    wdiv[k] = w;
    den += w;
  }
  float d[1] = { den };
  wredsumN<1>(d);
  float inv = d[0] > 0.f ? 1.f / d[0] : 0.f;
  for (int k = p0 + lane; k < p1; k += 64) wdiv[k] *= inv;
}

// chunked weighted SpMM from a bf16 table: per (node, chunk), 1 wave per node.
// out[i, ocol0 + f0 + 2l(+1)] = relu( sum_k wcsr[k] * tab[src[k], f0 + 2l(+1)] )
// chunk f0 = blockIdx.y * NF; chunk slab (20000 x NF bf16) is L2-resident.
template<int NF>
__global__ __launch_bounds__(256) void k_spmm(
    const unsigned short* __restrict__ tab, int ldt, int ncols,
    const int* __restrict__ ptr, const int* __restrict__ srcw,
    const float* __restrict__ wcsr,
    float* __restrict__ outp, int ldo, int ocol0){
  int wv = threadIdx.x >> 6, lane = threadIdx.x & 63;
  int i = blockIdx.x * 4 + wv;
  if (i >= Nn) return;
  int f0 = blockIdx.y * NF;
  int col = f0 + 2 * lane;
  bool act = (2 * lane < NF) && (col < ncols);
  int p0 = ptr[i], p1 = ptr[i + 1];
  float a0 = 0.f, a1 = 0.f;
  for (int k = p0; k < p1; k++){
    int j = srcw[k];
    float w = wcsr[k];
    if (act){
      unsigned int u = *(const unsigned int*)&tab[(size_t)j * ldt + col];
      a0 += w * b2f((unsigned short)(u & 0xFFFFu));
      a1 += w * b2f((unsigned short)(u >> 16));
    }
  }
  if (act){
    float* orow = outp + (size_t)i * ldo + ocol0 + col;
    orow[0] = fmaxf(a0, 0.f);
    orow[1] = fmaxf(a1, 0.f);
  }
}

// copy x1[:, :300] (f32, ld 600) into d_out[:, :300] (ld 900), float4 vectorized
__global__ __launch_bounds__(256) void k_copy300(const float* __restrict__ x1,
    float* __restrict__ dout){
  size_t idx = (size_t)blockIdx.x * 256 + threadIdx.x;
  if (idx >= (size_t)Nn * 75) return;
  int r = (int)(idx / 75), q = (int)(idx % 75);
  ((f32x4*)(dout + (size_t)r * 900))[q] = ((const f32x4*)(x1 + (size_t)r * 600))[q];
}

// bf16 MFMA GEMM: out = epi( Xb[nrows,Kp]bf16 @ Wb[M,Kp]bf16^T ).
template<int EPI, int MIR>
__global__ __launch_bounds__(256) void k_gemmb(
    const unsigned short* __restrict__ Xb, int ldxb, int nrows,
    const unsigned short* __restrict__ Wb, int Kp, int M,
    const float* __restrict__ bias,
    const float* __restrict__ X2, int ldx2,
    const float* __restrict__ Xf, int ldxf,
    float* __restrict__ out, int ldo,
    unsigned short* __restrict__ mir, int ldmir){
  __shared__ unsigned short Xs[64][40];
  __shared__ unsigned short Ws[64][40];
  int t = threadIdx.x;
  int wv = t >> 6, lane = t & 63;
  int c0 = blockIdx.x * 64, r0 = blockIdx.y * 64;
  int srow = t >> 2, skoff = (t & 3) * 8;
  int gxr = r0 + srow, gwr = c0 + srow;
  f32x4 acc[4] = {};
  for (int k0 = 0; k0 < Kp; k0 += 32){
    short8 xv = {0,0,0,0,0,0,0,0};
    short8 wv8 = {0,0,0,0,0,0,0,0};
    if (gxr < nrows) xv = *(const short8*)&Xb[(size_t)gxr * ldxb + k0 + skoff];
    if (gwr < M)     wv8 = *(const short8*)&Wb[(size_t)gwr * Kp + k0 + skoff];
    __syncthreads();
    *(short8*)&Xs[srow][skoff] = xv;
    *(short8*)&Ws[srow][skoff] = wv8;
    __syncthreads();
    int arow = wv * 16 + (lane & 15);
    int kk = (lane >> 4) * 8;
    short8 af = *(const short8*)&Xs[arow][kk];
#pragma unroll
    for (int j = 0; j < 4; j++){
      short8 bf = *(const short8*)&Ws[j * 16 + (lane & 15)][kk];
      acc[j] = __builtin_amdgcn_mfma_f32_16x16x32_bf16(af, bf, acc[j], 0, 0, 0);
    }
  }
  int rbase = r0 + wv * 16 + (lane >> 4) * 4;
  int cbase = c0 + (lane & 15);
#pragma unroll
  for (int j = 0; j < 4; j++){
    int c = cbase + j * 16;
    if (c >= M) continue;
#pragma unroll
    for (int r = 0; r < 4; r++){
      int row = rbase + r;
      if (row >= nrows) continue;
      float v = acc[j][r];
      float o;
      if (EPI == 0){
        o = fmaxf(v, 0.f);
      } else {
        float g = 1.f / (1.f + expf(-(v + bias[c])));
        o = g * X2[(size_t)row * ldx2 + c] + (1.f - g) * Xf[(size_t)row * ldxf + c];
      }
      out[(size_t)row * ldo + c] = o;
      if (MIR) mir[(size_t)row * ldmir + c] = f2b(o);
    }
  }
}

// per-node precompute for gat_e (xm/xo live in proj with ld 600); xn stored bf16 ld 152
__global__ __launch_bounds__(64) void k_ndots2(
    const float* __restrict__ xm, const float* __restrict__ xo, int ldp,
    const float* __restrict__ v2m, const float* __restrict__ v3m,
    const float* __restrict__ v2o, const float* __restrict__ v3o,
    const float* __restrict__ v4,
    unsigned short* __restrict__ xnb, float* __restrict__ pm,
    float* __restrict__ po, float* __restrict__ nv4){
  int n = blockIdx.x, lane = threadIdx.x;
  bool m2 = lane < (CHd - 128);
  const float* mr = xm + (size_t)n * ldp;
  const float* orw = xo + (size_t)n * ldp;
  float m0 = mr[lane], m1 = mr[lane + 64], mv2 = m2 ? mr[lane + 128] : 0.f;
  float o0 = orw[lane], o1 = orw[lane + 64], o2 = m2 ? orw[lane + 128] : 0.f;
  float s[4];
  s[0] = m0 * m0 + m1 * m1 + mv2 * mv2;
  s[1] = o0 * v2o[lane] + o1 * v2o[lane + 64] + (m2 ? o2 * v2o[lane + 128] : 0.f);
  s[2] = o0 * v3o[lane] + o1 * v3o[lane + 64] + (m2 ? o2 * v3o[lane + 128] : 0.f);
  s[3] = o0 * v4[lane]  + o1 * v4[lane + 64]  + (m2 ? o2 * v4[lane + 128]  : 0.f);
  wredsumN<4>(s);
  float inv = 1.f / fmaxf(sqrtf(s[0]), 1e-12f);
  float n0 = m0 * inv, n1 = m1 * inv, n2 = mv2 * inv;
  unsigned short* xr = xnb + (size_t)n * 152;
  xr[lane] = f2b(n0); xr[lane + 64] = f2b(n1);
  if (m2) xr[lane + 128] = f2b(n2);
  float d[2];
  d[0] = n0 * v2m[lane] + n1 * v2m[lane + 64] + (m2 ? n2 * v2m[lane + 128] : 0.f);
  d[1] = n0 * v3m[lane] + n1 * v3m[lane + 64] + (m2 ? n2 * v3m[lane + 128] : 0.f);
  wredsumN<2>(d);
  if (!lane){
    pm[n] = d[0] + 0.25f * d[1];
    po[n] = s[1] + 0.25f * s[2];
    nv4[n] = s[3];
  }
}

__global__ __launch_bounds__(256) void k_e2sum(
    const int* __restrict__ im, const int* __restrict__ io,
    const int* __restrict__ rel, const int* __restrict__ ci,
    const float* __restrict__ pm, const float* __restrict__ po,
    const float* __restrict__ ra1,
    float* __restrict__ es2, float* __restrict__ csum_p, int* __restrict__ ccnt_p){
  __shared__ float ls[Cc];
  __shared__ int lc[Cc];
  int t = threadIdx.x;
  for (int c = t; c < Cc; c += 256){ ls[c] = 0.f; lc[c] = 0; }
  __syncthreads();
  for (int e = blockIdx.x * 256 + t; e < Ee; e += gridDim.x * 256){
    float v = lrelu01(po[io[e]] + pm[im[e]] + ra1[rel[e]]);
    float s = expf(v);
    es2[e] = s;
    int c = ci[e];
    atomicAdd(&ls[c], s);
    atomicAdd(&lc[c], 1);
  }
  __syncthreads();
  for (int c = t; c < Cc; c += 256){
    if (lc[c]){
      atomicAdd(&csum_p[c * 16], ls[c]);
      atomicAdd(&ccnt_p[c * 16], lc[c]);
    }
  }
}

__global__ __launch_bounds__(256) void k_cscan(const int* __restrict__ ccnt_p,
    int* __restrict__ cstart, int* __restrict__ ccur_p){
  __shared__ int s[Cc + 1];
  int t = threadIdx.x;
  if (t == 0){
    int run = 0;
    for (int c = 0; c < Cc; c++){ s[c] = run; run += ccnt_p[c * 16]; }
    s[Cc] = run;
  }
  __syncthreads();
  if (t <= Cc) cstart[t] = s[t];
  if (t < Cc) ccur_p[t * 16] = s[t];
}

__global__ __launch_bounds__(256) void k_cscatter(
    const int* __restrict__ ci, const int* __restrict__ im,
    const float* __restrict__ es2,
    int* __restrict__ ccur_p, int* __restrict__ crows, float* __restrict__ cw){
  __shared__ int lcnt[Cc];
  __shared__ int lbase[Cc];
  int t = threadIdx.x;
  int epb = (Ee + gridDim.x - 1) / gridDim.x;
  int e0 = blockIdx.x * epb, e1 = e0 + epb; if (e1 > Ee) e1 = Ee;
  for (int c = t; c < Cc; c += 256) lcnt[c] = 0;
  __syncthreads();
  int myr[4], myc[4], mye[4]; int cnt = 0;
  for (int e = e0 + t; e < e1; e += 256){
    int c = ci[e];
    myr[cnt] = atomicAdd(&lcnt[c], 1);
    myc[cnt] = c; mye[cnt] = e; cnt++;
  }
  __syncthreads();
  for (int c = t; c < Cc; c += 256)
    lbase[c] = lcnt[c] ? atomicAdd(&ccur_p[c * 16], lcnt[c]) : 0;
  __syncthreads();
  for (int q = 0; q < cnt; q++){
    int pos = lbase[myc[q]] + myr[q];
    int e = mye[q];
    crows[pos] = im[im[e]];
    cw[pos] = es2[e];
  }
}

// class x_class accumulation: XSPL blocks per class, register accumulate + one
// atomicAdd per feature per block
__global__ __launch_bounds__(192) void k_xclassB(
    const int* __restrict__ cstart, const int* __restrict__ crows,
    const float* __restrict__ cw, const float* __restrict__ csum_p,
    const unsigned short* __restrict__ xnb, float* __restrict__ x_class){
  int c = blockIdx.x / XSPL, sp = blockIdx.x % XSPL;
  int t = threadIdx.x;
  int p0 = cstart[c], p1 = cstart[c + 1];
  int len = p1 - p0;
  if (len <= 0) return;
  int chunk = (len + XSPL - 1) / XSPL;
  int q0 = p0 + sp * chunk;
  int q1 = q0 + chunk; if (q1 > p1) q1 = p1;
  if (q0 >= q1) return;
  bool act = t < CHd;
  float inv = 1.f / csum_p[c * 16];
  float acc = 0.f;
  int k = q0;
  for (; k + 4 <= q1; k += 4){
    int r0 = crows[k], r1 = crows[k + 1], r2 = crows[k + 2], r3 = crows[k + 3];
    float w0 = cw[k] * inv, w1 = cw[k + 1] * inv, w2 = cw[k + 2] * inv, w3 = cw[k + 3] * inv;
    if (act){
      acc += w0 * b2f(xnb[(size_t)r0 * 152 + t]) + w1 * b2f(xnb[(size_t)r1 * 152 + t])
           + w2 * b2f(xnb[(size_t)r2 * 152 + t]) + w3 * b2f(xnb[(size_t)r3 * 152 + t]);
    }
  }
  for (; k < q1; k++){
    if (act) acc += cw[k] * inv * b2f(xnb[(size_t)crows[k] * 152 + t]);
  }
  if (act) atomicAdd(&x_class[c * CHd + t], acc);
}

__global__ __launch_bounds__(256) void k_classfinal(
    const float* __restrict__ x_class, const float* __restrict__ acv,
    const float* __restrict__ nv4, const int* __restrict__ cls_ent,
    float* __restrict__ outb){
  __shared__ float v[Cc];
  __shared__ float g[Cc];
  __shared__ int ce[Cc];
  int t = threadIdx.x;
  if (t < Cc){
    ce[t] = cls_ent[t];
    float dot = 0.f;
    for (int f = 0; f < CHd; f++) dot += x_class[t * CHd + f] * acv[f];
    v[t] = lrelu01(dot + nv4[ce[t]]);
  }
  __syncthreads();
  if (t < Cc){
    int sgm = ce[t];
    float m = -3.0e38f;
    for (int c2 = 0; c2 < Cc; c2++) if (ce[c2] == sgm) m = fmaxf(m, v[c2]);
    float sum = 0.f;
    for (int c2 = 0; c2 < Cc; c2++) if (ce[c2] == sgm) sum += expf(v[c2] - m);
    g[t] = expf(v[t] - m) / sum;
  }
  __syncthreads();
  for (int idx = t; idx < Cc * CHd; idx += 256){
    int c = idx / CHd, f = idx - c * CHd;
    atomicAdd(&outb[(size_t)ce[c] * CHd + f], g[c] * x_class[c * CHd + f]);
  }
}

__global__ __launch_bounds__(64) void k_s12(const unsigned short* __restrict__ x1b,
    const float* __restrict__ ai, const float* __restrict__ aj,
    float* __restrict__ s1, float* __restrict__ s2){
  int n = blockIdx.x, lane = threadIdx.x;
  const unsigned short* xr = x1b + (size_t)n * 600;
  float sa = 0.f, sb = 0.f;
#pragma unroll
  for (int u = 0; u < 10; u++){
    int f = lane + u * 64;
    if (f < 600){
      float x = b2f(xr[f]);
      sa += x * ai[f];
      sb += x * aj[f];
    }
  }
  float s[2] = { sa, sb };
  wredsumN<2>(s);
  if (!lane){ s1[n] = s[0]; s2[n] = s[1]; }
}

extern "C" void kernel_launch(void* const* d_in, const int* in_sizes, int n_in,
                              void* d_out, int out_size, void* d_ws, size_t ws_size,
                              hipStream_t stream) {
  const float* x_e    = (const float*)d_in[0];
  const int*   ei     = (const int*)d_in[1];
  const int*   rel    = (const int*)d_in[2];
  const int*   eall   = (const int*)d_in[3];
  const int*   cih    = (const int*)d_in[5];
  const int*   hcls   = (const int*)d_in[6];
  const int*   cit    = (const int*)d_in[7];
  const int*   tcls   = (const int*)d_in[8];
  const float* remb   = (const float*)d_in[9];
  const float* hw1w   = (const float*)d_in[10];
  const float* hw1b   = (const float*)d_in[11];
  const float* hw2w   = (const float*)d_in[12];
  const float* hw2b   = (const float*)d_in[13];
  const float* h2r_ac = (const float*)d_in[14];
  const float* h2r_ar = (const float*)d_in[15];
  const float* h2r_wh = (const float*)d_in[16];
  const float* h2r_wt = (const float*)d_in[17];
  const float* h2r_hww= (const float*)d_in[18];
  const float* h2r_hwb= (const float*)d_in[19];
  const float* et_ac  = (const float*)d_in[20];
  const float* et_ar  = (const float*)d_in[21];
  const float* et_wh  = (const float*)d_in[22];
  const float* et_wt  = (const float*)d_in[23];
  const float* et_hww = (const float*)d_in[24];
  const float* et_hwb = (const float*)d_in[25];
  const float* gai    = (const float*)d_in[26];
  const float* gaj    = (const float*)d_in[27];
  float* out = (float*)d_out;

  // ---- workspace allocator ----
  char* wsp = (char*)d_ws;
  auto alloc = [&](size_t nbytes) -> void* {
    void* p = (void*)wsp;
    wsp += (nbytes + 255) & ~(size_t)255;
    return p;
  };
  float* ra1h = (float*)alloc(Rr * 4);
  float* ra1e = (float*)alloc(Rr * 4);
  float* dis  = (float*)alloc(Nn * 4);
  int* degi    = (int*)alloc(Nn * 4);
  int* csr_ptr = (int*)alloc((Nn + 1) * 4);
  int* csr_cur = (int*)alloc(Nn * 4);
  int* csr_src = (int*)alloc((size_t)EALLe * 4);
  float* wg    = (float*)alloc((size_t)EALLe * 4);   // GCN csr weights
  float* wdiv  = (float*)alloc((size_t)EALLe * 4);   // GAT normalized csr weights
  float* x1  = (float*)alloc((size_t)Nn * 600 * 4);
  float* es2 = (float*)alloc((size_t)Ee * 4);
  float* pm  = (float*)alloc(Nn * 4);
  float* po  = (float*)alloc(Nn * 4);
  float* nv4 = (float*)alloc(Nn * 4);
  float* csum_p = (float*)alloc(Cc * 16 * 4);
  int*   ccnt_p = (int*)alloc(Cc * 16 * 4);
  int*   ccur_p = (int*)alloc(Cc * 16 * 4);
  int*   cstart = (int*)alloc((Cc + 1) * 4);
  int*   crows  = (int*)alloc((size_t)Ee * 4);
  float* cw     = (float*)alloc((size_t)Ee * 4);
  float* x_class = (float*)alloc(Cc * CHd * 4);
  float* s1v = (float*)alloc(Nn * 4);
  float* s2v = (float*)alloc(Nn * 4);
  // bf16 arenas
  unsigned short* arenaA = (unsigned short*)alloc((size_t)Nn * 320 * 2);
  unsigned short* arenaB = (unsigned short*)alloc((size_t)Nn * 320 * 2);
  unsigned short* x1b    = (unsigned short*)alloc(((size_t)Nn * 600 + 64) * 2);
  unsigned short* xnb    = (unsigned short*)alloc((size_t)Nn * 152 * 2);
  unsigned short* xob    = (unsigned short*)alloc((size_t)Nn * 160 * 2);
  unsigned short* w1b    = (unsigned short*)alloc((size_t)300 * 320 * 2);
  unsigned short* w2b    = (unsigned short*)alloc((size_t)300 * 320 * 2);
  unsigned short* wcatb  = (unsigned short*)alloc((size_t)600 * 320 * 2);
  unsigned short* hwwbA  = (unsigned short*)alloc((size_t)150 * 160 * 2);
  unsigned short* hwwbB  = (unsigned short*)alloc((size_t)150 * 160 * 2);

  // d_out staging layout (all dead before the final GAT rewrites d_out)
  float* h1   = out;
  float* gbuf = out + (size_t)Nn * EHd;
  float* proj = out;
  float* outb = out + (size_t)Nn * 600;

  // ---- prologue: r_emb norm, degrees, CSR, weight conversions ----
  hipMemsetAsync(degi, 0, Nn * 4, stream);
  k_rnorm<<<Rr, 64, 0, stream>>>(remb, h2r_ar, et_ar, ra1h, ra1e);
  k_count<<<cdiv_h(EALLe, 256), 256, 0, stream>>>(eall + EALLe, degi);
  k_dis<<<cdiv_h(Nn, 256), 256, 0, stream>>>(degi, dis);
  k_scan<<<1, 1024, 0, stream>>>(degi, csr_ptr, csr_cur);
  k_scatter<<<cdiv_h(EALLe, 256), 256, 0, stream>>>(eall, eall + EALLe, csr_cur, csr_src);
  k_wgcn<<<Nn, 64, 0, stream>>>(csr_ptr, csr_src, dis, wg);
  k_f2b<<<300, 64, 0, stream>>>(hw1w, 300, 300, w1b, 320);
  k_f2b<<<300, 64, 0, stream>>>(hw2w, 300, 300, w2b, 320);
  k_f2b<<<150, 64, 0, stream>>>(h2r_wh, 300, 300, wcatb + (size_t)0   * 320, 320);
  k_f2b<<<150, 64, 0, stream>>>(h2r_wt, 300, 300, wcatb + (size_t)150 * 320, 320);
  k_f2b<<<150, 64, 0, stream>>>(et_wh,  300, 300, wcatb + (size_t)300 * 320, 320);
  k_f2b<<<150, 64, 0, stream>>>(et_wt,  300, 300, wcatb + (size_t)450 * 320, 320);
  k_f2b<<<150, 64, 0, stream>>>(h2r_hww, 150, 150, hwwbA, 160);
  k_f2b<<<150, 64, 0, stream>>>(et_hww,  150, 150, hwwbB, 160);
  k_f2b<<<Nn, 64, 0, stream>>>(x_e, 300, 300, arenaA, 320);

  // ---- GCN + highway x2 (chunked L2-resident SpMM + bf16 MFMA GEMMs) ----
  k_spmm<100><<<dim3(cdiv_h(Nn, 4), 3), 256, 0, stream>>>(
      arenaA, 320, 300, csr_ptr, csr_src, wg, gbuf, 300, 0);
  k_gemmb<1,1><<<dim3(5, cdiv_h(Nn, 64)), 256, 0, stream>>>(
      arenaA, 320, Nn, w1b, 320, 300, hw1b, gbuf, 300, x_e, 300, h1, 300, arenaB, 320);
  k_spmm<100><<<dim3(cdiv_h(Nn, 4), 3), 256, 0, stream>>>(
      arenaB, 320, 300, csr_ptr, csr_src, wg, gbuf, 300, 0);
  k_gemmb<1,1><<<dim3(5, cdiv_h(Nn, 64)), 256, 0, stream>>>(
      arenaB, 320, Nn, w2b, 320, 300, hw2b, gbuf, 300, h1, 300, x1, 600, x1b, 600);

  // ---- batched projections: [xh_A | xt_A | xh_B | xt_B] = relu(x @ wcat^T) ----
  k_gemmb<0,0><<<dim3(10, cdiv_h(Nn, 64)), 256, 0, stream>>>(
      x1b, 600, Nn, wcatb, 320, 600, nullptr, nullptr, 0, nullptr, 0, proj, 600,
      nullptr, 0);

  // ---- gat_e (two calls) ----
  struct GP {
    const float* xm; const float* xo;
    const int* im; const int* io;
    const int* ci; const int* cls_ent;
    const float* ra1;
    const float* v2m; const float* v2o;
    const float* v3m; const float* v3o;
    const float* v4;  const float* acv;
    const unsigned short* hwwb; const float* hwb;
    float* x1out; unsigned short* x1outb;
  };
  const int* eh = ei;
  const int* et = ei + Ee;
  GP A = { proj + 150, proj + 0, et, eh, cih, hcls, ra1h,
           h2r_ac + 5 * CHd, h2r_ac + 1 * CHd,
           h2r_ac + 6 * CHd, h2r_ac + 2 * CHd,
           h2r_ac + 3 * CHd, h2r_ac + 7 * CHd,
           hwwbA, h2r_hwb, x1 + 300, x1b + 300 };
  GP B = { proj + 300, proj + 450, eh, et, cit, tcls, ra1e,
           et_ac + 1 * CHd, et_ac + 5 * CHd,
           et_ac + 2 * CHd, et_ac + 6 * CHd,
           et_ac + 3 * CHd, et_ac + 7 * CHd,
           hwwbB, et_hwb, x1 + 450, x1b + 450 };

  GP calls[2] = { A, B };
  for (int ci_ = 0; ci_ < 2; ci_++){
    const GP& P = calls[ci_];
    hipMemsetAsync(csum_p, 0, Cc * 16 * 4, stream);
    hipMemsetAsync(ccnt_p, 0, Cc * 16 * 4, stream);
    hipMemsetAsync(x_class, 0, Cc * CHd * 4, stream);
    hipMemsetAsync(outb, 0, (size_t)Nn * CHd * 4, stream);
    k_ndots2<<<Nn, 64, 0, stream>>>(P.xm, P.xo, 600, P.v2m, P.v3m, P.v2o, P.v3o, P.v4,
                                    xnb, pm, po, nv4);
    k_e2sum<<<CB, 256, 0, stream>>>(P.im, P.io, rel, P.ci, pm, po, P.ra1,
                                    es2, csum_p, ccnt_p);
    k_cscan<<<1, 256, 0, stream>>>(ccnt_p, cstart, ccur_p);
    k_cscatter<<<CB, 256, 0, stream>>>(P.ci, P.im, es2, ccur_p, crows, cw);
    k_xclassB<<<Cc * XSPL, 192, 0, stream>>>(cstart, crows, cw, csum_p, xnb, x_class);
    k_classfinal<<<1, 256, 0, stream>>>(x_class, P.acv, nv4, P.cls_ent, outb);
    k_f2b<<<Nn, 64, 0, stream>>>(P.xo, 150, 600, xob, 160);
    k_gemmb<1,1><<<dim3(3, cdiv_h(Nn, 64)), 256, 0, stream>>>(
        xob, 160, Nn, P.hwwb, 160, 150, P.hwb, outb, 150, P.xo, 600, P.x1out, 600,
        P.x1outb, 600);
  }

  // ---- final GAT: weights once, then chunked L2-resident SpMM + x-copy ----
  k_s12<<<Nn, 64, 0, stream>>>(x1b, gai, gaj, s1v, s2v);
  k_wgat<<<Nn, 64, 0, stream>>>(csr_ptr, csr_src, s1v, s2v, wdiv);
  k_copy300<<<cdiv_h(Nn * 75, 256), 256, 0, stream>>>(x1, out);
  k_spmm<120><<<dim3(cdiv_h(Nn, 4), 5), 256, 0, stream>>>(
      x1b, 600, 600, csr_ptr, csr_src, wdiv, out, 900, 300);
}

// Round 10
// 674.956 us; speedup vs baseline: 1.1948x; 1.1948x over previous
//
#include <hip/hip_runtime.h>
#include <math.h>

#define Nn 20000
#define Ee 120000
#define EALLe 240000
#define Cc 150
#define Rr 1000
#define EHd 300
#define RHd 100
#define CHd 150
#define CB 128
#define XSPL 16

static inline int cdiv_h(int a, int b){ return (a + b - 1) / b; }

typedef __attribute__((ext_vector_type(8))) short short8;
typedef __attribute__((ext_vector_type(4))) float f32x4;

__device__ __forceinline__ float lrelu01(float x){ return x > 0.f ? x : 0.01f * x; }

__device__ __forceinline__ unsigned short f2b(float f){
  unsigned int u = __float_as_uint(f);
  unsigned int r = (u + 0x7FFFu + ((u >> 16) & 1u)) >> 16;
  return (unsigned short)r;
}
__device__ __forceinline__ float b2f(unsigned short u){
  return __uint_as_float(((unsigned int)u) << 16);
}
__device__ __forceinline__ float b2f_lo(unsigned int u){
  return __uint_as_float(u << 16);
}
__device__ __forceinline__ float b2f_hi(unsigned int u){
  return __uint_as_float(u & 0xFFFF0000u);
}

template<int Kq>
__device__ __forceinline__ void wredsumN(float* v){
#pragma unroll
  for (int m = 32; m >= 1; m >>= 1){
#pragma unroll
    for (int k = 0; k < Kq; k++) v[k] += __shfl_xor(v[k], m, 64);
  }
}

// f32 [rows, ncols] (ld ldsrc) -> bf16 [rows, ldp], zero-padded cols ncols..ldp
__global__ __launch_bounds__(64) void k_f2b(const float* __restrict__ src, int ncols,
    int ldsrc, unsigned short* __restrict__ dst, int ldp){
  int r = blockIdx.x, t = threadIdx.x;
  for (int c = t; c < ldp; c += 64)
    dst[(size_t)r * ldp + c] = (c < ncols) ? f2b(src[(size_t)r * ldsrc + c]) : (unsigned short)0;
}

__global__ __launch_bounds__(64) void k_rnorm(const float* __restrict__ rt,
    const float* __restrict__ arh, const float* __restrict__ are,
    float* __restrict__ ra1h, float* __restrict__ ra1e){
  int r = blockIdx.x, lane = threadIdx.x;
  bool m1 = (lane + 64 < RHd);
  float v0 = rt[r * RHd + lane];
  float v1 = m1 ? rt[r * RHd + lane + 64] : 0.f;
  float s[3];
  s[0] = v0 * v0 + v1 * v1;
  s[1] = v0 * arh[RHd + lane] + (m1 ? v1 * arh[RHd + lane + 64] : 0.f);
  s[2] = v0 * are[RHd + lane] + (m1 ? v1 * are[RHd + lane + 64] : 0.f);
  wredsumN<3>(s);
  float inv = 0.5f / fmaxf(sqrtf(s[0]), 1e-12f);
  if (!lane){
    ra1h[r] = s[1] * inv;
    ra1e[r] = s[2] * inv;
  }
}

__global__ void k_count(const int* __restrict__ dst, int* __restrict__ degi){
  int e = blockIdx.x * blockDim.x + threadIdx.x;
  if (e < EALLe) atomicAdd(&degi[dst[e]], 1);
}

__global__ void k_dis(const int* __restrict__ degi, float* __restrict__ dis){
  int n = blockIdx.x * blockDim.x + threadIdx.x;
  if (n < Nn) dis[n] = degi[n] > 0 ? rsqrtf((float)degi[n]) : 0.f;
}

__global__ __launch_bounds__(1024) void k_scan(const int* __restrict__ degi,
    int* __restrict__ ptr, int* __restrict__ cur){
  __shared__ int s[1024];
  int t = threadIdx.x;
  const int per = (Nn + 1023) / 1024;
  int b0 = t * per; if (b0 > Nn) b0 = Nn;
  int b1 = b0 + per; if (b1 > Nn) b1 = Nn;
  int sum = 0;
  for (int i = b0; i < b1; i++) sum += degi[i];
  s[t] = sum;
  __syncthreads();
  for (int off = 1; off < 1024; off <<= 1){
    int v = (t >= off) ? s[t - off] : 0;
    __syncthreads();
    s[t] += v;
    __syncthreads();
  }
  int run = (t > 0) ? s[t - 1] : 0;
  for (int i = b0; i < b1; i++){
    ptr[i] = run; cur[i] = run; run += degi[i];
  }
  if (t == 1023) ptr[Nn] = s[1023];
}

__global__ void k_scatter(const int* __restrict__ src, const int* __restrict__ dst,
    int* __restrict__ cur, int* __restrict__ csr_src){
  int e = blockIdx.x * blockDim.x + threadIdx.x;
  if (e >= EALLe) return;
  int pos = atomicAdd(&cur[dst[e]], 1);
  csr_src[pos] = src[e];
}

// GCN edge weights per CSR slot: wg[k] = dis[i]*dis[src[k]]
__global__ __launch_bounds__(64) void k_wgcn(const int* __restrict__ ptr,
    const int* __restrict__ srcw, const float* __restrict__ dis, float* __restrict__ wg){
  int i = blockIdx.x, lane = threadIdx.x;
  int p0 = ptr[i], p1 = ptr[i + 1];
  float di = dis[i];
  for (int k = p0 + lane; k < p1; k += 64) wg[k] = di * dis[srcw[k]];
}

// GAT normalized edge weights per CSR slot: wdiv[k] = exp(lrelu(s1[i]+s2[j])) / den_i
__global__ __launch_bounds__(64) void k_wgat(const int* __restrict__ ptr,
    const int* __restrict__ srcw, const float* __restrict__ s1,
    const float* __restrict__ s2, float* __restrict__ wdiv){
  int i = blockIdx.x, lane = threadIdx.x;
  int p0 = ptr[i], p1 = ptr[i + 1];
  float s1i = s1[i];
  float den = 0.f;
  for (int k = p0 + lane; k < p1; k += 64){
    float w = expf(lrelu01(s1i + s2[srcw[k]]));
    wdiv[k] = w;
    den += w;
  }
  float d[1] = { den };
  wredsumN<1>(d);
  float inv = d[0] > 0.f ? 1.f / d[0] : 0.f;
  for (int k = p0 + lane; k < p1; k += 64) wdiv[k] *= inv;
}

// GCN SpMM + relu: 128 threads per node, dword (2xbf16) gathers.
// thread t owns dword t (cols 2t,2t+1) and, for t<22, dword 128+t (cols 256+2t..).
__global__ __launch_bounds__(128) void k_gcn2(const unsigned short* __restrict__ tab,
    const int* __restrict__ ptr, const int* __restrict__ srcw,
    const float* __restrict__ wg, float* __restrict__ outp){
  int i = blockIdx.x, t = threadIdx.x;
  int p0 = ptr[i], p1 = ptr[i + 1];
  bool m2 = t < 22;
  float a0 = 0.f, a1 = 0.f, c0 = 0.f, c1 = 0.f;
  for (int k = p0; k < p1; k++){
    int j = srcw[k];
    float w = wg[k];
    const unsigned short* xr = tab + (size_t)j * 320;
    unsigned int u = *(const unsigned int*)&xr[2 * t];
    a0 += w * b2f_lo(u);
    a1 += w * b2f_hi(u);
    if (m2){
      unsigned int v = *(const unsigned int*)&xr[256 + 2 * t];
      c0 += w * b2f_lo(v);
      c1 += w * b2f_hi(v);
    }
  }
  float* orow = outp + (size_t)i * 300;
  orow[2 * t] = fmaxf(a0, 0.f);
  orow[2 * t + 1] = fmaxf(a1, 0.f);
  if (m2){
    orow[256 + 2 * t] = fmaxf(c0, 0.f);
    orow[256 + 2 * t + 1] = fmaxf(c1, 0.f);
  }
}

// final GAT SpMM: 1 block (256 thr) per node, precomputed normalized weights,
// dword gathers: thread t owns dword t (cols 2t..) and, for t<44, dword 256+t.
__global__ __launch_bounds__(256) void k_gat2(
    const unsigned short* __restrict__ x1b,
    const int* __restrict__ ptr, const int* __restrict__ src,
    const float* __restrict__ wdiv, float* __restrict__ dout){
  __shared__ float wl[128];
  __shared__ int jl[128];
  int i = blockIdx.x, t = threadIdx.x;
  float* orow = dout + (size_t)i * 900;
  int p0 = ptr[i], p1 = ptr[i + 1];
  if (p0 == p1){
    for (int f = t; f < 600; f += 256) orow[300 + f] = 0.f;
    return;
  }
  bool m2 = t < 44;
  float a0 = 0.f, a1 = 0.f, c0 = 0.f, c1 = 0.f;
  for (int base = p0; base < p1; base += 128){
    int k = base + t;
    if (t < 128 && k < p1){
      jl[t] = src[k];
      wl[t] = wdiv[k];
    }
    __syncthreads();
    int lim = p1 - base; if (lim > 128) lim = 128;
    for (int q = 0; q < lim; q++){
      float w = wl[q];
      const unsigned short* xj = x1b + (size_t)jl[q] * 600;
      unsigned int u = *(const unsigned int*)&xj[2 * t];
      a0 += w * b2f_lo(u);
      a1 += w * b2f_hi(u);
      if (m2){
        unsigned int v = *(const unsigned int*)&xj[512 + 2 * t];
        c0 += w * b2f_lo(v);
        c1 += w * b2f_hi(v);
      }
    }
    __syncthreads();
  }
  orow[300 + 2 * t] = fmaxf(a0, 0.f);
  orow[300 + 2 * t + 1] = fmaxf(a1, 0.f);
  if (m2){
    orow[300 + 512 + 2 * t] = fmaxf(c0, 0.f);
    orow[300 + 512 + 2 * t + 1] = fmaxf(c1, 0.f);
  }
}

// copy x1[:, :300] (f32, ld 600) into d_out[:, :300] (ld 900), float4 vectorized
__global__ __launch_bounds__(256) void k_copy300(const float* __restrict__ x1,
    float* __restrict__ dout){
  size_t idx = (size_t)blockIdx.x * 256 + threadIdx.x;
  if (idx >= (size_t)Nn * 75) return;
  int r = (int)(idx / 75), q = (int)(idx % 75);
  ((f32x4*)(dout + (size_t)r * 900))[q] = ((const f32x4*)(x1 + (size_t)r * 600))[q];
}

// bf16 MFMA GEMM: out = epi( Xb[nrows,Kp]bf16 @ Wb[M,Kp]bf16^T ).
template<int EPI, int MIR>
__global__ __launch_bounds__(256) void k_gemmb(
    const unsigned short* __restrict__ Xb, int ldxb, int nrows,
    const unsigned short* __restrict__ Wb, int Kp, int M,
    const float* __restrict__ bias,
    const float* __restrict__ X2, int ldx2,
    const float* __restrict__ Xf, int ldxf,
    float* __restrict__ out, int ldo,
    unsigned short* __restrict__ mir, int ldmir){
  __shared__ unsigned short Xs[64][40];
  __shared__ unsigned short Ws[64][40];
  int t = threadIdx.x;
  int wv = t >> 6, lane = t & 63;
  int c0 = blockIdx.x * 64, r0 = blockIdx.y * 64;
  int srow = t >> 2, skoff = (t & 3) * 8;
  int gxr = r0 + srow, gwr = c0 + srow;
  f32x4 acc[4] = {};
  for (int k0 = 0; k0 < Kp; k0 += 32){
    short8 xv = {0,0,0,0,0,0,0,0};
    short8 wv8 = {0,0,0,0,0,0,0,0};
    if (gxr < nrows) xv = *(const short8*)&Xb[(size_t)gxr * ldxb + k0 + skoff];
    if (gwr < M)     wv8 = *(const short8*)&Wb[(size_t)gwr * Kp + k0 + skoff];
    __syncthreads();
    *(short8*)&Xs[srow][skoff] = xv;
    *(short8*)&Ws[srow][skoff] = wv8;
    __syncthreads();
    int arow = wv * 16 + (lane & 15);
    int kk = (lane >> 4) * 8;
    short8 af = *(const short8*)&Xs[arow][kk];
#pragma unroll
    for (int j = 0; j < 4; j++){
      short8 bf = *(const short8*)&Ws[j * 16 + (lane & 15)][kk];
      acc[j] = __builtin_amdgcn_mfma_f32_16x16x32_bf16(af, bf, acc[j], 0, 0, 0);
    }
  }
  int rbase = r0 + wv * 16 + (lane >> 4) * 4;
  int cbase = c0 + (lane & 15);
#pragma unroll
  for (int j = 0; j < 4; j++){
    int c = cbase + j * 16;
    if (c >= M) continue;
#pragma unroll
    for (int r = 0; r < 4; r++){
      int row = rbase + r;
      if (row >= nrows) continue;
      float v = acc[j][r];
      float o;
      if (EPI == 0){
        o = fmaxf(v, 0.f);
      } else {
        float g = 1.f / (1.f + expf(-(v + bias[c])));
        o = g * X2[(size_t)row * ldx2 + c] + (1.f - g) * Xf[(size_t)row * ldxf + c];
      }
      out[(size_t)row * ldo + c] = o;
      if (MIR) mir[(size_t)row * ldmir + c] = f2b(o);
    }
  }
}

// per-node precompute for gat_e (xm/xo live in proj with ld 600); xn stored bf16 ld 152
__global__ __launch_bounds__(64) void k_ndots2(
    const float* __restrict__ xm, const float* __restrict__ xo, int ldp,
    const float* __restrict__ v2m, const float* __restrict__ v3m,
    const float* __restrict__ v2o, const float* __restrict__ v3o,
    const float* __restrict__ v4,
    unsigned short* __restrict__ xnb, float* __restrict__ pm,
    float* __restrict__ po, float* __restrict__ nv4){
  int n = blockIdx.x, lane = threadIdx.x;
  bool m2 = lane < (CHd - 128);
  const float* mr = xm + (size_t)n * ldp;
  const float* orw = xo + (size_t)n * ldp;
  float m0 = mr[lane], m1 = mr[lane + 64], mv2 = m2 ? mr[lane + 128] : 0.f;
  float o0 = orw[lane], o1 = orw[lane + 64], o2 = m2 ? orw[lane + 128] : 0.f;
  float s[4];
  s[0] = m0 * m0 + m1 * m1 + mv2 * mv2;
  s[1] = o0 * v2o[lane] + o1 * v2o[lane + 64] + (m2 ? o2 * v2o[lane + 128] : 0.f);
  s[2] = o0 * v3o[lane] + o1 * v3o[lane + 64] + (m2 ? o2 * v3o[lane + 128] : 0.f);
  s[3] = o0 * v4[lane]  + o1 * v4[lane + 64]  + (m2 ? o2 * v4[lane + 128]  : 0.f);
  wredsumN<4>(s);
  float inv = 1.f / fmaxf(sqrtf(s[0]), 1e-12f);
  float n0 = m0 * inv, n1 = m1 * inv, n2 = mv2 * inv;
  unsigned short* xr = xnb + (size_t)n * 152;
  xr[lane] = f2b(n0); xr[lane + 64] = f2b(n1);
  if (m2) xr[lane + 128] = f2b(n2);
  float d[2];
  d[0] = n0 * v2m[lane] + n1 * v2m[lane + 64] + (m2 ? n2 * v2m[lane + 128] : 0.f);
  d[1] = n0 * v3m[lane] + n1 * v3m[lane + 64] + (m2 ? n2 * v3m[lane + 128] : 0.f);
  wredsumN<2>(d);
  if (!lane){
    pm[n] = d[0] + 0.25f * d[1];
    po[n] = s[1] + 0.25f * s[2];
    nv4[n] = s[3];
  }
}

__global__ __launch_bounds__(256) void k_e2sum(
    const int* __restrict__ im, const int* __restrict__ io,
    const int* __restrict__ rel, const int* __restrict__ ci,
    const float* __restrict__ pm, const float* __restrict__ po,
    const float* __restrict__ ra1,
    float* __restrict__ es2, float* __restrict__ csum_p, int* __restrict__ ccnt_p){
  __shared__ float ls[Cc];
  __shared__ int lc[Cc];
  int t = threadIdx.x;
  for (int c = t; c < Cc; c += 256){ ls[c] = 0.f; lc[c] = 0; }
  __syncthreads();
  for (int e = blockIdx.x * 256 + t; e < Ee; e += gridDim.x * 256){
    float v = lrelu01(po[io[e]] + pm[im[e]] + ra1[rel[e]]);
    float s = expf(v);
    es2[e] = s;
    int c = ci[e];
    atomicAdd(&ls[c], s);
    atomicAdd(&lc[c], 1);
  }
  __syncthreads();
  for (int c = t; c < Cc; c += 256){
    if (lc[c]){
      atomicAdd(&csum_p[c * 16], ls[c]);
      atomicAdd(&ccnt_p[c * 16], lc[c]);
    }
  }
}

__global__ __launch_bounds__(256) void k_cscan(const int* __restrict__ ccnt_p,
    int* __restrict__ cstart, int* __restrict__ ccur_p){
  __shared__ int s[Cc + 1];
  int t = threadIdx.x;
  if (t == 0){
    int run = 0;
    for (int c = 0; c < Cc; c++){ s[c] = run; run += ccnt_p[c * 16]; }
    s[Cc] = run;
  }
  __syncthreads();
  if (t <= Cc) cstart[t] = s[t];
  if (t < Cc) ccur_p[t * 16] = s[t];
}

__global__ __launch_bounds__(256) void k_cscatter(
    const int* __restrict__ ci, const int* __restrict__ im,
    const float* __restrict__ es2,
    int* __restrict__ ccur_p, int* __restrict__ crows, float* __restrict__ cw){
  __shared__ int lcnt[Cc];
  __shared__ int lbase[Cc];
  int t = threadIdx.x;
  int epb = (Ee + gridDim.x - 1) / gridDim.x;
  int e0 = blockIdx.x * epb, e1 = e0 + epb; if (e1 > Ee) e1 = Ee;
  for (int c = t; c < Cc; c += 256) lcnt[c] = 0;
  __syncthreads();
  int myr[4], myc[4], mye[4]; int cnt = 0;
  for (int e = e0 + t; e < e1; e += 256){
    int c = ci[e];
    myr[cnt] = atomicAdd(&lcnt[c], 1);
    myc[cnt] = c; mye[cnt] = e; cnt++;
  }
  __syncthreads();
  for (int c = t; c < Cc; c += 256)
    lbase[c] = lcnt[c] ? atomicAdd(&ccur_p[c * 16], lcnt[c]) : 0;
  __syncthreads();
  for (int q = 0; q < cnt; q++){
    int pos = lbase[myc[q]] + myr[q];
    int e = mye[q];
    crows[pos] = im[im[e]];
    cw[pos] = es2[e];
  }
}

__global__ __launch_bounds__(192) void k_xclassB(
    const int* __restrict__ cstart, const int* __restrict__ crows,
    const float* __restrict__ cw, const float* __restrict__ csum_p,
    const unsigned short* __restrict__ xnb, float* __restrict__ x_class){
  int c = blockIdx.x / XSPL, sp = blockIdx.x % XSPL;
  int t = threadIdx.x;
  int p0 = cstart[c], p1 = cstart[c + 1];
  int len = p1 - p0;
  if (len <= 0) return;
  int chunk = (len + XSPL - 1) / XSPL;
  int q0 = p0 + sp * chunk;
  int q1 = q0 + chunk; if (q1 > p1) q1 = p1;
  if (q0 >= q1) return;
  bool act = t < CHd;
  float inv = 1.f / csum_p[c * 16];
  float acc = 0.f;
  int k = q0;
  for (; k + 4 <= q1; k += 4){
    int r0 = crows[k], r1 = crows[k + 1], r2 = crows[k + 2], r3 = crows[k + 3];
    float w0 = cw[k] * inv, w1 = cw[k + 1] * inv, w2 = cw[k + 2] * inv, w3 = cw[k + 3] * inv;
    if (act){
      acc += w0 * b2f(xnb[(size_t)r0 * 152 + t]) + w1 * b2f(xnb[(size_t)r1 * 152 + t])
           + w2 * b2f(xnb[(size_t)r2 * 152 + t]) + w3 * b2f(xnb[(size_t)r3 * 152 + t]);
    }
  }
  for (; k < q1; k++){
    if (act) acc += cw[k] * inv * b2f(xnb[(size_t)crows[k] * 152 + t]);
  }
  if (act) atomicAdd(&x_class[c * CHd + t], acc);
}

__global__ __launch_bounds__(256) void k_classfinal(
    const float* __restrict__ x_class, const float* __restrict__ acv,
    const float* __restrict__ nv4, const int* __restrict__ cls_ent,
    float* __restrict__ outb){
  __shared__ float v[Cc];
  __shared__ float g[Cc];
  __shared__ int ce[Cc];
  int t = threadIdx.x;
  if (t < Cc){
    ce[t] = cls_ent[t];
    float dot = 0.f;
    for (int f = 0; f < CHd; f++) dot += x_class[t * CHd + f] * acv[f];
    v[t] = lrelu01(dot + nv4[ce[t]]);
  }
  __syncthreads();
  if (t < Cc){
    int sgm = ce[t];
    float m = -3.0e38f;
    for (int c2 = 0; c2 < Cc; c2++) if (ce[c2] == sgm) m = fmaxf(m, v[c2]);
    float sum = 0.f;
    for (int c2 = 0; c2 < Cc; c2++) if (ce[c2] == sgm) sum += expf(v[c2] - m);
    g[t] = expf(v[t] - m) / sum;
  }
  __syncthreads();
  for (int idx = t; idx < Cc * CHd; idx += 256){
    int c = idx / CHd, f = idx - c * CHd;
    atomicAdd(&outb[(size_t)ce[c] * CHd + f], g[c] * x_class[c * CHd + f]);
  }
}

__global__ __launch_bounds__(64) void k_s12(const unsigned short* __restrict__ x1b,
    const float* __restrict__ ai, const float* __restrict__ aj,
    float* __restrict__ s1, float* __restrict__ s2){
  int n = blockIdx.x, lane = threadIdx.x;
  const unsigned short* xr = x1b + (size_t)n * 600;
  float sa = 0.f, sb = 0.f;
#pragma unroll
  for (int u = 0; u < 10; u++){
    int f = lane + u * 64;
    if (f < 600){
      float x = b2f(xr[f]);
      sa += x * ai[f];
      sb += x * aj[f];
    }
  }
  float s[2] = { sa, sb };
  wredsumN<2>(s);
  if (!lane){ s1[n] = s[0]; s2[n] = s[1]; }
}

extern "C" void kernel_launch(void* const* d_in, const int* in_sizes, int n_in,
                              void* d_out, int out_size, void* d_ws, size_t ws_size,
                              hipStream_t stream) {
  const float* x_e    = (const float*)d_in[0];
  const int*   ei     = (const int*)d_in[1];
  const int*   rel    = (const int*)d_in[2];
  const int*   eall   = (const int*)d_in[3];
  const int*   cih    = (const int*)d_in[5];
  const int*   hcls   = (const int*)d_in[6];
  const int*   cit    = (const int*)d_in[7];
  const int*   tcls   = (const int*)d_in[8];
  const float* remb   = (const float*)d_in[9];
  const float* hw1w   = (const float*)d_in[10];
  const float* hw1b   = (const float*)d_in[11];
  const float* hw2w   = (const float*)d_in[12];
  const float* hw2b   = (const float*)d_in[13];
  const float* h2r_ac = (const float*)d_in[14];
  const float* h2r_ar = (const float*)d_in[15];
  const float* h2r_wh = (const float*)d_in[16];
  const float* h2r_wt = (const float*)d_in[17];
  const float* h2r_hww= (const float*)d_in[18];
  const float* h2r_hwb= (const float*)d_in[19];
  const float* et_ac  = (const float*)d_in[20];
  const float* et_ar  = (const float*)d_in[21];
  const float* et_wh  = (const float*)d_in[22];
  const float* et_wt  = (const float*)d_in[23];
  const float* et_hww = (const float*)d_in[24];
  const float* et_hwb = (const float*)d_in[25];
  const float* gai    = (const float*)d_in[26];
  const float* gaj    = (const float*)d_in[27];
  float* out = (float*)d_out;

  // ---- workspace allocator ----
  char* wsp = (char*)d_ws;
  auto alloc = [&](size_t nbytes) -> void* {
    void* p = (void*)wsp;
    wsp += (nbytes + 255) & ~(size_t)255;
    return p;
  };
  float* ra1h = (float*)alloc(Rr * 4);
  float* ra1e = (float*)alloc(Rr * 4);
  float* dis  = (float*)alloc(Nn * 4);
  int* degi    = (int*)alloc(Nn * 4);
  int* csr_ptr = (int*)alloc((Nn + 1) * 4);
  int* csr_cur = (int*)alloc(Nn * 4);
  int* csr_src = (int*)alloc((size_t)EALLe * 4);
  float* wg    = (float*)alloc((size_t)EALLe * 4);
  float* wdiv  = (float*)alloc((size_t)EALLe * 4);
  float* x1  = (float*)alloc((size_t)Nn * 600 * 4);
  float* es2 = (float*)alloc((size_t)Ee * 4);
  float* pm  = (float*)alloc(Nn * 4);
  float* po  = (float*)alloc(Nn * 4);
  float* nv4 = (float*)alloc(Nn * 4);
  float* csum_p = (float*)alloc(Cc * 16 * 4);
  int*   ccnt_p = (int*)alloc(Cc * 16 * 4);
  int*   ccur_p = (int*)alloc(Cc * 16 * 4);
  int*   cstart = (int*)alloc((Cc + 1) * 4);
  int*   crows  = (int*)alloc((size_t)Ee * 4);
  float* cw     = (float*)alloc((size_t)Ee * 4);
  float* x_class = (float*)alloc(Cc * CHd * 4);
  float* s1v = (float*)alloc(Nn * 4);
  float* s2v = (float*)alloc(Nn * 4);
  unsigned short* arenaA = (unsigned short*)alloc((size_t)Nn * 320 * 2);
  unsigned short* arenaB = (unsigned short*)alloc((size_t)Nn * 320 * 2);
  unsigned short* x1b    = (unsigned short*)alloc(((size_t)Nn * 600 + 64) * 2);
  unsigned short* xnb    = (unsigned short*)alloc((size_t)Nn * 152 * 2);
  unsigned short* xob    = (unsigned short*)alloc((size_t)Nn * 160 * 2);
  unsigned short* w1b    = (unsigned short*)alloc((size_t)300 * 320 * 2);
  unsigned short* w2b    = (unsigned short*)alloc((size_t)300 * 320 * 2);
  unsigned short* wcatb  = (unsigned short*)alloc((size_t)600 * 320 * 2);
  unsigned short* hwwbA  = (unsigned short*)alloc((size_t)150 * 160 * 2);
  unsigned short* hwwbB  = (unsigned short*)alloc((size_t)150 * 160 * 2);

  // d_out staging layout (all dead before the final GAT rewrites d_out)
  float* h1   = out;
  float* gbuf = out + (size_t)Nn * EHd;
  float* proj = out;
  float* outb = out + (size_t)Nn * 600;

  // ---- prologue: r_emb norm, degrees, CSR, weight conversions ----
  hipMemsetAsync(degi, 0, Nn * 4, stream);
  k_rnorm<<<Rr, 64, 0, stream>>>(remb, h2r_ar, et_ar, ra1h, ra1e);
  k_count<<<cdiv_h(EALLe, 256), 256, 0, stream>>>(eall + EALLe, degi);
  k_dis<<<cdiv_h(Nn, 256), 256, 0, stream>>>(degi, dis);
  k_scan<<<1, 1024, 0, stream>>>(degi, csr_ptr, csr_cur);
  k_scatter<<<cdiv_h(EALLe, 256), 256, 0, stream>>>(eall, eall + EALLe, csr_cur, csr_src);
  k_wgcn<<<Nn, 64, 0, stream>>>(csr_ptr, csr_src, dis, wg);
  k_f2b<<<300, 64, 0, stream>>>(hw1w, 300, 300, w1b, 320);
  k_f2b<<<300, 64, 0, stream>>>(hw2w, 300, 300, w2b, 320);
  k_f2b<<<150, 64, 0, stream>>>(h2r_wh, 300, 300, wcatb + (size_t)0   * 320, 320);
  k_f2b<<<150, 64, 0, stream>>>(h2r_wt, 300, 300, wcatb + (size_t)150 * 320, 320);
  k_f2b<<<150, 64, 0, stream>>>(et_wh,  300, 300, wcatb + (size_t)300 * 320, 320);
  k_f2b<<<150, 64, 0, stream>>>(et_wt,  300, 300, wcatb + (size_t)450 * 320, 320);
  k_f2b<<<150, 64, 0, stream>>>(h2r_hww, 150, 150, hwwbA, 160);
  k_f2b<<<150, 64, 0, stream>>>(et_hww,  150, 150, hwwbB, 160);
  k_f2b<<<Nn, 64, 0, stream>>>(x_e, 300, 300, arenaA, 320);

  // ---- GCN + highway x2 (dword-gather SpMM + bf16 MFMA GEMMs) ----
  k_gcn2<<<Nn, 128, 0, stream>>>(arenaA, csr_ptr, csr_src, wg, gbuf);
  k_gemmb<1,1><<<dim3(5, cdiv_h(Nn, 64)), 256, 0, stream>>>(
      arenaA, 320, Nn, w1b, 320, 300, hw1b, gbuf, 300, x_e, 300, h1, 300, arenaB, 320);
  k_gcn2<<<Nn, 128, 0, stream>>>(arenaB, csr_ptr, csr_src, wg, gbuf);
  k_gemmb<1,1><<<dim3(5, cdiv_h(Nn, 64)), 256, 0, stream>>>(
      arenaB, 320, Nn, w2b, 320, 300, hw2b, gbuf, 300, h1, 300, x1, 600, x1b, 600);

  // ---- batched projections: [xh_A | xt_A | xh_B | xt_B] = relu(x @ wcat^T) ----
  k_gemmb<0,0><<<dim3(10, cdiv_h(Nn, 64)), 256, 0, stream>>>(
      x1b, 600, Nn, wcatb, 320, 600, nullptr, nullptr, 0, nullptr, 0, proj, 600,
      nullptr, 0);

  // ---- gat_e (two calls) ----
  struct GP {
    const float* xm; const float* xo;
    const int* im; const int* io;
    const int* ci; const int* cls_ent;
    const float* ra1;
    const float* v2m; const float* v2o;
    const float* v3m; const float* v3o;
    const float* v4;  const float* acv;
    const unsigned short* hwwb; const float* hwb;
    float* x1out; unsigned short* x1outb;
  };
  const int* eh = ei;
  const int* et = ei + Ee;
  GP A = { proj + 150, proj + 0, et, eh, cih, hcls, ra1h,
           h2r_ac + 5 * CHd, h2r_ac + 1 * CHd,
           h2r_ac + 6 * CHd, h2r_ac + 2 * CHd,
           h2r_ac + 3 * CHd, h2r_ac + 7 * CHd,
           hwwbA, h2r_hwb, x1 + 300, x1b + 300 };
  GP B = { proj + 300, proj + 450, eh, et, cit, tcls, ra1e,
           et_ac + 1 * CHd, et_ac + 5 * CHd,
           et_ac + 2 * CHd, et_ac + 6 * CHd,
           et_ac + 3 * CHd, et_ac + 7 * CHd,
           hwwbB, et_hwb, x1 + 450, x1b + 450 };

  GP calls[2] = { A, B };
  for (int ci_ = 0; ci_ < 2; ci_++){
    const GP& P = calls[ci_];
    hipMemsetAsync(csum_p, 0, Cc * 16 * 4, stream);
    hipMemsetAsync(ccnt_p, 0, Cc * 16 * 4, stream);
    hipMemsetAsync(x_class, 0, Cc * CHd * 4, stream);
    hipMemsetAsync(outb, 0, (size_t)Nn * CHd * 4, stream);
    k_ndots2<<<Nn, 64, 0, stream>>>(P.xm, P.xo, 600, P.v2m, P.v3m, P.v2o, P.v3o, P.v4,
                                    xnb, pm, po, nv4);
    k_e2sum<<<CB, 256, 0, stream>>>(P.im, P.io, rel, P.ci, pm, po, P.ra1,
                                    es2, csum_p, ccnt_p);
    k_cscan<<<1, 256, 0, stream>>>(ccnt_p, cstart, ccur_p);
    k_cscatter<<<CB, 256, 0, stream>>>(P.ci, P.im, es2, ccur_p, crows, cw);
    k_xclassB<<<Cc * XSPL, 192, 0, stream>>>(cstart, crows, cw, csum_p, xnb, x_class);
    k_classfinal<<<1, 256, 0, stream>>>(x_class, P.acv, nv4, P.cls_ent, outb);
    k_f2b<<<Nn, 64, 0, stream>>>(P.xo, 150, 600, xob, 160);
    k_gemmb<1,1><<<dim3(3, cdiv_h(Nn, 64)), 256, 0, stream>>>(
        xob, 160, Nn, P.hwwb, 160, 150, P.hwb, outb, 150, P.xo, 600, P.x1out, 600,
        P.x1outb, 600);
  }

  // ---- final GAT: weights once, copy + dword-gather SpMM ----
  k_s12<<<Nn, 64, 0, stream>>>(x1b, gai, gaj, s1v, s2v);
  k_wgat<<<Nn, 64, 0, stream>>>(csr_ptr, csr_src, s1v, s2v, wdiv);
  k_copy300<<<cdiv_h(Nn * 75, 256), 256, 0, stream>>>(x1, out);
  k_gat2<<<Nn, 256, 0, stream>>>(x1b, csr_ptr, csr_src, wdiv, out);
}

// Round 11
// 549.196 us; speedup vs baseline: 1.4684x; 1.2290x over previous
//
#include <hip/hip_runtime.h>
#include <math.h>

#define Nn 20000
#define Ee 120000
#define EALLe 240000
#define Cc 150
#define Rr 1000
#define EHd 300
#define RHd 100
#define CHd 150
#define CB 128
#define XSPL 16

static inline int cdiv_h(int a, int b){ return (a + b - 1) / b; }

typedef __attribute__((ext_vector_type(8))) short short8;
typedef __attribute__((ext_vector_type(4))) float f32x4;

__device__ __forceinline__ float lrelu01(float x){ return x > 0.f ? x : 0.01f * x; }

__device__ __forceinline__ unsigned short f2b(float f){
  unsigned int u = __float_as_uint(f);
  unsigned int r = (u + 0x7FFFu + ((u >> 16) & 1u)) >> 16;
  return (unsigned short)r;
}
__device__ __forceinline__ float b2f(unsigned short u){
  return __uint_as_float(((unsigned int)u) << 16);
}
__device__ __forceinline__ float b2f_lo(unsigned int u){
  return __uint_as_float(u << 16);
}
__device__ __forceinline__ float b2f_hi(unsigned int u){
  return __uint_as_float(u & 0xFFFF0000u);
}

template<int Kq>
__device__ __forceinline__ void wredsumN(float* v){
#pragma unroll
  for (int m = 32; m >= 1; m >>= 1){
#pragma unroll
    for (int k = 0; k < Kq; k++) v[k] += __shfl_xor(v[k], m, 64);
  }
}

// f32 [rows, ncols] (ld ldsrc) -> bf16 [rows, ldp], zero-padded cols ncols..ldp
__global__ __launch_bounds__(64) void k_f2b(const float* __restrict__ src, int ncols,
    int ldsrc, unsigned short* __restrict__ dst, int ldp){
  int r = blockIdx.x, t = threadIdx.x;
  for (int c = t; c < ldp; c += 64)
    dst[(size_t)r * ldp + c] = (c < ncols) ? f2b(src[(size_t)r * ldsrc + c]) : (unsigned short)0;
}

// batched xo->bf16 for both gat_e calls: g selects proj slice (A: +0, B: +450)
__global__ __launch_bounds__(64) void k_f2bxo(const float* __restrict__ proj,
    unsigned short* __restrict__ xob){
  int r = blockIdx.x, g = blockIdx.y, t = threadIdx.x;
  const float* src = proj + (size_t)r * 600 + (g ? 450 : 0);
  unsigned short* dst = xob + (size_t)g * Nn * 160 + (size_t)r * 160;
  for (int c = t; c < 160; c += 64)
    dst[c] = (c < 150) ? f2b(src[c]) : (unsigned short)0;
}

__global__ __launch_bounds__(64) void k_rnorm(const float* __restrict__ rt,
    const float* __restrict__ arh, const float* __restrict__ are,
    float* __restrict__ ra1h, float* __restrict__ ra1e){
  int r = blockIdx.x, lane = threadIdx.x;
  bool m1 = (lane + 64 < RHd);
  float v0 = rt[r * RHd + lane];
  float v1 = m1 ? rt[r * RHd + lane + 64] : 0.f;
  float s[3];
  s[0] = v0 * v0 + v1 * v1;
  s[1] = v0 * arh[RHd + lane] + (m1 ? v1 * arh[RHd + lane + 64] : 0.f);
  s[2] = v0 * are[RHd + lane] + (m1 ? v1 * are[RHd + lane + 64] : 0.f);
  wredsumN<3>(s);
  float inv = 0.5f / fmaxf(sqrtf(s[0]), 1e-12f);
  if (!lane){
    ra1h[r] = s[1] * inv;
    ra1e[r] = s[2] * inv;
  }
}

__global__ void k_count(const int* __restrict__ dst, int* __restrict__ degi){
  int e = blockIdx.x * blockDim.x + threadIdx.x;
  if (e < EALLe) atomicAdd(&degi[dst[e]], 1);
}

__global__ void k_dis(const int* __restrict__ degi, float* __restrict__ dis){
  int n = blockIdx.x * blockDim.x + threadIdx.x;
  if (n < Nn) dis[n] = degi[n] > 0 ? rsqrtf((float)degi[n]) : 0.f;
}

__global__ __launch_bounds__(1024) void k_scan(const int* __restrict__ degi,
    int* __restrict__ ptr, int* __restrict__ cur){
  __shared__ int s[1024];
  int t = threadIdx.x;
  const int per = (Nn + 1023) / 1024;
  int b0 = t * per; if (b0 > Nn) b0 = Nn;
  int b1 = b0 + per; if (b1 > Nn) b1 = Nn;
  int sum = 0;
  for (int i = b0; i < b1; i++) sum += degi[i];
  s[t] = sum;
  __syncthreads();
  for (int off = 1; off < 1024; off <<= 1){
    int v = (t >= off) ? s[t - off] : 0;
    __syncthreads();
    s[t] += v;
    __syncthreads();
  }
  int run = (t > 0) ? s[t - 1] : 0;
  for (int i = b0; i < b1; i++){
    ptr[i] = run; cur[i] = run; run += degi[i];
  }
  if (t == 1023) ptr[Nn] = s[1023];
}

__global__ void k_scatter(const int* __restrict__ src, const int* __restrict__ dst,
    int* __restrict__ cur, int* __restrict__ csr_src){
  int e = blockIdx.x * blockDim.x + threadIdx.x;
  if (e >= EALLe) return;
  int pos = atomicAdd(&cur[dst[e]], 1);
  csr_src[pos] = src[e];
}

// GCN SpMM + relu, gathering from a bf16 table (ld ldx) — R8-proven 64-thread 5-way ILP
__global__ __launch_bounds__(64) void k_gcnb(const unsigned short* __restrict__ x, int ldx,
    const int* __restrict__ ptr, const int* __restrict__ src,
    const float* __restrict__ dis, float* __restrict__ out){
  int i = blockIdx.x, lane = threadIdx.x;
  int p0 = ptr[i], p1 = ptr[i + 1];
  float di = dis[i];
  float a0 = 0.f, a1 = 0.f, a2 = 0.f, a3 = 0.f, a4 = 0.f;
  for (int k = p0; k < p1; k++){
    int j = src[k];
    float w = di * dis[j];
    const unsigned short* xr = x + (size_t)j * ldx;
    a0 += w * b2f(xr[lane]);
    a1 += w * b2f(xr[lane + 64]);
    a2 += w * b2f(xr[lane + 128]);
    a3 += w * b2f(xr[lane + 192]);
    if (lane < EHd - 256) a4 += w * b2f(xr[lane + 256]);
  }
  float* orow = out + (size_t)i * EHd;
  orow[lane] = fmaxf(a0, 0.f);
  orow[lane + 64] = fmaxf(a1, 0.f);
  orow[lane + 128] = fmaxf(a2, 0.f);
  orow[lane + 192] = fmaxf(a3, 0.f);
  if (lane < EHd - 256) orow[lane + 256] = fmaxf(a4, 0.f);
}

// final GAT: fused x-copy + in-LDS edge weights + dword bf16 gathers.
__global__ __launch_bounds__(256) void k_gat3(const float* __restrict__ x1,
    const unsigned short* __restrict__ x1b,
    const int* __restrict__ ptr, const int* __restrict__ src,
    const float* __restrict__ s1, const float* __restrict__ s2,
    float* __restrict__ dout){
  __shared__ float wl[128];
  __shared__ int jl[128];
  int i = blockIdx.x, t = threadIdx.x;
  float* orow = dout + (size_t)i * 900;
  const float* xi = x1 + (size_t)i * 600;
  if (t < 75) ((f32x4*)orow)[t] = ((const f32x4*)xi)[t];
  int p0 = ptr[i], p1 = ptr[i + 1];
  if (p0 == p1){
    for (int f = t; f < 600; f += 256) orow[300 + f] = 0.f;
    return;
  }
  float s1i = s1[i];
  bool m2 = t < 44;
  float a0 = 0.f, a1 = 0.f, c0 = 0.f, c1 = 0.f, den = 0.f;
  for (int base = p0; base < p1; base += 128){
    int k = base + t;
    if (t < 128 && k < p1){
      int j = src[k];
      jl[t] = j;
      wl[t] = expf(lrelu01(s1i + s2[j]));
    }
    __syncthreads();
    int lim = p1 - base; if (lim > 128) lim = 128;
    for (int q = 0; q < lim; q++){
      float w = wl[q];
      den += w;
      const unsigned short* xj = x1b + (size_t)jl[q] * 600;
      unsigned int u = *(const unsigned int*)&xj[2 * t];
      a0 += w * b2f_lo(u);
      a1 += w * b2f_hi(u);
      if (m2){
        unsigned int v = *(const unsigned int*)&xj[512 + 2 * t];
        c0 += w * b2f_lo(v);
        c1 += w * b2f_hi(v);
      }
    }
    __syncthreads();
  }
  float invd = 1.f / den;
  orow[300 + 2 * t] = fmaxf(a0 * invd, 0.f);
  orow[300 + 2 * t + 1] = fmaxf(a1 * invd, 0.f);
  if (m2){
    orow[300 + 512 + 2 * t] = fmaxf(c0 * invd, 0.f);
    orow[300 + 512 + 2 * t + 1] = fmaxf(c1 * invd, 0.f);
  }
}

// bf16 MFMA GEMM: out = epi( Xb[nrows,Kp]bf16 @ Wb[M,Kp]bf16^T ).
template<int EPI, int MIR>
__global__ __launch_bounds__(256) void k_gemmb(
    const unsigned short* __restrict__ Xb, int ldxb, int nrows,
    const unsigned short* __restrict__ Wb, int Kp, int M,
    const float* __restrict__ bias,
    const float* __restrict__ X2, int ldx2,
    const float* __restrict__ Xf, int ldxf,
    float* __restrict__ out, int ldo,
    unsigned short* __restrict__ mir, int ldmir){
  __shared__ unsigned short Xs[64][40];
  __shared__ unsigned short Ws[64][40];
  int t = threadIdx.x;
  int wv = t >> 6, lane = t & 63;
  int c0 = blockIdx.x * 64, r0 = blockIdx.y * 64;
  int srow = t >> 2, skoff = (t & 3) * 8;
  int gxr = r0 + srow, gwr = c0 + srow;
  f32x4 acc[4] = {};
  for (int k0 = 0; k0 < Kp; k0 += 32){
    short8 xv = {0,0,0,0,0,0,0,0};
    short8 wv8 = {0,0,0,0,0,0,0,0};
    if (gxr < nrows) xv = *(const short8*)&Xb[(size_t)gxr * ldxb + k0 + skoff];
    if (gwr < M)     wv8 = *(const short8*)&Wb[(size_t)gwr * Kp + k0 + skoff];
    __syncthreads();
    *(short8*)&Xs[srow][skoff] = xv;
    *(short8*)&Ws[srow][skoff] = wv8;
    __syncthreads();
    int arow = wv * 16 + (lane & 15);
    int kk = (lane >> 4) * 8;
    short8 af = *(const short8*)&Xs[arow][kk];
#pragma unroll
    for (int j = 0; j < 4; j++){
      short8 bf = *(const short8*)&Ws[j * 16 + (lane & 15)][kk];
      acc[j] = __builtin_amdgcn_mfma_f32_16x16x32_bf16(af, bf, acc[j], 0, 0, 0);
    }
  }
  int rbase = r0 + wv * 16 + (lane >> 4) * 4;
  int cbase = c0 + (lane & 15);
#pragma unroll
  for (int j = 0; j < 4; j++){
    int c = cbase + j * 16;
    if (c >= M) continue;
#pragma unroll
    for (int r = 0; r < 4; r++){
      int row = rbase + r;
      if (row >= nrows) continue;
      float v = acc[j][r];
      float o;
      if (EPI == 0){
        o = fmaxf(v, 0.f);
      } else {
        float g = 1.f / (1.f + expf(-(v + bias[c])));
        o = g * X2[(size_t)row * ldx2 + c] + (1.f - g) * Xf[(size_t)row * ldxf + c];
      }
      out[(size_t)row * ldo + c] = o;
      if (MIR) mir[(size_t)row * ldmir + c] = f2b(o);
    }
  }
}

// batched gat_e highway GEMM: blockIdx.z = call g. Kp=160, M=150, highway epilogue,
// mirror into x1b slice.
__global__ __launch_bounds__(256) void k_hwgemm(
    const unsigned short* __restrict__ xob,
    const unsigned short* __restrict__ hwwbA, const unsigned short* __restrict__ hwwbB,
    const float* __restrict__ hwbA, const float* __restrict__ hwbB,
    const float* __restrict__ outb, const float* __restrict__ proj,
    float* __restrict__ x1, unsigned short* __restrict__ x1b){
  __shared__ unsigned short Xs[64][40];
  __shared__ unsigned short Ws[64][40];
  int g = blockIdx.z;
  const unsigned short* Xb = xob + (size_t)g * Nn * 160;
  const unsigned short* Wb = g ? hwwbB : hwwbA;
  const float* bias = g ? hwbB : hwbA;
  const float* X2 = outb + (size_t)g * Nn * CHd;
  const float* Xf = proj + (g ? 450 : 0);
  float* outp = x1 + (g ? 450 : 300);
  unsigned short* mir = x1b + (g ? 450 : 300);
  int t = threadIdx.x;
  int wv = t >> 6, lane = t & 63;
  int c0 = blockIdx.x * 64, r0 = blockIdx.y * 64;
  int srow = t >> 2, skoff = (t & 3) * 8;
  int gxr = r0 + srow, gwr = c0 + srow;
  f32x4 acc[4] = {};
  for (int k0 = 0; k0 < 160; k0 += 32){
    short8 xv = {0,0,0,0,0,0,0,0};
    short8 wv8 = {0,0,0,0,0,0,0,0};
    if (gxr < Nn) xv = *(const short8*)&Xb[(size_t)gxr * 160 + k0 + skoff];
    if (gwr < 150) wv8 = *(const short8*)&Wb[(size_t)gwr * 160 + k0 + skoff];
    __syncthreads();
    *(short8*)&Xs[srow][skoff] = xv;
    *(short8*)&Ws[srow][skoff] = wv8;
    __syncthreads();
    int arow = wv * 16 + (lane & 15);
    int kk = (lane >> 4) * 8;
    short8 af = *(const short8*)&Xs[arow][kk];
#pragma unroll
    for (int j = 0; j < 4; j++){
      short8 bf = *(const short8*)&Ws[j * 16 + (lane & 15)][kk];
      acc[j] = __builtin_amdgcn_mfma_f32_16x16x32_bf16(af, bf, acc[j], 0, 0, 0);
    }
  }
  int rbase = r0 + wv * 16 + (lane >> 4) * 4;
  int cbase = c0 + (lane & 15);
#pragma unroll
  for (int j = 0; j < 4; j++){
    int c = cbase + j * 16;
    if (c >= 150) continue;
#pragma unroll
    for (int r = 0; r < 4; r++){
      int row = rbase + r;
      if (row >= Nn) continue;
      float v = acc[j][r];
      float gg = 1.f / (1.f + expf(-(v + bias[c])));
      float o = gg * X2[(size_t)row * CHd + c] + (1.f - gg) * Xf[(size_t)row * 600 + c];
      outp[(size_t)row * 600 + c] = o;
      mir[(size_t)row * 600 + c] = f2b(o);
    }
  }
}

// batched per-node precompute for both gat_e calls: blockIdx.y = call g
__global__ __launch_bounds__(64) void k_ndots2b(const float* __restrict__ proj,
    const float* __restrict__ h2r_ac, const float* __restrict__ et_ac,
    unsigned short* __restrict__ xnb, float* __restrict__ pm,
    float* __restrict__ po, float* __restrict__ nv4){
  int n = blockIdx.x, g = blockIdx.y, lane = threadIdx.x;
  const float* ac = g ? et_ac : h2r_ac;
  const float* xm = proj + (g ? 300 : 150);
  const float* xo = proj + (g ? 450 : 0);
  const float* v2m = ac + (g ? 1 : 5) * CHd;
  const float* v2o = ac + (g ? 5 : 1) * CHd;
  const float* v3m = ac + (g ? 2 : 6) * CHd;
  const float* v3o = ac + (g ? 6 : 2) * CHd;
  const float* v4  = ac + 3 * CHd;
  bool m2 = lane < (CHd - 128);
  const float* mr = xm + (size_t)n * 600;
  const float* orw = xo + (size_t)n * 600;
  float m0 = mr[lane], m1 = mr[lane + 64], mv2 = m2 ? mr[lane + 128] : 0.f;
  float o0 = orw[lane], o1 = orw[lane + 64], o2 = m2 ? orw[lane + 128] : 0.f;
  float s[4];
  s[0] = m0 * m0 + m1 * m1 + mv2 * mv2;
  s[1] = o0 * v2o[lane] + o1 * v2o[lane + 64] + (m2 ? o2 * v2o[lane + 128] : 0.f);
  s[2] = o0 * v3o[lane] + o1 * v3o[lane + 64] + (m2 ? o2 * v3o[lane + 128] : 0.f);
  s[3] = o0 * v4[lane]  + o1 * v4[lane + 64]  + (m2 ? o2 * v4[lane + 128]  : 0.f);
  wredsumN<4>(s);
  float inv = 1.f / fmaxf(sqrtf(s[0]), 1e-12f);
  float n0 = m0 * inv, n1 = m1 * inv, n2 = mv2 * inv;
  unsigned short* xr = xnb + (size_t)g * Nn * 152 + (size_t)n * 152;
  xr[lane] = f2b(n0); xr[lane + 64] = f2b(n1);
  if (m2) xr[lane + 128] = f2b(n2);
  float d[2];
  d[0] = n0 * v2m[lane] + n1 * v2m[lane + 64] + (m2 ? n2 * v2m[lane + 128] : 0.f);
  d[1] = n0 * v3m[lane] + n1 * v3m[lane + 64] + (m2 ? n2 * v3m[lane + 128] : 0.f);
  wredsumN<2>(d);
  if (!lane){
    pm[g * Nn + n] = d[0] + 0.25f * d[1];
    po[g * Nn + n] = s[1] + 0.25f * s[2];
    nv4[g * Nn + n] = s[3];
  }
}

// batched per-edge exp-logit + LDS class sums/counts: blockIdx.y = call g
__global__ __launch_bounds__(256) void k_e2sumb(const int* __restrict__ ei,
    const int* __restrict__ rel, const int* __restrict__ cih, const int* __restrict__ cit,
    const float* __restrict__ pm, const float* __restrict__ po,
    const float* __restrict__ ra1h, const float* __restrict__ ra1e,
    float* __restrict__ es2, float* __restrict__ csum_p, int* __restrict__ ccnt_p){
  __shared__ float ls[Cc];
  __shared__ int lc[Cc];
  int t = threadIdx.x, g = blockIdx.y;
  const int* im = ei + (g ? 0 : Ee);
  const int* io = ei + (g ? Ee : 0);
  const int* ci = g ? cit : cih;
  const float* ra1 = g ? ra1e : ra1h;
  const float* pmg = pm + g * Nn;
  const float* pog = po + g * Nn;
  float* es2g = es2 + (size_t)g * Ee;
  float* csg = csum_p + g * Cc * 16;
  int* ccg = ccnt_p + g * Cc * 16;
  for (int c = t; c < Cc; c += 256){ ls[c] = 0.f; lc[c] = 0; }
  __syncthreads();
  for (int e = blockIdx.x * 256 + t; e < Ee; e += gridDim.x * 256){
    float v = lrelu01(pog[io[e]] + pmg[im[e]] + ra1[rel[e]]);
    float s = expf(v);
    es2g[e] = s;
    int c = ci[e];
    atomicAdd(&ls[c], s);
    atomicAdd(&lc[c], 1);
  }
  __syncthreads();
  for (int c = t; c < Cc; c += 256){
    if (lc[c]){
      atomicAdd(&csg[c * 16], ls[c]);
      atomicAdd(&ccg[c * 16], lc[c]);
    }
  }
}

__global__ __launch_bounds__(256) void k_cscanb(const int* __restrict__ ccnt_p,
    int* __restrict__ cstart, int* __restrict__ ccur_p){
  __shared__ int s[Cc + 1];
  int t = threadIdx.x, g = blockIdx.x;
  const int* ccg = ccnt_p + g * Cc * 16;
  int* csg = cstart + g * (Cc + 1);
  int* cug = ccur_p + g * Cc * 16;
  if (t == 0){
    int run = 0;
    for (int c = 0; c < Cc; c++){ s[c] = run; run += ccg[c * 16]; }
    s[Cc] = run;
  }
  __syncthreads();
  if (t <= Cc) csg[t] = s[t];
  if (t < Cc) cug[t * 16] = s[t];
}

__global__ __launch_bounds__(256) void k_cscatterb(const int* __restrict__ ei,
    const int* __restrict__ cih, const int* __restrict__ cit,
    const float* __restrict__ es2,
    int* __restrict__ ccur_p, int* __restrict__ crows, float* __restrict__ cw){
  __shared__ int lcnt[Cc];
  __shared__ int lbase[Cc];
  int t = threadIdx.x, g = blockIdx.y;
  const int* im = ei + (g ? 0 : Ee);
  const int* ci = g ? cit : cih;
  const float* es2g = es2 + (size_t)g * Ee;
  int* cug = ccur_p + g * Cc * 16;
  int* crg = crows + (size_t)g * Ee;
  float* cwg = cw + (size_t)g * Ee;
  int epb = (Ee + gridDim.x - 1) / gridDim.x;
  int e0 = blockIdx.x * epb, e1 = e0 + epb; if (e1 > Ee) e1 = Ee;
  for (int c = t; c < Cc; c += 256) lcnt[c] = 0;
  __syncthreads();
  int myr[4], myc[4], mye[4]; int cnt = 0;
  for (int e = e0 + t; e < e1; e += 256){
    int c = ci[e];
    myr[cnt] = atomicAdd(&lcnt[c], 1);
    myc[cnt] = c; mye[cnt] = e; cnt++;
  }
  __syncthreads();
  for (int c = t; c < Cc; c += 256)
    lbase[c] = lcnt[c] ? atomicAdd(&cug[c * 16], lcnt[c]) : 0;
  __syncthreads();
  for (int q = 0; q < cnt; q++){
    int pos = lbase[myc[q]] + myr[q];
    int e = mye[q];
    crg[pos] = im[im[e]];
    cwg[pos] = es2g[e];
  }
}

__global__ __launch_bounds__(192) void k_xclassBb(
    const int* __restrict__ cstart, const int* __restrict__ crows,
    const float* __restrict__ cw, const float* __restrict__ csum_p,
    const unsigned short* __restrict__ xnb, float* __restrict__ x_class){
  int g = blockIdx.y;
  int c = blockIdx.x / XSPL, sp = blockIdx.x % XSPL;
  int t = threadIdx.x;
  const int* csg = cstart + g * (Cc + 1);
  const int* crg = crows + (size_t)g * Ee;
  const float* cwg = cw + (size_t)g * Ee;
  const unsigned short* xng = xnb + (size_t)g * Nn * 152;
  float* xcg = x_class + g * Cc * CHd;
  int p0 = csg[c], p1 = csg[c + 1];
  int len = p1 - p0;
  if (len <= 0) return;
  int chunk = (len + XSPL - 1) / XSPL;
  int q0 = p0 + sp * chunk;
  int q1 = q0 + chunk; if (q1 > p1) q1 = p1;
  if (q0 >= q1) return;
  bool act = t < CHd;
  float inv = 1.f / csum_p[g * Cc * 16 + c * 16];
  float acc = 0.f;
  int k = q0;
  for (; k + 4 <= q1; k += 4){
    int r0 = crg[k], r1 = crg[k + 1], r2 = crg[k + 2], r3 = crg[k + 3];
    float w0 = cwg[k] * inv, w1 = cwg[k + 1] * inv, w2 = cwg[k + 2] * inv, w3 = cwg[k + 3] * inv;
    if (act){
      acc += w0 * b2f(xng[(size_t)r0 * 152 + t]) + w1 * b2f(xng[(size_t)r1 * 152 + t])
           + w2 * b2f(xng[(size_t)r2 * 152 + t]) + w3 * b2f(xng[(size_t)r3 * 152 + t]);
    }
  }
  for (; k < q1; k++){
    if (act) acc += cwg[k] * inv * b2f(xng[(size_t)crg[k] * 152 + t]);
  }
  if (act) atomicAdd(&xcg[c * CHd + t], acc);
}

__global__ __launch_bounds__(256) void k_classfinalb(
    const float* __restrict__ x_class,
    const float* __restrict__ h2r_ac, const float* __restrict__ et_ac,
    const float* __restrict__ nv4,
    const int* __restrict__ hcls, const int* __restrict__ tcls,
    float* __restrict__ outb){
  __shared__ float v[Cc];
  __shared__ float gm[Cc];
  __shared__ int ce[Cc];
  int t = threadIdx.x, g = blockIdx.x;
  const float* xcg = x_class + g * Cc * CHd;
  const float* acv = (g ? et_ac : h2r_ac) + 7 * CHd;
  const float* nvg = nv4 + g * Nn;
  const int* cls_ent = g ? tcls : hcls;
  float* obg = outb + (size_t)g * Nn * CHd;
  if (t < Cc){
    ce[t] = cls_ent[t];
    float dot = 0.f;
    for (int f = 0; f < CHd; f++) dot += xcg[t * CHd + f] * acv[f];
    v[t] = lrelu01(dot + nvg[ce[t]]);
  }
  __syncthreads();
  if (t < Cc){
    int sgm = ce[t];
    float m = -3.0e38f;
    for (int c2 = 0; c2 < Cc; c2++) if (ce[c2] == sgm) m = fmaxf(m, v[c2]);
    float sum = 0.f;
    for (int c2 = 0; c2 < Cc; c2++) if (ce[c2] == sgm) sum += expf(v[c2] - m);
    gm[t] = expf(v[t] - m) / sum;
  }
  __syncthreads();
  for (int idx = t; idx < Cc * CHd; idx += 256){
    int c = idx / CHd, f = idx - c * CHd;
    atomicAdd(&obg[(size_t)ce[c] * CHd + f], gm[c] * xcg[c * CHd + f]);
  }
}

__global__ __launch_bounds__(64) void k_s12(const unsigned short* __restrict__ x1b,
    const float* __restrict__ ai, const float* __restrict__ aj,
    float* __restrict__ s1, float* __restrict__ s2){
  int n = blockIdx.x, lane = threadIdx.x;
  const unsigned short* xr = x1b + (size_t)n * 600;
  float sa = 0.f, sb = 0.f;
#pragma unroll
  for (int u = 0; u < 10; u++){
    int f = lane + u * 64;
    if (f < 600){
      float x = b2f(xr[f]);
      sa += x * ai[f];
      sb += x * aj[f];
    }
  }
  float s[2] = { sa, sb };
  wredsumN<2>(s);
  if (!lane){ s1[n] = s[0]; s2[n] = s[1]; }
}

extern "C" void kernel_launch(void* const* d_in, const int* in_sizes, int n_in,
                              void* d_out, int out_size, void* d_ws, size_t ws_size,
                              hipStream_t stream) {
  const float* x_e    = (const float*)d_in[0];
  const int*   ei     = (const int*)d_in[1];
  const int*   rel    = (const int*)d_in[2];
  const int*   eall   = (const int*)d_in[3];
  const int*   cih    = (const int*)d_in[5];
  const int*   hcls   = (const int*)d_in[6];
  const int*   cit    = (const int*)d_in[7];
  const int*   tcls   = (const int*)d_in[8];
  const float* remb   = (const float*)d_in[9];
  const float* hw1w   = (const float*)d_in[10];
  const float* hw1b   = (const float*)d_in[11];
  const float* hw2w   = (const float*)d_in[12];
  const float* hw2b   = (const float*)d_in[13];
  const float* h2r_ac = (const float*)d_in[14];
  const float* h2r_ar = (const float*)d_in[15];
  const float* h2r_wh = (const float*)d_in[16];
  const float* h2r_wt = (const float*)d_in[17];
  const float* h2r_hww= (const float*)d_in[18];
  const float* h2r_hwb= (const float*)d_in[19];
  const float* et_ac  = (const float*)d_in[20];
  const float* et_ar  = (const float*)d_in[21];
  const float* et_wh  = (const float*)d_in[22];
  const float* et_wt  = (const float*)d_in[23];
  const float* et_hww = (const float*)d_in[24];
  const float* et_hwb = (const float*)d_in[25];
  const float* gai    = (const float*)d_in[26];
  const float* gaj    = (const float*)d_in[27];
  float* out = (float*)d_out;

  // ---- workspace allocator ----
  char* wsp = (char*)d_ws;
  auto alloc = [&](size_t nbytes) -> void* {
    void* p = (void*)wsp;
    wsp += (nbytes + 255) & ~(size_t)255;
    return p;
  };
  float* ra1h = (float*)alloc(Rr * 4);
  float* ra1e = (float*)alloc(Rr * 4);
  float* dis  = (float*)alloc(Nn * 4);
  int* degi    = (int*)alloc(Nn * 4);
  int* csr_ptr = (int*)alloc((Nn + 1) * 4);
  int* csr_cur = (int*)alloc(Nn * 4);
  int* csr_src = (int*)alloc((size_t)EALLe * 4);
  float* x1  = (float*)alloc((size_t)Nn * 600 * 4);
  float* es2 = (float*)alloc((size_t)2 * Ee * 4);
  float* pm  = (float*)alloc(2 * Nn * 4);
  float* po  = (float*)alloc(2 * Nn * 4);
  float* nv4 = (float*)alloc(2 * Nn * 4);
  // contiguous zero-init region: csum_p, ccnt_p, x_class
  float* csum_p = (float*)alloc(2 * Cc * 16 * 4);
  int*   ccnt_p = (int*)alloc(2 * Cc * 16 * 4);
  float* x_class = (float*)alloc(2 * Cc * CHd * 4);
  size_t zregion = (size_t)((char*)x_class + ((2 * Cc * CHd * 4 + 255) & ~255)) - (size_t)(char*)csum_p;
  int*   ccur_p = (int*)alloc(2 * Cc * 16 * 4);
  int*   cstart = (int*)alloc(2 * (Cc + 1) * 4);
  int*   crows  = (int*)alloc((size_t)2 * Ee * 4);
  float* cw     = (float*)alloc((size_t)2 * Ee * 4);
  float* s1v = (float*)alloc(Nn * 4);
  float* s2v = (float*)alloc(Nn * 4);
  unsigned short* arenaA = (unsigned short*)alloc((size_t)Nn * 320 * 2);
  unsigned short* arenaB = (unsigned short*)alloc((size_t)Nn * 320 * 2);
  unsigned short* x1b    = (unsigned short*)alloc(((size_t)Nn * 600 + 64) * 2);
  unsigned short* w1b    = (unsigned short*)alloc((size_t)300 * 320 * 2);
  unsigned short* w2b    = (unsigned short*)alloc((size_t)300 * 320 * 2);
  unsigned short* wcatb  = (unsigned short*)alloc((size_t)600 * 320 * 2);
  unsigned short* hwwbA  = (unsigned short*)alloc((size_t)150 * 160 * 2);
  unsigned short* hwwbB  = (unsigned short*)alloc((size_t)150 * 160 * 2);
  // aliases over dead arenas (dead after the two main GEMMs consume them):
  unsigned short* xob = arenaA;   // 2 x Nn x 160 bf16 = 12.8 MB, fits arenaA
  unsigned short* xnb = arenaB;   // 2 x Nn x 152 bf16 = 12.2 MB, fits arenaB

  // d_out staging layout (all dead before k_gat3 rewrites d_out)
  float* h1   = out;
  float* gbuf = out + (size_t)Nn * EHd;
  float* proj = out;
  float* outb = out + (size_t)Nn * 600;   // 2 x Nn x 150 f32 = region 600N..900N

  // ---- prologue ----
  hipMemsetAsync(degi, 0, Nn * 4, stream);
  hipMemsetAsync(csum_p, 0, zregion, stream);
  hipMemsetAsync(outb, 0, (size_t)2 * Nn * CHd * 4, stream);
  k_rnorm<<<Rr, 64, 0, stream>>>(remb, h2r_ar, et_ar, ra1h, ra1e);
  k_count<<<cdiv_h(EALLe, 256), 256, 0, stream>>>(eall + EALLe, degi);
  k_dis<<<cdiv_h(Nn, 256), 256, 0, stream>>>(degi, dis);
  k_scan<<<1, 1024, 0, stream>>>(degi, csr_ptr, csr_cur);
  k_scatter<<<cdiv_h(EALLe, 256), 256, 0, stream>>>(eall, eall + EALLe, csr_cur, csr_src);
  k_f2b<<<300, 64, 0, stream>>>(hw1w, 300, 300, w1b, 320);
  k_f2b<<<300, 64, 0, stream>>>(hw2w, 300, 300, w2b, 320);
  k_f2b<<<150, 64, 0, stream>>>(h2r_wh, 300, 300, wcatb + (size_t)0   * 320, 320);
  k_f2b<<<150, 64, 0, stream>>>(h2r_wt, 300, 300, wcatb + (size_t)150 * 320, 320);
  k_f2b<<<150, 64, 0, stream>>>(et_wh,  300, 300, wcatb + (size_t)300 * 320, 320);
  k_f2b<<<150, 64, 0, stream>>>(et_wt,  300, 300, wcatb + (size_t)450 * 320, 320);
  k_f2b<<<150, 64, 0, stream>>>(h2r_hww, 150, 150, hwwbA, 160);
  k_f2b<<<150, 64, 0, stream>>>(et_hww,  150, 150, hwwbB, 160);
  k_f2b<<<Nn, 64, 0, stream>>>(x_e, 300, 300, arenaA, 320);

  // ---- GCN + highway x2 ----
  k_gcnb<<<Nn, 64, 0, stream>>>(arenaA, 320, csr_ptr, csr_src, dis, gbuf);
  k_gemmb<1,1><<<dim3(5, cdiv_h(Nn, 64)), 256, 0, stream>>>(
      arenaA, 320, Nn, w1b, 320, 300, hw1b, gbuf, 300, x_e, 300, h1, 300, arenaB, 320);
  k_gcnb<<<Nn, 64, 0, stream>>>(arenaB, 320, csr_ptr, csr_src, dis, gbuf);
  k_gemmb<1,1><<<dim3(5, cdiv_h(Nn, 64)), 256, 0, stream>>>(
      arenaB, 320, Nn, w2b, 320, 300, hw2b, gbuf, 300, h1, 300, x1, 600, x1b, 600);

  // ---- batched projections: [xh_A | xt_A | xh_B | xt_B] = relu(x @ wcat^T) ----
  // (arenaA/arenaB become dead here; xob/xnb aliases become live below)
  k_gemmb<0,0><<<dim3(10, cdiv_h(Nn, 64)), 256, 0, stream>>>(
      x1b, 600, Nn, wcatb, 320, 600, nullptr, nullptr, 0, nullptr, 0, proj, 600,
      nullptr, 0);

  // ---- gat_e: both calls batched per kernel ----
  k_f2bxo<<<dim3(Nn, 2), 64, 0, stream>>>(proj, xob);
  k_ndots2b<<<dim3(Nn, 2), 64, 0, stream>>>(proj, h2r_ac, et_ac, xnb, pm, po, nv4);
  k_e2sumb<<<dim3(CB, 2), 256, 0, stream>>>(ei, rel, cih, cit, pm, po, ra1h, ra1e,
                                            es2, csum_p, ccnt_p);
  k_cscanb<<<2, 256, 0, stream>>>(ccnt_p, cstart, ccur_p);
  k_cscatterb<<<dim3(CB, 2), 256, 0, stream>>>(ei, cih, cit, es2, ccur_p, crows, cw);
  k_xclassBb<<<dim3(Cc * XSPL, 2), 192, 0, stream>>>(cstart, crows, cw, csum_p,
                                                     xnb, x_class);
  k_classfinalb<<<2, 256, 0, stream>>>(x_class, h2r_ac, et_ac, nv4, hcls, tcls, outb);
  k_hwgemm<<<dim3(3, cdiv_h(Nn, 64), 2), 256, 0, stream>>>(
      xob, hwwbA, hwwbB, h2r_hwb, et_hwb, outb, proj, x1, x1b);

  // ---- final GAT ----
  k_s12<<<Nn, 64, 0, stream>>>(x1b, gai, gaj, s1v, s2v);
  k_gat3<<<Nn, 256, 0, stream>>>(x1, x1b, csr_ptr, csr_src, s1v, s2v, out);
}

// Round 13
// 525.726 us; speedup vs baseline: 1.5340x; 1.0446x over previous
//
#include <hip/hip_runtime.h>
#include <math.h>

#define Nn 20000
#define Ee 120000
#define EALLe 240000
#define Cc 150
#define Rr 1000
#define EHd 300
#define RHd 100
#define CHd 150
#define CB 128
#define XSPL 16

static inline int cdiv_h(int a, int b){ return (a + b - 1) / b; }

typedef __attribute__((ext_vector_type(8))) short short8;
typedef __attribute__((ext_vector_type(4))) float f32x4;

__device__ __forceinline__ float lrelu01(float x){ return x > 0.f ? x : 0.01f * x; }

__device__ __forceinline__ unsigned short f2b(float f){
  unsigned int u = __float_as_uint(f);
  unsigned int r = (u + 0x7FFFu + ((u >> 16) & 1u)) >> 16;
  return (unsigned short)r;
}
__device__ __forceinline__ float b2f(unsigned short u){
  return __uint_as_float(((unsigned int)u) << 16);
}
__device__ __forceinline__ float b2f_lo(unsigned int u){
  return __uint_as_float(u << 16);
}
__device__ __forceinline__ float b2f_hi(unsigned int u){
  return __uint_as_float(u & 0xFFFF0000u);
}

template<int Kq>
__device__ __forceinline__ void wredsumN(float* v){
#pragma unroll
  for (int m = 32; m >= 1; m >>= 1){
#pragma unroll
    for (int k = 0; k < Kq; k++) v[k] += __shfl_xor(v[k], m, 64);
  }
}

// f32 [rows, ncols] (ld ldsrc) -> bf16 [rows, ldp], zero-padded cols ncols..ldp
__global__ __launch_bounds__(64) void k_f2b(const float* __restrict__ src, int ncols,
    int ldsrc, unsigned short* __restrict__ dst, int ldp){
  int r = blockIdx.x, t = threadIdx.x;
  for (int c = t; c < ldp; c += 64)
    dst[(size_t)r * ldp + c] = (c < ncols) ? f2b(src[(size_t)r * ldsrc + c]) : (unsigned short)0;
}

// batched weight conversion: 8 matrices in one launch via descriptor struct
struct Cvt8 {
  const float* s[8];
  unsigned short* d[8];
  int nc[8]; int lds[8]; int ldp[8]; int r0[9];
};
__global__ __launch_bounds__(64) void k_f2ball(Cvt8 c){
  int b = blockIdx.x, t = threadIdx.x;
  int idx = 0;
#pragma unroll
  for (int q = 1; q < 8; q++) if (b >= c.r0[q]) idx = q;
  int r = b - c.r0[idx];
  const float* src = c.s[idx] + (size_t)r * c.lds[idx];
  unsigned short* dst = c.d[idx] + (size_t)r * c.ldp[idx];
  int nc = c.nc[idx], ldp = c.ldp[idx];
  for (int col = t; col < ldp; col += 64)
    dst[col] = (col < nc) ? f2b(src[col]) : (unsigned short)0;
}

__global__ __launch_bounds__(64) void k_rnorm(const float* __restrict__ rt,
    const float* __restrict__ arh, const float* __restrict__ are,
    float* __restrict__ ra1h, float* __restrict__ ra1e){
  int r = blockIdx.x, lane = threadIdx.x;
  bool m1 = (lane + 64 < RHd);
  float v0 = rt[r * RHd + lane];
  float v1 = m1 ? rt[r * RHd + lane + 64] : 0.f;
  float s[3];
  s[0] = v0 * v0 + v1 * v1;
  s[1] = v0 * arh[RHd + lane] + (m1 ? v1 * arh[RHd + lane + 64] : 0.f);
  s[2] = v0 * are[RHd + lane] + (m1 ? v1 * are[RHd + lane + 64] : 0.f);
  wredsumN<3>(s);
  float inv = 0.5f / fmaxf(sqrtf(s[0]), 1e-12f);
  if (!lane){
    ra1h[r] = s[1] * inv;
    ra1e[r] = s[2] * inv;
  }
}

__global__ void k_count(const int* __restrict__ dst, int* __restrict__ degi){
  int e = blockIdx.x * blockDim.x + threadIdx.x;
  if (e < EALLe) atomicAdd(&degi[dst[e]], 1);
}

// exclusive scan of degi -> csr_ptr + cursor copy + fused dis = deg^-1/2
__global__ __launch_bounds__(1024) void k_scan(const int* __restrict__ degi,
    int* __restrict__ ptr, int* __restrict__ cur, float* __restrict__ dis){
  __shared__ int s[1024];
  int t = threadIdx.x;
  const int per = (Nn + 1023) / 1024;
  int b0 = t * per; if (b0 > Nn) b0 = Nn;
  int b1 = b0 + per; if (b1 > Nn) b1 = Nn;
  int sum = 0;
  for (int i = b0; i < b1; i++) sum += degi[i];
  s[t] = sum;
  __syncthreads();
  for (int off = 1; off < 1024; off <<= 1){
    int v = (t >= off) ? s[t - off] : 0;
    __syncthreads();
    s[t] += v;
    __syncthreads();
  }
  int run = (t > 0) ? s[t - 1] : 0;
  for (int i = b0; i < b1; i++){
    int dg = degi[i];
    ptr[i] = run; cur[i] = run; run += dg;
    dis[i] = dg > 0 ? rsqrtf((float)dg) : 0.f;
  }
  if (t == 1023) ptr[Nn] = s[1023];
}

__global__ void k_scatter(const int* __restrict__ src, const int* __restrict__ dst,
    int* __restrict__ cur, int* __restrict__ csr_src){
  int e = blockIdx.x * blockDim.x + threadIdx.x;
  if (e >= EALLe) return;
  int pos = atomicAdd(&cur[dst[e]], 1);
  csr_src[pos] = src[e];
}

// GCN SpMM + relu, dword (2xbf16) gathers: lane owns dwords lane, lane+64,
// and (lane<22) lane+128 of the 160-dword row (300 cols live).
__global__ __launch_bounds__(64) void k_gcnb(const unsigned short* __restrict__ x,
    const int* __restrict__ ptr, const int* __restrict__ src,
    const float* __restrict__ dis, float* __restrict__ out){
  int i = blockIdx.x, lane = threadIdx.x;
  int p0 = ptr[i], p1 = ptr[i + 1];
  float di = dis[i];
  bool m2 = lane < 22;
  float a0 = 0.f, a1 = 0.f, b0 = 0.f, b1 = 0.f, c0 = 0.f, c1 = 0.f;
  for (int k = p0; k < p1; k++){
    int j = src[k];
    float w = di * dis[j];
    const unsigned int* xr = (const unsigned int*)(x + (size_t)j * 320);
    unsigned int u0 = xr[lane];
    unsigned int u1 = xr[lane + 64];
    a0 += w * b2f_lo(u0); a1 += w * b2f_hi(u0);
    b0 += w * b2f_lo(u1); b1 += w * b2f_hi(u1);
    if (m2){
      unsigned int u2 = xr[lane + 128];
      c0 += w * b2f_lo(u2); c1 += w * b2f_hi(u2);
    }
  }
  float* orow = out + (size_t)i * EHd;
  orow[2 * lane]       = fmaxf(a0, 0.f);
  orow[2 * lane + 1]   = fmaxf(a1, 0.f);
  orow[128 + 2 * lane]     = fmaxf(b0, 0.f);
  orow[128 + 2 * lane + 1] = fmaxf(b1, 0.f);
  if (m2){
    orow[256 + 2 * lane]     = fmaxf(c0, 0.f);
    orow[256 + 2 * lane + 1] = fmaxf(c1, 0.f);
  }
}

// final GAT: fused x-copy + in-LDS edge weights + dword bf16 gathers.
__global__ __launch_bounds__(256) void k_gat3(const float* __restrict__ x1,
    const unsigned short* __restrict__ x1b,
    const int* __restrict__ ptr, const int* __restrict__ src,
    const float* __restrict__ s1, const float* __restrict__ s2,
    float* __restrict__ dout){
  __shared__ float wl[128];
  __shared__ int jl[128];
  int i = blockIdx.x, t = threadIdx.x;
  float* orow = dout + (size_t)i * 900;
  const float* xi = x1 + (size_t)i * 600;
  if (t < 75) ((f32x4*)orow)[t] = ((const f32x4*)xi)[t];
  int p0 = ptr[i], p1 = ptr[i + 1];
  if (p0 == p1){
    for (int f = t; f < 600; f += 256) orow[300 + f] = 0.f;
    return;
  }
  float s1i = s1[i];
  bool m2 = t < 44;
  float a0 = 0.f, a1 = 0.f, c0 = 0.f, c1 = 0.f, den = 0.f;
  for (int base = p0; base < p1; base += 128){
    int k = base + t;
    if (t < 128 && k < p1){
      int j = src[k];
      jl[t] = j;
      wl[t] = expf(lrelu01(s1i + s2[j]));
    }
    __syncthreads();
    int lim = p1 - base; if (lim > 128) lim = 128;
    for (int q = 0; q < lim; q++){
      float w = wl[q];
      den += w;
      const unsigned short* xj = x1b + (size_t)jl[q] * 600;
      unsigned int u = *(const unsigned int*)&xj[2 * t];
      a0 += w * b2f_lo(u);
      a1 += w * b2f_hi(u);
      if (m2){
        unsigned int v = *(const unsigned int*)&xj[512 + 2 * t];
        c0 += w * b2f_lo(v);
        c1 += w * b2f_hi(v);
      }
    }
    __syncthreads();
  }
  float invd = 1.f / den;
  orow[300 + 2 * t] = fmaxf(a0 * invd, 0.f);
  orow[300 + 2 * t + 1] = fmaxf(a1 * invd, 0.f);
  if (m2){
    orow[300 + 512 + 2 * t] = fmaxf(c0 * invd, 0.f);
    orow[300 + 512 + 2 * t + 1] = fmaxf(c1 * invd, 0.f);
  }
}

// bf16 MFMA GEMM: out = epi( Xb[nrows,Kp]bf16 @ Wb[M,Kp]bf16^T ).
template<int EPI, int MIR>
__global__ __launch_bounds__(256) void k_gemmb(
    const unsigned short* __restrict__ Xb, int ldxb, int nrows,
    const unsigned short* __restrict__ Wb, int Kp, int M,
    const float* __restrict__ bias,
    const float* __restrict__ X2, int ldx2,
    const float* __restrict__ Xf, int ldxf,
    float* __restrict__ out, int ldo,
    unsigned short* __restrict__ mir, int ldmir){
  __shared__ unsigned short Xs[64][40];
  __shared__ unsigned short Ws[64][40];
  int t = threadIdx.x;
  int wv = t >> 6, lane = t & 63;
  int c0 = blockIdx.x * 64, r0 = blockIdx.y * 64;
  int srow = t >> 2, skoff = (t & 3) * 8;
  int gxr = r0 + srow, gwr = c0 + srow;
  f32x4 acc[4] = {};
  for (int k0 = 0; k0 < Kp; k0 += 32){
    short8 xv = {0,0,0,0,0,0,0,0};
    short8 wv8 = {0,0,0,0,0,0,0,0};
    if (gxr < nrows) xv = *(const short8*)&Xb[(size_t)gxr * ldxb + k0 + skoff];
    if (gwr < M)     wv8 = *(const short8*)&Wb[(size_t)gwr * Kp + k0 + skoff];
    __syncthreads();
    *(short8*)&Xs[srow][skoff] = xv;
    *(short8*)&Ws[srow][skoff] = wv8;
    __syncthreads();
    int arow = wv * 16 + (lane & 15);
    int kk = (lane >> 4) * 8;
    short8 af = *(const short8*)&Xs[arow][kk];
#pragma unroll
    for (int j = 0; j < 4; j++){
      short8 bf = *(const short8*)&Ws[j * 16 + (lane & 15)][kk];
      acc[j] = __builtin_amdgcn_mfma_f32_16x16x32_bf16(af, bf, acc[j], 0, 0, 0);
    }
  }
  int rbase = r0 + wv * 16 + (lane >> 4) * 4;
  int cbase = c0 + (lane & 15);
#pragma unroll
  for (int j = 0; j < 4; j++){
    int c = cbase + j * 16;
    if (c >= M) continue;
#pragma unroll
    for (int r = 0; r < 4; r++){
      int row = rbase + r;
      if (row >= nrows) continue;
      float v = acc[j][r];
      float o;
      if (EPI == 0){
        o = fmaxf(v, 0.f);
      } else {
        float g = 1.f / (1.f + expf(-(v + bias[c])));
        o = g * X2[(size_t)row * ldx2 + c] + (1.f - g) * Xf[(size_t)row * ldxf + c];
      }
      out[(size_t)row * ldo + c] = o;
      if (MIR) mir[(size_t)row * ldmir + c] = f2b(o);
    }
  }
}

// batched gat_e highway GEMM: blockIdx.z = call g
__global__ __launch_bounds__(256) void k_hwgemm(
    const unsigned short* __restrict__ xob,
    const unsigned short* __restrict__ hwwbA, const unsigned short* __restrict__ hwwbB,
    const float* __restrict__ hwbA, const float* __restrict__ hwbB,
    const float* __restrict__ outb, const float* __restrict__ proj,
    float* __restrict__ x1, unsigned short* __restrict__ x1b){
  __shared__ unsigned short Xs[64][40];
  __shared__ unsigned short Ws[64][40];
  int g = blockIdx.z;
  const unsigned short* Xb = xob + (size_t)g * Nn * 160;
  const unsigned short* Wb = g ? hwwbB : hwwbA;
  const float* bias = g ? hwbB : hwbA;
  const float* X2 = outb + (size_t)g * Nn * CHd;
  const float* Xf = proj + (g ? 450 : 0);
  float* outp = x1 + (g ? 450 : 300);
  unsigned short* mir = x1b + (g ? 450 : 300);
  int t = threadIdx.x;
  int wv = t >> 6, lane = t & 63;
  int c0 = blockIdx.x * 64, r0 = blockIdx.y * 64;
  int srow = t >> 2, skoff = (t & 3) * 8;
  int gxr = r0 + srow, gwr = c0 + srow;
  f32x4 acc[4] = {};
  for (int k0 = 0; k0 < 160; k0 += 32){
    short8 xv = {0,0,0,0,0,0,0,0};
    short8 wv8 = {0,0,0,0,0,0,0,0};
    if (gxr < Nn) xv = *(const short8*)&Xb[(size_t)gxr * 160 + k0 + skoff];
    if (gwr < 150) wv8 = *(const short8*)&Wb[(size_t)gwr * 160 + k0 + skoff];
    __syncthreads();
    *(short8*)&Xs[srow][skoff] = xv;
    *(short8*)&Ws[srow][skoff] = wv8;
    __syncthreads();
    int arow = wv * 16 + (lane & 15);
    int kk = (lane >> 4) * 8;
    short8 af = *(const short8*)&Xs[arow][kk];
#pragma unroll
    for (int j = 0; j < 4; j++){
      short8 bf = *(const short8*)&Ws[j * 16 + (lane & 15)][kk];
      acc[j] = __builtin_amdgcn_mfma_f32_16x16x32_bf16(af, bf, acc[j], 0, 0, 0);
    }
  }
  int rbase = r0 + wv * 16 + (lane >> 4) * 4;
  int cbase = c0 + (lane & 15);
#pragma unroll
  for (int j = 0; j < 4; j++){
    int c = cbase + j * 16;
    if (c >= 150) continue;
#pragma unroll
    for (int r = 0; r < 4; r++){
      int row = rbase + r;
      if (row >= Nn) continue;
      float v = acc[j][r];
      float gg = 1.f / (1.f + expf(-(v + bias[c])));
      float o = gg * X2[(size_t)row * CHd + c] + (1.f - gg) * Xf[(size_t)row * 600 + c];
      outp[(size_t)row * 600 + c] = o;
      mir[(size_t)row * 600 + c] = f2b(o);
    }
  }
}

// batched per-node precompute for both gat_e calls + fused xo->bf16 mirror
__global__ __launch_bounds__(64) void k_ndots2b(const float* __restrict__ proj,
    const float* __restrict__ h2r_ac, const float* __restrict__ et_ac,
    unsigned short* __restrict__ xob,
    unsigned short* __restrict__ xnb, float* __restrict__ pm,
    float* __restrict__ po, float* __restrict__ nv4){
  int n = blockIdx.x, g = blockIdx.y, lane = threadIdx.x;
  const float* ac = g ? et_ac : h2r_ac;
  const float* xm = proj + (g ? 300 : 150);
  const float* xo = proj + (g ? 450 : 0);
  const float* v2m = ac + (g ? 1 : 5) * CHd;
  const float* v2o = ac + (g ? 5 : 1) * CHd;
  const float* v3m = ac + (g ? 2 : 6) * CHd;
  const float* v3o = ac + (g ? 6 : 2) * CHd;
  const float* v4  = ac + 3 * CHd;
  bool m2 = lane < (CHd - 128);
  const float* mr = xm + (size_t)n * 600;
  const float* orw = xo + (size_t)n * 600;
  float m0 = mr[lane], m1 = mr[lane + 64], mv2 = m2 ? mr[lane + 128] : 0.f;
  float o0 = orw[lane], o1 = orw[lane + 64], o2 = m2 ? orw[lane + 128] : 0.f;
  // fused xo -> bf16 (xob row, 160-padded)
  unsigned short* xod = xob + (size_t)g * Nn * 160 + (size_t)n * 160;
  xod[lane] = f2b(o0);
  xod[lane + 64] = f2b(o1);
  if (m2) xod[lane + 128] = f2b(o2);
  if (lane < 10) xod[150 + lane] = 0;
  float s[4];
  s[0] = m0 * m0 + m1 * m1 + mv2 * mv2;
  s[1] = o0 * v2o[lane] + o1 * v2o[lane + 64] + (m2 ? o2 * v2o[lane + 128] : 0.f);
  s[2] = o0 * v3o[lane] + o1 * v3o[lane + 64] + (m2 ? o2 * v3o[lane + 128] : 0.f);
  s[3] = o0 * v4[lane]  + o1 * v4[lane + 64]  + (m2 ? o2 * v4[lane + 128]  : 0.f);
  wredsumN<4>(s);
  float inv = 1.f / fmaxf(sqrtf(s[0]), 1e-12f);
  float n0 = m0 * inv, n1 = m1 * inv, n2 = mv2 * inv;
  unsigned short* xr = xnb + (size_t)g * Nn * 152 + (size_t)n * 152;
  xr[lane] = f2b(n0); xr[lane + 64] = f2b(n1);
  if (m2) xr[lane + 128] = f2b(n2);
  float d[2];
  d[0] = n0 * v2m[lane] + n1 * v2m[lane + 64] + (m2 ? n2 * v2m[lane + 128] : 0.f);
  d[1] = n0 * v3m[lane] + n1 * v3m[lane + 64] + (m2 ? n2 * v3m[lane + 128] : 0.f);
  wredsumN<2>(d);
  if (!lane){
    pm[g * Nn + n] = d[0] + 0.25f * d[1];
    po[g * Nn + n] = s[1] + 0.25f * s[2];
    nv4[g * Nn + n] = s[3];
  }
}

// batched per-edge exp-logit + LDS class sums/counts: blockIdx.y = call g
__global__ __launch_bounds__(256) void k_e2sumb(const int* __restrict__ ei,
    const int* __restrict__ rel, const int* __restrict__ cih, const int* __restrict__ cit,
    const float* __restrict__ pm, const float* __restrict__ po,
    const float* __restrict__ ra1h, const float* __restrict__ ra1e,
    float* __restrict__ es2, float* __restrict__ csum_p, int* __restrict__ ccnt_p){
  __shared__ float ls[Cc];
  __shared__ int lc[Cc];
  int t = threadIdx.x, g = blockIdx.y;
  const int* im = ei + (g ? 0 : Ee);
  const int* io = ei + (g ? Ee : 0);
  const int* ci = g ? cit : cih;
  const float* ra1 = g ? ra1e : ra1h;
  const float* pmg = pm + g * Nn;
  const float* pog = po + g * Nn;
  float* es2g = es2 + (size_t)g * Ee;
  float* csg = csum_p + g * Cc * 16;
  int* ccg = ccnt_p + g * Cc * 16;
  for (int c = t; c < Cc; c += 256){ ls[c] = 0.f; lc[c] = 0; }
  __syncthreads();
  for (int e = blockIdx.x * 256 + t; e < Ee; e += gridDim.x * 256){
    float v = lrelu01(pog[io[e]] + pmg[im[e]] + ra1[rel[e]]);
    float s = expf(v);
    es2g[e] = s;
    int c = ci[e];
    atomicAdd(&ls[c], s);
    atomicAdd(&lc[c], 1);
  }
  __syncthreads();
  for (int c = t; c < Cc; c += 256){
    if (lc[c]){
      atomicAdd(&csg[c * 16], ls[c]);
      atomicAdd(&ccg[c * 16], lc[c]);
    }
  }
}

__global__ __launch_bounds__(256) void k_cscanb(const int* __restrict__ ccnt_p,
    int* __restrict__ cstart, int* __restrict__ ccur_p){
  __shared__ int s[Cc + 1];
  int t = threadIdx.x, g = blockIdx.x;
  const int* ccg = ccnt_p + g * Cc * 16;
  int* csg = cstart + g * (Cc + 1);
  int* cug = ccur_p + g * Cc * 16;
  if (t == 0){
    int run = 0;
    for (int c = 0; c < Cc; c++){ s[c] = run; run += ccg[c * 16]; }
    s[Cc] = run;
  }
  __syncthreads();
  if (t <= Cc) csg[t] = s[t];
  if (t < Cc) cug[t * 16] = s[t];
}

__global__ __launch_bounds__(256) void k_cscatterb(const int* __restrict__ ei,
    const int* __restrict__ cih, const int* __restrict__ cit,
    const float* __restrict__ es2,
    int* __restrict__ ccur_p, int* __restrict__ crows, float* __restrict__ cw){
  __shared__ int lcnt[Cc];
  __shared__ int lbase[Cc];
  int t = threadIdx.x, g = blockIdx.y;
  const int* im = ei + (g ? 0 : Ee);
  const int* ci = g ? cit : cih;
  const float* es2g = es2 + (size_t)g * Ee;
  int* cug = ccur_p + g * Cc * 16;
  int* crg = crows + (size_t)g * Ee;
  float* cwg = cw + (size_t)g * Ee;
  int epb = (Ee + gridDim.x - 1) / gridDim.x;
  int e0 = blockIdx.x * epb, e1 = e0 + epb; if (e1 > Ee) e1 = Ee;
  for (int c = t; c < Cc; c += 256) lcnt[c] = 0;
  __syncthreads();
  int myr[4], myc[4], mye[4]; int cnt = 0;
  for (int e = e0 + t; e < e1; e += 256){
    int c = ci[e];
    myr[cnt] = atomicAdd(&lcnt[c], 1);
    myc[cnt] = c; mye[cnt] = e; cnt++;
  }
  __syncthreads();
  for (int c = t; c < Cc; c += 256)
    lbase[c] = lcnt[c] ? atomicAdd(&cug[c * 16], lcnt[c]) : 0;
  __syncthreads();
  for (int q = 0; q < cnt; q++){
    int pos = lbase[myc[q]] + myr[q];
    int e = mye[q];
    crg[pos] = im[im[e]];
    cwg[pos] = es2g[e];
  }
}

__global__ __launch_bounds__(192) void k_xclassBb(
    const int* __restrict__ cstart, const int* __restrict__ crows,
    const float* __restrict__ cw, const float* __restrict__ csum_p,
    const unsigned short* __restrict__ xnb, float* __restrict__ x_class){
  int g = blockIdx.y;
  int c = blockIdx.x / XSPL, sp = blockIdx.x % XSPL;
  int t = threadIdx.x;
  const int* csg = cstart + g * (Cc + 1);
  const int* crg = crows + (size_t)g * Ee;
  const float* cwg = cw + (size_t)g * Ee;
  const unsigned short* xng = xnb + (size_t)g * Nn * 152;
  float* xcg = x_class + g * Cc * CHd;
  int p0 = csg[c], p1 = csg[c + 1];
  int len = p1 - p0;
  if (len <= 0) return;
  int chunk = (len + XSPL - 1) / XSPL;
  int q0 = p0 + sp * chunk;
  int q1 = q0 + chunk; if (q1 > p1) q1 = p1;
  if (q0 >= q1) return;
  bool act = t < CHd;
  float inv = 1.f / csum_p[g * Cc * 16 + c * 16];
  float acc = 0.f;
  int k = q0;
  for (; k + 4 <= q1; k += 4){
    int r0 = crg[k], r1 = crg[k + 1], r2 = crg[k + 2], r3 = crg[k + 3];
    float w0 = cwg[k] * inv, w1 = cwg[k + 1] * inv, w2 = cwg[k + 2] * inv, w3 = cwg[k + 3] * inv;
    if (act){
      acc += w0 * b2f(xng[(size_t)r0 * 152 + t]) + w1 * b2f(xng[(size_t)r1 * 152 + t])
           + w2 * b2f(xng[(size_t)r2 * 152 + t]) + w3 * b2f(xng[(size_t)r3 * 152 + t]);
    }
  }
  for (; k < q1; k++){
    if (act) acc += cwg[k] * inv * b2f(xng[(size_t)crg[k] * 152 + t]);
  }
  if (act) atomicAdd(&xcg[c * CHd + t], acc);
}

__global__ __launch_bounds__(256) void k_classfinalb(
    const float* __restrict__ x_class,
    const float* __restrict__ h2r_ac, const float* __restrict__ et_ac,
    const float* __restrict__ nv4,
    const int* __restrict__ hcls, const int* __restrict__ tcls,
    float* __restrict__ outb){
  __shared__ float v[Cc];
  __shared__ float gm[Cc];
  __shared__ int ce[Cc];
  int t = threadIdx.x, g = blockIdx.x;
  const float* xcg = x_class + g * Cc * CHd;
  const float* acv = (g ? et_ac : h2r_ac) + 7 * CHd;
  const float* nvg = nv4 + g * Nn;
  const int* cls_ent = g ? tcls : hcls;
  float* obg = outb + (size_t)g * Nn * CHd;
  if (t < Cc){
    ce[t] = cls_ent[t];
    float dot = 0.f;
    for (int f = 0; f < CHd; f++) dot += xcg[t * CHd + f] * acv[f];
    v[t] = lrelu01(dot + nvg[ce[t]]);
  }
  __syncthreads();
  if (t < Cc){
    int sgm = ce[t];
    float m = -3.0e38f;
    for (int c2 = 0; c2 < Cc; c2++) if (ce[c2] == sgm) m = fmaxf(m, v[c2]);
    float sum = 0.f;
    for (int c2 = 0; c2 < Cc; c2++) if (ce[c2] == sgm) sum += expf(v[c2] - m);
    gm[t] = expf(v[t] - m) / sum;
  }
  __syncthreads();
  for (int idx = t; idx < Cc * CHd; idx += 256){
    int c = idx / CHd, f = idx - c * CHd;
    atomicAdd(&obg[(size_t)ce[c] * CHd + f], gm[c] * xcg[c * CHd + f]);
  }
}

// per node dot of x1b row with gat_ai / gat_aj — dword loads
__global__ __launch_bounds__(64) void k_s12(const unsigned short* __restrict__ x1b,
    const float* __restrict__ ai, const float* __restrict__ aj,
    float* __restrict__ s1, float* __restrict__ s2){
  int n = blockIdx.x, lane = threadIdx.x;
  const unsigned int* xr = (const unsigned int*)(x1b + (size_t)n * 600);
  float sa = 0.f, sb = 0.f;
#pragma unroll
  for (int u = 0; u < 5; u++){
    int d = lane + u * 64;
    if (d < 300){
      unsigned int w = xr[d];
      float xlo = b2f_lo(w), xhi = b2f_hi(w);
      sa += xlo * ai[2 * d] + xhi * ai[2 * d + 1];
      sb += xlo * aj[2 * d] + xhi * aj[2 * d + 1];
    }
  }
  float s[2] = { sa, sb };
  wredsumN<2>(s);
  if (!lane){ s1[n] = s[0]; s2[n] = s[1]; }
}

extern "C" void kernel_launch(void* const* d_in, const int* in_sizes, int n_in,
                              void* d_out, int out_size, void* d_ws, size_t ws_size,
                              hipStream_t stream) {
  const float* x_e    = (const float*)d_in[0];
  const int*   ei     = (const int*)d_in[1];
  const int*   rel    = (const int*)d_in[2];
  const int*   eall   = (const int*)d_in[3];
  const int*   cih    = (const int*)d_in[5];
  const int*   hcls   = (const int*)d_in[6];
  const int*   cit    = (const int*)d_in[7];
  const int*   tcls   = (const int*)d_in[8];
  const float* remb   = (const float*)d_in[9];
  const float* hw1w   = (const float*)d_in[10];
  const float* hw1b   = (const float*)d_in[11];
  const float* hw2w   = (const float*)d_in[12];
  const float* hw2b   = (const float*)d_in[13];
  const float* h2r_ac = (const float*)d_in[14];
  const float* h2r_ar = (const float*)d_in[15];
  const float* h2r_wh = (const float*)d_in[16];
  const float* h2r_wt = (const float*)d_in[17];
  const float* h2r_hww= (const float*)d_in[18];
  const float* h2r_hwb= (const float*)d_in[19];
  const float* et_ac  = (const float*)d_in[20];
  const float* et_ar  = (const float*)d_in[21];
  const float* et_wh  = (const float*)d_in[22];
  const float* et_wt  = (const float*)d_in[23];
  const float* et_hww = (const float*)d_in[24];
  const float* et_hwb = (const float*)d_in[25];
  const float* gai    = (const float*)d_in[26];
  const float* gaj    = (const float*)d_in[27];
  float* out = (float*)d_out;

  // ---- workspace allocator ----
  char* wsp = (char*)d_ws;
  auto alloc = [&](size_t nbytes) -> void* {
    void* p = (void*)wsp;
    wsp += (nbytes + 255) & ~(size_t)255;
    return p;
  };
  float* ra1h = (float*)alloc(Rr * 4);
  float* ra1e = (float*)alloc(Rr * 4);
  float* dis  = (float*)alloc(Nn * 4);
  int* degi    = (int*)alloc(Nn * 4);
  int* csr_ptr = (int*)alloc((Nn + 1) * 4);
  int* csr_cur = (int*)alloc(Nn * 4);
  int* csr_src = (int*)alloc((size_t)EALLe * 4);
  float* x1  = (float*)alloc((size_t)Nn * 600 * 4);
  float* es2 = (float*)alloc((size_t)2 * Ee * 4);
  float* pm  = (float*)alloc(2 * Nn * 4);
  float* po  = (float*)alloc(2 * Nn * 4);
  float* nv4 = (float*)alloc(2 * Nn * 4);
  float* csum_p = (float*)alloc(2 * Cc * 16 * 4);
  int*   ccnt_p = (int*)alloc(2 * Cc * 16 * 4);
  float* x_class = (float*)alloc(2 * Cc * CHd * 4);
  size_t zregion = (size_t)((char*)x_class + ((2 * Cc * CHd * 4 + 255) & ~255)) - (size_t)(char*)csum_p;
  int*   ccur_p = (int*)alloc(2 * Cc * 16 * 4);
  int*   cstart = (int*)alloc(2 * (Cc + 1) * 4);
  int*   crows  = (int*)alloc((size_t)2 * Ee * 4);
  float* cw     = (float*)alloc((size_t)2 * Ee * 4);
  float* s1v = (float*)alloc(Nn * 4);
  float* s2v = (float*)alloc(Nn * 4);
  unsigned short* arenaA = (unsigned short*)alloc((size_t)Nn * 320 * 2);
  unsigned short* arenaB = (unsigned short*)alloc((size_t)Nn * 320 * 2);
  unsigned short* x1b    = (unsigned short*)alloc(((size_t)Nn * 600 + 64) * 2);
  unsigned short* w1b    = (unsigned short*)alloc((size_t)300 * 320 * 2);
  unsigned short* w2b    = (unsigned short*)alloc((size_t)300 * 320 * 2);
  unsigned short* wcatb  = (unsigned short*)alloc((size_t)600 * 320 * 2);
  unsigned short* hwwbA  = (unsigned short*)alloc((size_t)150 * 160 * 2);
  unsigned short* hwwbB  = (unsigned short*)alloc((size_t)150 * 160 * 2);
  // aliases over dead arenas (dead after the two main GEMMs consume them):
  unsigned short* xob = arenaA;   // 2 x Nn x 160 bf16
  unsigned short* xnb = arenaB;   // 2 x Nn x 152 bf16

  // d_out staging layout (all dead before k_gat3 rewrites d_out)
  float* h1   = out;
  float* gbuf = out + (size_t)Nn * EHd;
  float* proj = out;
  float* outb = out + (size_t)Nn * 600;

  // ---- prologue ----
  hipMemsetAsync(degi, 0, Nn * 4, stream);
  hipMemsetAsync(csum_p, 0, zregion, stream);
  hipMemsetAsync(outb, 0, (size_t)2 * Nn * CHd * 4, stream);
  k_rnorm<<<Rr, 64, 0, stream>>>(remb, h2r_ar, et_ar, ra1h, ra1e);
  k_count<<<cdiv_h(EALLe, 256), 256, 0, stream>>>(eall + EALLe, degi);
  k_scan<<<1, 1024, 0, stream>>>(degi, csr_ptr, csr_cur, dis);
  k_scatter<<<cdiv_h(EALLe, 256), 256, 0, stream>>>(eall, eall + EALLe, csr_cur, csr_src);
  {
    Cvt8 cv;
    cv.s[0] = hw1w;    cv.d[0] = w1b;                         cv.nc[0] = 300; cv.lds[0] = 300; cv.ldp[0] = 320;
    cv.s[1] = hw2w;    cv.d[1] = w2b;                         cv.nc[1] = 300; cv.lds[1] = 300; cv.ldp[1] = 320;
    cv.s[2] = h2r_wh;  cv.d[2] = wcatb + (size_t)0   * 320;   cv.nc[2] = 300; cv.lds[2] = 300; cv.ldp[2] = 320;
    cv.s[3] = h2r_wt;  cv.d[3] = wcatb + (size_t)150 * 320;   cv.nc[3] = 300; cv.lds[3] = 300; cv.ldp[3] = 320;
    cv.s[4] = et_wh;   cv.d[4] = wcatb + (size_t)300 * 320;   cv.nc[4] = 300; cv.lds[4] = 300; cv.ldp[4] = 320;
    cv.s[5] = et_wt;   cv.d[5] = wcatb + (size_t)450 * 320;   cv.nc[5] = 300; cv.lds[5] = 300; cv.ldp[5] = 320;
    cv.s[6] = h2r_hww; cv.d[6] = hwwbA;                       cv.nc[6] = 150; cv.lds[6] = 150; cv.ldp[6] = 160;
    cv.s[7] = et_hww;  cv.d[7] = hwwbB;                       cv.nc[7] = 150; cv.lds[7] = 150; cv.ldp[7] = 160;
    cv.r0[0] = 0;    cv.r0[1] = 300;  cv.r0[2] = 600;  cv.r0[3] = 750;
    cv.r0[4] = 900;  cv.r0[5] = 1050; cv.r0[6] = 1200; cv.r0[7] = 1350; cv.r0[8] = 1500;
    k_f2ball<<<1500, 64, 0, stream>>>(cv);
  }
  k_f2b<<<Nn, 64, 0, stream>>>(x_e, 300, 300, arenaA, 320);

  // ---- GCN + highway x2 ----
  k_gcnb<<<Nn, 64, 0, stream>>>(arenaA, csr_ptr, csr_src, dis, gbuf);
  k_gemmb<1,1><<<dim3(5, cdiv_h(Nn, 64)), 256, 0, stream>>>(
      arenaA, 320, Nn, w1b, 320, 300, hw1b, gbuf, 300, x_e, 300, h1, 300, arenaB, 320);
  k_gcnb<<<Nn, 64, 0, stream>>>(arenaB, csr_ptr, csr_src, dis, gbuf);
  k_gemmb<1,1><<<dim3(5, cdiv_h(Nn, 64)), 256, 0, stream>>>(
      arenaB, 320, Nn, w2b, 320, 300, hw2b, gbuf, 300, h1, 300, x1, 600, x1b, 600);

  // ---- batched projections ----
  k_gemmb<0,0><<<dim3(10, cdiv_h(Nn, 64)), 256, 0, stream>>>(
      x1b, 600, Nn, wcatb, 320, 600, nullptr, nullptr, 0, nullptr, 0, proj, 600,
      nullptr, 0);

  // ---- gat_e: both calls batched per kernel ----
  k_ndots2b<<<dim3(Nn, 2), 64, 0, stream>>>(proj, h2r_ac, et_ac, xob, xnb, pm, po, nv4);
  k_e2sumb<<<dim3(CB, 2), 256, 0, stream>>>(ei, rel, cih, cit, pm, po, ra1h, ra1e,
                                            es2, csum_p, ccnt_p);
  k_cscanb<<<2, 256, 0, stream>>>(ccnt_p, cstart, ccur_p);
  k_cscatterb<<<dim3(CB, 2), 256, 0, stream>>>(ei, cih, cit, es2, ccur_p, crows, cw);
  k_xclassBb<<<dim3(Cc * XSPL, 2), 192, 0, stream>>>(cstart, crows, cw, csum_p,
                                                     xnb, x_class);
  k_classfinalb<<<2, 256, 0, stream>>>(x_class, h2r_ac, et_ac, nv4, hcls, tcls, outb);
  k_hwgemm<<<dim3(3, cdiv_h(Nn, 64), 2), 256, 0, stream>>>(
      xob, hwwbA, hwwbB, h2r_hwb, et_hwb, outb, proj, x1, x1b);

  // ---- final GAT ----
  k_s12<<<Nn, 64, 0, stream>>>(x1b, gai, gaj, s1v, s2v);
  k_gat3<<<Nn, 256, 0, stream>>>(x1, x1b, csr_ptr, csr_src, s1v, s2v, out);
}

// Round 14
// 511.724 us; speedup vs baseline: 1.5760x; 1.0274x over previous
//
#include <hip/hip_runtime.h>
#include <math.h>

#define Nn 20000
#define Ee 120000
#define EALLe 240000
#define Cc 150
#define Rr 1000
#define EHd 300
#define RHd 100
#define CHd 150
#define CB 128
#define XSPL 16

static inline int cdiv_h(int a, int b){ return (a + b - 1) / b; }

typedef __attribute__((ext_vector_type(8))) short short8;
typedef __attribute__((ext_vector_type(4))) float f32x4;

__device__ __forceinline__ float lrelu01(float x){ return x > 0.f ? x : 0.01f * x; }

__device__ __forceinline__ unsigned short f2b(float f){
  unsigned int u = __float_as_uint(f);
  unsigned int r = (u + 0x7FFFu + ((u >> 16) & 1u)) >> 16;
  return (unsigned short)r;
}
__device__ __forceinline__ float b2f(unsigned short u){
  return __uint_as_float(((unsigned int)u) << 16);
}
__device__ __forceinline__ float b2f_lo(unsigned int u){
  return __uint_as_float(u << 16);
}
__device__ __forceinline__ float b2f_hi(unsigned int u){
  return __uint_as_float(u & 0xFFFF0000u);
}

template<int Kq>
__device__ __forceinline__ void wredsumN(float* v){
#pragma unroll
  for (int m = 32; m >= 1; m >>= 1){
#pragma unroll
    for (int k = 0; k < Kq; k++) v[k] += __shfl_xor(v[k], m, 64);
  }
}

// f32 [rows, ncols] (ld ldsrc) -> bf16 [rows, ldp], zero-padded cols ncols..ldp
__global__ __launch_bounds__(64) void k_f2b(const float* __restrict__ src, int ncols,
    int ldsrc, unsigned short* __restrict__ dst, int ldp){
  int r = blockIdx.x, t = threadIdx.x;
  for (int c = t; c < ldp; c += 64)
    dst[(size_t)r * ldp + c] = (c < ncols) ? f2b(src[(size_t)r * ldsrc + c]) : (unsigned short)0;
}

// batched weight conversion: 8 matrices in one launch via descriptor struct
struct Cvt8 {
  const float* s[8];
  unsigned short* d[8];
  int nc[8]; int lds[8]; int ldp[8]; int r0[9];
};
__global__ __launch_bounds__(64) void k_f2ball(Cvt8 c){
  int b = blockIdx.x, t = threadIdx.x;
  int idx = 0;
#pragma unroll
  for (int q = 1; q < 8; q++) if (b >= c.r0[q]) idx = q;
  int r = b - c.r0[idx];
  const float* src = c.s[idx] + (size_t)r * c.lds[idx];
  unsigned short* dst = c.d[idx] + (size_t)r * c.ldp[idx];
  int nc = c.nc[idx], ldp = c.ldp[idx];
  for (int col = t; col < ldp; col += 64)
    dst[col] = (col < nc) ? f2b(src[col]) : (unsigned short)0;
}

__global__ __launch_bounds__(64) void k_rnorm(const float* __restrict__ rt,
    const float* __restrict__ arh, const float* __restrict__ are,
    float* __restrict__ ra1h, float* __restrict__ ra1e){
  int r = blockIdx.x, lane = threadIdx.x;
  bool m1 = (lane + 64 < RHd);
  float v0 = rt[r * RHd + lane];
  float v1 = m1 ? rt[r * RHd + lane + 64] : 0.f;
  float s[3];
  s[0] = v0 * v0 + v1 * v1;
  s[1] = v0 * arh[RHd + lane] + (m1 ? v1 * arh[RHd + lane + 64] : 0.f);
  s[2] = v0 * are[RHd + lane] + (m1 ? v1 * are[RHd + lane + 64] : 0.f);
  wredsumN<3>(s);
  float inv = 0.5f / fmaxf(sqrtf(s[0]), 1e-12f);
  if (!lane){
    ra1h[r] = s[1] * inv;
    ra1e[r] = s[2] * inv;
  }
}

__global__ void k_count(const int* __restrict__ dst, int* __restrict__ degi){
  int e = blockIdx.x * blockDim.x + threadIdx.x;
  if (e < EALLe) atomicAdd(&degi[dst[e]], 1);
}

// exclusive scan of degi -> csr_ptr + cursor copy + fused dis = deg^-1/2
__global__ __launch_bounds__(1024) void k_scan(const int* __restrict__ degi,
    int* __restrict__ ptr, int* __restrict__ cur, float* __restrict__ dis){
  __shared__ int s[1024];
  int t = threadIdx.x;
  const int per = (Nn + 1023) / 1024;
  int b0 = t * per; if (b0 > Nn) b0 = Nn;
  int b1 = b0 + per; if (b1 > Nn) b1 = Nn;
  int sum = 0;
  for (int i = b0; i < b1; i++) sum += degi[i];
  s[t] = sum;
  __syncthreads();
  for (int off = 1; off < 1024; off <<= 1){
    int v = (t >= off) ? s[t - off] : 0;
    __syncthreads();
    s[t] += v;
    __syncthreads();
  }
  int run = (t > 0) ? s[t - 1] : 0;
  for (int i = b0; i < b1; i++){
    int dg = degi[i];
    ptr[i] = run; cur[i] = run; run += dg;
    dis[i] = dg > 0 ? rsqrtf((float)dg) : 0.f;
  }
  if (t == 1023) ptr[Nn] = s[1023];
}

__global__ void k_scatter(const int* __restrict__ src, const int* __restrict__ dst,
    int* __restrict__ cur, int* __restrict__ csr_src){
  int e = blockIdx.x * blockDim.x + threadIdx.x;
  if (e >= EALLe) return;
  int pos = atomicAdd(&cur[dst[e]], 1);
  csr_src[pos] = src[e];
}

// GCN SpMM + relu, float4 (8xbf16) gathers over padded arena rows (ld 320).
// 6 edge-groups of 40 threads; per-thread partial acc, LDS reduce at end.
__global__ __launch_bounds__(256) void k_gcn4(const unsigned short* __restrict__ x,
    const int* __restrict__ ptr, const int* __restrict__ src,
    const float* __restrict__ dis, float* __restrict__ out){
  __shared__ float wl[128];
  __shared__ int jl[128];
  __shared__ float red[5][40][8];
  int i = blockIdx.x, t = threadIdx.x;
  int p0 = ptr[i], p1 = ptr[i + 1];
  float* orow = out + (size_t)i * 300;
  if (p0 == p1){
    for (int f = t; f < 300; f += 256) orow[f] = 0.f;
    return;
  }
  int g = t / 40, c = t - g * 40;
  bool act = t < 240;
  float di = dis[i];
  float acc[8] = {};
  for (int base = p0; base < p1; base += 128){
    int k = base + t;
    if (t < 128 && k < p1){
      int j = src[k];
      jl[t] = j;
      wl[t] = di * dis[j];
    }
    __syncthreads();
    int lim = p1 - base; if (lim > 128) lim = 128;
    if (act){
      for (int q = g; q < lim; q += 6){
        float w = wl[q];
        const unsigned short* xr = x + (size_t)jl[q] * 320;
        union { f32x4 f; unsigned int u[4]; } U;
        U.f = *(const f32x4*)&xr[8 * c];
#pragma unroll
        for (int h = 0; h < 4; h++){
          acc[2 * h]     += w * b2f_lo(U.u[h]);
          acc[2 * h + 1] += w * b2f_hi(U.u[h]);
        }
      }
    }
    __syncthreads();
  }
  if (act && g > 0){
#pragma unroll
    for (int h = 0; h < 8; h++) red[g - 1][c][h] = acc[h];
  }
  __syncthreads();
  if (g == 0){
#pragma unroll
    for (int h = 0; h < 8; h++){
      float v = acc[h];
#pragma unroll
      for (int r = 0; r < 5; r++) v += red[r][c][h];
      acc[h] = fmaxf(v, 0.f);
    }
    int col0 = 8 * c;
    if (col0 + 8 <= 300){
      f32x4 o0 = { acc[0], acc[1], acc[2], acc[3] };
      f32x4 o1 = { acc[4], acc[5], acc[6], acc[7] };
      *(f32x4*)&orow[col0] = o0;
      *(f32x4*)&orow[col0 + 4] = o1;
    } else {
      for (int h = 0; h < 8 && col0 + h < 300; h++) orow[col0 + h] = acc[h];
    }
  }
}

// final GAT: fused x-copy + in-LDS edge weights + float4 bf16 gathers.
// 3 edge-groups of 75 threads; per-thread partial acc, LDS reduce at end.
__global__ __launch_bounds__(256) void k_gat4(const float* __restrict__ x1,
    const unsigned short* __restrict__ x1b,
    const int* __restrict__ ptr, const int* __restrict__ src,
    const float* __restrict__ s1, const float* __restrict__ s2,
    float* __restrict__ dout){
  __shared__ float wl[128];
  __shared__ int jl[128];
  __shared__ float red[2][75][8];
  int i = blockIdx.x, t = threadIdx.x;
  float* orow = dout + (size_t)i * 900;
  const float* xi = x1 + (size_t)i * 600;
  if (t < 75) ((f32x4*)orow)[t] = ((const f32x4*)xi)[t];
  int p0 = ptr[i], p1 = ptr[i + 1];
  if (p0 == p1){
    for (int f = t; f < 600; f += 256) orow[300 + f] = 0.f;
    return;
  }
  float s1i = s1[i];
  int g = t / 75, c = t - g * 75;
  bool act = t < 225;
  float acc[8] = {};
  float den = 0.f;
  for (int base = p0; base < p1; base += 128){
    int k = base + t;
    if (t < 128 && k < p1){
      int j = src[k];
      jl[t] = j;
      wl[t] = expf(lrelu01(s1i + s2[j]));
    }
    __syncthreads();
    int lim = p1 - base; if (lim > 128) lim = 128;
    for (int q = 0; q < lim; q++) den += wl[q];
    if (act){
      for (int q = g; q < lim; q += 3){
        float w = wl[q];
        const unsigned short* xj = x1b + (size_t)jl[q] * 600;
        union { f32x4 f; unsigned int u[4]; } U;
        U.f = *(const f32x4*)&xj[8 * c];
#pragma unroll
        for (int h = 0; h < 4; h++){
          acc[2 * h]     += w * b2f_lo(U.u[h]);
          acc[2 * h + 1] += w * b2f_hi(U.u[h]);
        }
      }
    }
    __syncthreads();
  }
  if (act && g > 0){
#pragma unroll
    for (int h = 0; h < 8; h++) red[g - 1][c][h] = acc[h];
  }
  __syncthreads();
  if (g == 0){
    float invd = 1.f / den;
#pragma unroll
    for (int h = 0; h < 8; h++){
      float v = acc[h] + red[0][c][h] + red[1][c][h];
      acc[h] = fmaxf(v * invd, 0.f);
    }
    f32x4 o0 = { acc[0], acc[1], acc[2], acc[3] };
    f32x4 o1 = { acc[4], acc[5], acc[6], acc[7] };
    ((f32x4*)(orow + 300))[2 * c] = o0;
    ((f32x4*)(orow + 300))[2 * c + 1] = o1;
  }
}

// bf16 MFMA GEMM: out = epi( Xb[nrows,Kp]bf16 @ Wb[M,Kp]bf16^T ).
template<int EPI, int MIR>
__global__ __launch_bounds__(256) void k_gemmb(
    const unsigned short* __restrict__ Xb, int ldxb, int nrows,
    const unsigned short* __restrict__ Wb, int Kp, int M,
    const float* __restrict__ bias,
    const float* __restrict__ X2, int ldx2,
    const float* __restrict__ Xf, int ldxf,
    float* __restrict__ out, int ldo,
    unsigned short* __restrict__ mir, int ldmir){
  __shared__ unsigned short Xs[64][40];
  __shared__ unsigned short Ws[64][40];
  int t = threadIdx.x;
  int wv = t >> 6, lane = t & 63;
  int c0 = blockIdx.x * 64, r0 = blockIdx.y * 64;
  int srow = t >> 2, skoff = (t & 3) * 8;
  int gxr = r0 + srow, gwr = c0 + srow;
  f32x4 acc[4] = {};
  for (int k0 = 0; k0 < Kp; k0 += 32){
    short8 xv = {0,0,0,0,0,0,0,0};
    short8 wv8 = {0,0,0,0,0,0,0,0};
    if (gxr < nrows) xv = *(const short8*)&Xb[(size_t)gxr * ldxb + k0 + skoff];
    if (gwr < M)     wv8 = *(const short8*)&Wb[(size_t)gwr * Kp + k0 + skoff];
    __syncthreads();
    *(short8*)&Xs[srow][skoff] = xv;
    *(short8*)&Ws[srow][skoff] = wv8;
    __syncthreads();
    int arow = wv * 16 + (lane & 15);
    int kk = (lane >> 4) * 8;
    short8 af = *(const short8*)&Xs[arow][kk];
#pragma unroll
    for (int j = 0; j < 4; j++){
      short8 bf = *(const short8*)&Ws[j * 16 + (lane & 15)][kk];
      acc[j] = __builtin_amdgcn_mfma_f32_16x16x32_bf16(af, bf, acc[j], 0, 0, 0);
    }
  }
  int rbase = r0 + wv * 16 + (lane >> 4) * 4;
  int cbase = c0 + (lane & 15);
#pragma unroll
  for (int j = 0; j < 4; j++){
    int c = cbase + j * 16;
    if (c >= M) continue;
#pragma unroll
    for (int r = 0; r < 4; r++){
      int row = rbase + r;
      if (row >= nrows) continue;
      float v = acc[j][r];
      float o;
      if (EPI == 0){
        o = fmaxf(v, 0.f);
      } else {
        float g = 1.f / (1.f + expf(-(v + bias[c])));
        o = g * X2[(size_t)row * ldx2 + c] + (1.f - g) * Xf[(size_t)row * ldxf + c];
      }
      out[(size_t)row * ldo + c] = o;
      if (MIR) mir[(size_t)row * ldmir + c] = f2b(o);
    }
  }
}

// batched gat_e highway GEMM: blockIdx.z = call g
__global__ __launch_bounds__(256) void k_hwgemm(
    const unsigned short* __restrict__ xob,
    const unsigned short* __restrict__ hwwbA, const unsigned short* __restrict__ hwwbB,
    const float* __restrict__ hwbA, const float* __restrict__ hwbB,
    const float* __restrict__ outb, const float* __restrict__ proj,
    float* __restrict__ x1, unsigned short* __restrict__ x1b){
  __shared__ unsigned short Xs[64][40];
  __shared__ unsigned short Ws[64][40];
  int g = blockIdx.z;
  const unsigned short* Xb = xob + (size_t)g * Nn * 160;
  const unsigned short* Wb = g ? hwwbB : hwwbA;
  const float* bias = g ? hwbB : hwbA;
  const float* X2 = outb + (size_t)g * Nn * CHd;
  const float* Xf = proj + (g ? 450 : 0);
  float* outp = x1 + (g ? 450 : 300);
  unsigned short* mir = x1b + (g ? 450 : 300);
  int t = threadIdx.x;
  int wv = t >> 6, lane = t & 63;
  int c0 = blockIdx.x * 64, r0 = blockIdx.y * 64;
  int srow = t >> 2, skoff = (t & 3) * 8;
  int gxr = r0 + srow, gwr = c0 + srow;
  f32x4 acc[4] = {};
  for (int k0 = 0; k0 < 160; k0 += 32){
    short8 xv = {0,0,0,0,0,0,0,0};
    short8 wv8 = {0,0,0,0,0,0,0,0};
    if (gxr < Nn) xv = *(const short8*)&Xb[(size_t)gxr * 160 + k0 + skoff];
    if (gwr < 150) wv8 = *(const short8*)&Wb[(size_t)gwr * 160 + k0 + skoff];
    __syncthreads();
    *(short8*)&Xs[srow][skoff] = xv;
    *(short8*)&Ws[srow][skoff] = wv8;
    __syncthreads();
    int arow = wv * 16 + (lane & 15);
    int kk = (lane >> 4) * 8;
    short8 af = *(const short8*)&Xs[arow][kk];
#pragma unroll
    for (int j = 0; j < 4; j++){
      short8 bf = *(const short8*)&Ws[j * 16 + (lane & 15)][kk];
      acc[j] = __builtin_amdgcn_mfma_f32_16x16x32_bf16(af, bf, acc[j], 0, 0, 0);
    }
  }
  int rbase = r0 + wv * 16 + (lane >> 4) * 4;
  int cbase = c0 + (lane & 15);
#pragma unroll
  for (int j = 0; j < 4; j++){
    int c = cbase + j * 16;
    if (c >= 150) continue;
#pragma unroll
    for (int r = 0; r < 4; r++){
      int row = rbase + r;
      if (row >= Nn) continue;
      float v = acc[j][r];
      float gg = 1.f / (1.f + expf(-(v + bias[c])));
      float o = gg * X2[(size_t)row * CHd + c] + (1.f - gg) * Xf[(size_t)row * 600 + c];
      outp[(size_t)row * 600 + c] = o;
      mir[(size_t)row * 600 + c] = f2b(o);
    }
  }
}

// batched per-node precompute for both gat_e calls + fused xo->bf16 mirror
__global__ __launch_bounds__(64) void k_ndots2b(const float* __restrict__ proj,
    const float* __restrict__ h2r_ac, const float* __restrict__ et_ac,
    unsigned short* __restrict__ xob,
    unsigned short* __restrict__ xnb, float* __restrict__ pm,
    float* __restrict__ po, float* __restrict__ nv4){
  int n = blockIdx.x, g = blockIdx.y, lane = threadIdx.x;
  const float* ac = g ? et_ac : h2r_ac;
  const float* xm = proj + (g ? 300 : 150);
  const float* xo = proj + (g ? 450 : 0);
  const float* v2m = ac + (g ? 1 : 5) * CHd;
  const float* v2o = ac + (g ? 5 : 1) * CHd;
  const float* v3m = ac + (g ? 2 : 6) * CHd;
  const float* v3o = ac + (g ? 6 : 2) * CHd;
  const float* v4  = ac + 3 * CHd;
  bool m2 = lane < (CHd - 128);
  const float* mr = xm + (size_t)n * 600;
  const float* orw = xo + (size_t)n * 600;
  float m0 = mr[lane], m1 = mr[lane + 64], mv2 = m2 ? mr[lane + 128] : 0.f;
  float o0 = orw[lane], o1 = orw[lane + 64], o2 = m2 ? orw[lane + 128] : 0.f;
  // fused xo -> bf16 (xob row, 160-padded)
  unsigned short* xod = xob + (size_t)g * Nn * 160 + (size_t)n * 160;
  xod[lane] = f2b(o0);
  xod[lane + 64] = f2b(o1);
  if (m2) xod[lane + 128] = f2b(o2);
  if (lane < 10) xod[150 + lane] = 0;
  float s[4];
  s[0] = m0 * m0 + m1 * m1 + mv2 * mv2;
  s[1] = o0 * v2o[lane] + o1 * v2o[lane + 64] + (m2 ? o2 * v2o[lane + 128] : 0.f);
  s[2] = o0 * v3o[lane] + o1 * v3o[lane + 64] + (m2 ? o2 * v3o[lane + 128] : 0.f);
  s[3] = o0 * v4[lane]  + o1 * v4[lane + 64]  + (m2 ? o2 * v4[lane + 128]  : 0.f);
  wredsumN<4>(s);
  float inv = 1.f / fmaxf(sqrtf(s[0]), 1e-12f);
  float n0 = m0 * inv, n1 = m1 * inv, n2 = mv2 * inv;
  unsigned short* xr = xnb + (size_t)g * Nn * 152 + (size_t)n * 152;
  xr[lane] = f2b(n0); xr[lane + 64] = f2b(n1);
  if (m2) xr[lane + 128] = f2b(n2);
  float d[2];
  d[0] = n0 * v2m[lane] + n1 * v2m[lane + 64] + (m2 ? n2 * v2m[lane + 128] : 0.f);
  d[1] = n0 * v3m[lane] + n1 * v3m[lane + 64] + (m2 ? n2 * v3m[lane + 128] : 0.f);
  wredsumN<2>(d);
  if (!lane){
    pm[g * Nn + n] = d[0] + 0.25f * d[1];
    po[g * Nn + n] = s[1] + 0.25f * s[2];
    nv4[g * Nn + n] = s[3];
  }
}

// batched per-edge exp-logit + LDS class sums/counts: blockIdx.y = call g
__global__ __launch_bounds__(256) void k_e2sumb(const int* __restrict__ ei,
    const int* __restrict__ rel, const int* __restrict__ cih, const int* __restrict__ cit,
    const float* __restrict__ pm, const float* __restrict__ po,
    const float* __restrict__ ra1h, const float* __restrict__ ra1e,
    float* __restrict__ es2, float* __restrict__ csum_p, int* __restrict__ ccnt_p){
  __shared__ float ls[Cc];
  __shared__ int lc[Cc];
  int t = threadIdx.x, g = blockIdx.y;
  const int* im = ei + (g ? 0 : Ee);
  const int* io = ei + (g ? Ee : 0);
  const int* ci = g ? cit : cih;
  const float* ra1 = g ? ra1e : ra1h;
  const float* pmg = pm + g * Nn;
  const float* pog = po + g * Nn;
  float* es2g = es2 + (size_t)g * Ee;
  float* csg = csum_p + g * Cc * 16;
  int* ccg = ccnt_p + g * Cc * 16;
  for (int c = t; c < Cc; c += 256){ ls[c] = 0.f; lc[c] = 0; }
  __syncthreads();
  for (int e = blockIdx.x * 256 + t; e < Ee; e += gridDim.x * 256){
    float v = lrelu01(pog[io[e]] + pmg[im[e]] + ra1[rel[e]]);
    float s = expf(v);
    es2g[e] = s;
    int c = ci[e];
    atomicAdd(&ls[c], s);
    atomicAdd(&lc[c], 1);
  }
  __syncthreads();
  for (int c = t; c < Cc; c += 256){
    if (lc[c]){
      atomicAdd(&csg[c * 16], ls[c]);
      atomicAdd(&ccg[c * 16], lc[c]);
    }
  }
}

__global__ __launch_bounds__(256) void k_cscanb(const int* __restrict__ ccnt_p,
    int* __restrict__ cstart, int* __restrict__ ccur_p){
  __shared__ int s[Cc + 1];
  int t = threadIdx.x, g = blockIdx.x;
  const int* ccg = ccnt_p + g * Cc * 16;
  int* csg = cstart + g * (Cc + 1);
  int* cug = ccur_p + g * Cc * 16;
  if (t == 0){
    int run = 0;
    for (int c = 0; c < Cc; c++){ s[c] = run; run += ccg[c * 16]; }
    s[Cc] = run;
  }
  __syncthreads();
  if (t <= Cc) csg[t] = s[t];
  if (t < Cc) cug[t * 16] = s[t];
}

__global__ __launch_bounds__(256) void k_cscatterb(const int* __restrict__ ei,
    const int* __restrict__ cih, const int* __restrict__ cit,
    const float* __restrict__ es2,
    int* __restrict__ ccur_p, int* __restrict__ crows, float* __restrict__ cw){
  __shared__ int lcnt[Cc];
  __shared__ int lbase[Cc];
  int t = threadIdx.x, g = blockIdx.y;
  const int* im = ei + (g ? 0 : Ee);
  const int* ci = g ? cit : cih;
  const float* es2g = es2 + (size_t)g * Ee;
  int* cug = ccur_p + g * Cc * 16;
  int* crg = crows + (size_t)g * Ee;
  float* cwg = cw + (size_t)g * Ee;
  int epb = (Ee + gridDim.x - 1) / gridDim.x;
  int e0 = blockIdx.x * epb, e1 = e0 + epb; if (e1 > Ee) e1 = Ee;
  for (int c = t; c < Cc; c += 256) lcnt[c] = 0;
  __syncthreads();
  int myr[4], myc[4], mye[4]; int cnt = 0;
  for (int e = e0 + t; e < e1; e += 256){
    int c = ci[e];
    myr[cnt] = atomicAdd(&lcnt[c], 1);
    myc[cnt] = c; mye[cnt] = e; cnt++;
  }
  __syncthreads();
  for (int c = t; c < Cc; c += 256)
    lbase[c] = lcnt[c] ? atomicAdd(&cug[c * 16], lcnt[c]) : 0;
  __syncthreads();
  for (int q = 0; q < cnt; q++){
    int pos = lbase[myc[q]] + myr[q];
    int e = mye[q];
    crg[pos] = im[im[e]];
    cwg[pos] = es2g[e];
  }
}

__global__ __launch_bounds__(192) void k_xclassBb(
    const int* __restrict__ cstart, const int* __restrict__ crows,
    const float* __restrict__ cw, const float* __restrict__ csum_p,
    const unsigned short* __restrict__ xnb, float* __restrict__ x_class){
  int g = blockIdx.y;
  int c = blockIdx.x / XSPL, sp = blockIdx.x % XSPL;
  int t = threadIdx.x;
  const int* csg = cstart + g * (Cc + 1);
  const int* crg = crows + (size_t)g * Ee;
  const float* cwg = cw + (size_t)g * Ee;
  const unsigned short* xng = xnb + (size_t)g * Nn * 152;
  float* xcg = x_class + g * Cc * CHd;
  int p0 = csg[c], p1 = csg[c + 1];
  int len = p1 - p0;
  if (len <= 0) return;
  int chunk = (len + XSPL - 1) / XSPL;
  int q0 = p0 + sp * chunk;
  int q1 = q0 + chunk; if (q1 > p1) q1 = p1;
  if (q0 >= q1) return;
  bool act = t < CHd;
  float inv = 1.f / csum_p[g * Cc * 16 + c * 16];
  float acc = 0.f;
  int k = q0;
  for (; k + 4 <= q1; k += 4){
    int r0 = crg[k], r1 = crg[k + 1], r2 = crg[k + 2], r3 = crg[k + 3];
    float w0 = cwg[k] * inv, w1 = cwg[k + 1] * inv, w2 = cwg[k + 2] * inv, w3 = cwg[k + 3] * inv;
    if (act){
      acc += w0 * b2f(xng[(size_t)r0 * 152 + t]) + w1 * b2f(xng[(size_t)r1 * 152 + t])
           + w2 * b2f(xng[(size_t)r2 * 152 + t]) + w3 * b2f(xng[(size_t)r3 * 152 + t]);
    }
  }
  for (; k < q1; k++){
    if (act) acc += cwg[k] * inv * b2f(xng[(size_t)crg[k] * 152 + t]);
  }
  if (act) atomicAdd(&xcg[c * CHd + t], acc);
}

__global__ __launch_bounds__(256) void k_classfinalb(
    const float* __restrict__ x_class,
    const float* __restrict__ h2r_ac, const float* __restrict__ et_ac,
    const float* __restrict__ nv4,
    const int* __restrict__ hcls, const int* __restrict__ tcls,
    float* __restrict__ outb){
  __shared__ float v[Cc];
  __shared__ float gm[Cc];
  __shared__ int ce[Cc];
  int t = threadIdx.x, g = blockIdx.x;
  const float* xcg = x_class + g * Cc * CHd;
  const float* acv = (g ? et_ac : h2r_ac) + 7 * CHd;
  const float* nvg = nv4 + g * Nn;
  const int* cls_ent = g ? tcls : hcls;
  float* obg = outb + (size_t)g * Nn * CHd;
  if (t < Cc){
    ce[t] = cls_ent[t];
    float dot = 0.f;
    for (int f = 0; f < CHd; f++) dot += xcg[t * CHd + f] * acv[f];
    v[t] = lrelu01(dot + nvg[ce[t]]);
  }
  __syncthreads();
  if (t < Cc){
    int sgm = ce[t];
    float m = -3.0e38f;
    for (int c2 = 0; c2 < Cc; c2++) if (ce[c2] == sgm) m = fmaxf(m, v[c2]);
    float sum = 0.f;
    for (int c2 = 0; c2 < Cc; c2++) if (ce[c2] == sgm) sum += expf(v[c2] - m);
    gm[t] = expf(v[t] - m) / sum;
  }
  __syncthreads();
  for (int idx = t; idx < Cc * CHd; idx += 256){
    int c = idx / CHd, f = idx - c * CHd;
    atomicAdd(&obg[(size_t)ce[c] * CHd + f], gm[c] * xcg[c * CHd + f]);
  }
}

// per node dot of x1b row with gat_ai / gat_aj — dword loads
__global__ __launch_bounds__(64) void k_s12(const unsigned short* __restrict__ x1b,
    const float* __restrict__ ai, const float* __restrict__ aj,
    float* __restrict__ s1, float* __restrict__ s2){
  int n = blockIdx.x, lane = threadIdx.x;
  const unsigned int* xr = (const unsigned int*)(x1b + (size_t)n * 600);
  float sa = 0.f, sb = 0.f;
#pragma unroll
  for (int u = 0; u < 5; u++){
    int d = lane + u * 64;
    if (d < 300){
      unsigned int w = xr[d];
      float xlo = b2f_lo(w), xhi = b2f_hi(w);
      sa += xlo * ai[2 * d] + xhi * ai[2 * d + 1];
      sb += xlo * aj[2 * d] + xhi * aj[2 * d + 1];
    }
  }
  float s[2] = { sa, sb };
  wredsumN<2>(s);
  if (!lane){ s1[n] = s[0]; s2[n] = s[1]; }
}

extern "C" void kernel_launch(void* const* d_in, const int* in_sizes, int n_in,
                              void* d_out, int out_size, void* d_ws, size_t ws_size,
                              hipStream_t stream) {
  const float* x_e    = (const float*)d_in[0];
  const int*   ei     = (const int*)d_in[1];
  const int*   rel    = (const int*)d_in[2];
  const int*   eall   = (const int*)d_in[3];
  const int*   cih    = (const int*)d_in[5];
  const int*   hcls   = (const int*)d_in[6];
  const int*   cit    = (const int*)d_in[7];
  const int*   tcls   = (const int*)d_in[8];
  const float* remb   = (const float*)d_in[9];
  const float* hw1w   = (const float*)d_in[10];
  const float* hw1b   = (const float*)d_in[11];
  const float* hw2w   = (const float*)d_in[12];
  const float* hw2b   = (const float*)d_in[13];
  const float* h2r_ac = (const float*)d_in[14];
  const float* h2r_ar = (const float*)d_in[15];
  const float* h2r_wh = (const float*)d_in[16];
  const float* h2r_wt = (const float*)d_in[17];
  const float* h2r_hww= (const float*)d_in[18];
  const float* h2r_hwb= (const float*)d_in[19];
  const float* et_ac  = (const float*)d_in[20];
  const float* et_ar  = (const float*)d_in[21];
  const float* et_wh  = (const float*)d_in[22];
  const float* et_wt  = (const float*)d_in[23];
  const float* et_hww = (const float*)d_in[24];
  const float* et_hwb = (const float*)d_in[25];
  const float* gai    = (const float*)d_in[26];
  const float* gaj    = (const float*)d_in[27];
  float* out = (float*)d_out;

  // ---- workspace allocator ----
  char* wsp = (char*)d_ws;
  auto alloc = [&](size_t nbytes) -> void* {
    void* p = (void*)wsp;
    wsp += (nbytes + 255) & ~(size_t)255;
    return p;
  };
  float* ra1h = (float*)alloc(Rr * 4);
  float* ra1e = (float*)alloc(Rr * 4);
  float* dis  = (float*)alloc(Nn * 4);
  int* degi    = (int*)alloc(Nn * 4);
  int* csr_ptr = (int*)alloc((Nn + 1) * 4);
  int* csr_cur = (int*)alloc(Nn * 4);
  int* csr_src = (int*)alloc((size_t)EALLe * 4);
  float* x1  = (float*)alloc((size_t)Nn * 600 * 4);
  float* es2 = (float*)alloc((size_t)2 * Ee * 4);
  float* pm  = (float*)alloc(2 * Nn * 4);
  float* po  = (float*)alloc(2 * Nn * 4);
  float* nv4 = (float*)alloc(2 * Nn * 4);
  float* csum_p = (float*)alloc(2 * Cc * 16 * 4);
  int*   ccnt_p = (int*)alloc(2 * Cc * 16 * 4);
  float* x_class = (float*)alloc(2 * Cc * CHd * 4);
  size_t zregion = (size_t)((char*)x_class + ((2 * Cc * CHd * 4 + 255) & ~255)) - (size_t)(char*)csum_p;
  int*   ccur_p = (int*)alloc(2 * Cc * 16 * 4);
  int*   cstart = (int*)alloc(2 * (Cc + 1) * 4);
  int*   crows  = (int*)alloc((size_t)2 * Ee * 4);
  float* cw     = (float*)alloc((size_t)2 * Ee * 4);
  float* s1v = (float*)alloc(Nn * 4);
  float* s2v = (float*)alloc(Nn * 4);
  unsigned short* arenaA = (unsigned short*)alloc((size_t)Nn * 320 * 2);
  unsigned short* arenaB = (unsigned short*)alloc((size_t)Nn * 320 * 2);
  unsigned short* x1b    = (unsigned short*)alloc(((size_t)Nn * 600 + 64) * 2);
  unsigned short* w1b    = (unsigned short*)alloc((size_t)300 * 320 * 2);
  unsigned short* w2b    = (unsigned short*)alloc((size_t)300 * 320 * 2);
  unsigned short* wcatb  = (unsigned short*)alloc((size_t)600 * 320 * 2);
  unsigned short* hwwbA  = (unsigned short*)alloc((size_t)150 * 160 * 2);
  unsigned short* hwwbB  = (unsigned short*)alloc((size_t)150 * 160 * 2);
  // aliases over dead arenas (dead after the two main GEMMs consume them):
  unsigned short* xob = arenaA;   // 2 x Nn x 160 bf16
  unsigned short* xnb = arenaB;   // 2 x Nn x 152 bf16

  // d_out staging layout (all dead before k_gat4 rewrites d_out)
  float* h1   = out;
  float* gbuf = out + (size_t)Nn * EHd;
  float* proj = out;
  float* outb = out + (size_t)Nn * 600;

  // ---- prologue ----
  hipMemsetAsync(degi, 0, Nn * 4, stream);
  hipMemsetAsync(csum_p, 0, zregion, stream);
  hipMemsetAsync(outb, 0, (size_t)2 * Nn * CHd * 4, stream);
  k_rnorm<<<Rr, 64, 0, stream>>>(remb, h2r_ar, et_ar, ra1h, ra1e);
  k_count<<<cdiv_h(EALLe, 256), 256, 0, stream>>>(eall + EALLe, degi);
  k_scan<<<1, 1024, 0, stream>>>(degi, csr_ptr, csr_cur, dis);
  k_scatter<<<cdiv_h(EALLe, 256), 256, 0, stream>>>(eall, eall + EALLe, csr_cur, csr_src);
  {
    Cvt8 cv;
    cv.s[0] = hw1w;    cv.d[0] = w1b;                         cv.nc[0] = 300; cv.lds[0] = 300; cv.ldp[0] = 320;
    cv.s[1] = hw2w;    cv.d[1] = w2b;                         cv.nc[1] = 300; cv.lds[1] = 300; cv.ldp[1] = 320;
    cv.s[2] = h2r_wh;  cv.d[2] = wcatb + (size_t)0   * 320;   cv.nc[2] = 300; cv.lds[2] = 300; cv.ldp[2] = 320;
    cv.s[3] = h2r_wt;  cv.d[3] = wcatb + (size_t)150 * 320;   cv.nc[3] = 300; cv.lds[3] = 300; cv.ldp[3] = 320;
    cv.s[4] = et_wh;   cv.d[4] = wcatb + (size_t)300 * 320;   cv.nc[4] = 300; cv.lds[4] = 300; cv.ldp[4] = 320;
    cv.s[5] = et_wt;   cv.d[5] = wcatb + (size_t)450 * 320;   cv.nc[5] = 300; cv.lds[5] = 300; cv.ldp[5] = 320;
    cv.s[6] = h2r_hww; cv.d[6] = hwwbA;                       cv.nc[6] = 150; cv.lds[6] = 150; cv.ldp[6] = 160;
    cv.s[7] = et_hww;  cv.d[7] = hwwbB;                       cv.nc[7] = 150; cv.lds[7] = 150; cv.ldp[7] = 160;
    cv.r0[0] = 0;    cv.r0[1] = 300;  cv.r0[2] = 600;  cv.r0[3] = 750;
    cv.r0[4] = 900;  cv.r0[5] = 1050; cv.r0[6] = 1200; cv.r0[7] = 1350; cv.r0[8] = 1500;
    k_f2ball<<<1500, 64, 0, stream>>>(cv);
  }
  k_f2b<<<Nn, 64, 0, stream>>>(x_e, 300, 300, arenaA, 320);

  // ---- GCN + highway x2 ----
  k_gcn4<<<Nn, 256, 0, stream>>>(arenaA, csr_ptr, csr_src, dis, gbuf);
  k_gemmb<1,1><<<dim3(5, cdiv_h(Nn, 64)), 256, 0, stream>>>(
      arenaA, 320, Nn, w1b, 320, 300, hw1b, gbuf, 300, x_e, 300, h1, 300, arenaB, 320);
  k_gcn4<<<Nn, 256, 0, stream>>>(arenaB, csr_ptr, csr_src, dis, gbuf);
  k_gemmb<1,1><<<dim3(5, cdiv_h(Nn, 64)), 256, 0, stream>>>(
      arenaB, 320, Nn, w2b, 320, 300, hw2b, gbuf, 300, h1, 300, x1, 600, x1b, 600);

  // ---- batched projections ----
  k_gemmb<0,0><<<dim3(10, cdiv_h(Nn, 64)), 256, 0, stream>>>(
      x1b, 600, Nn, wcatb, 320, 600, nullptr, nullptr, 0, nullptr, 0, proj, 600,
      nullptr, 0);

  // ---- gat_e: both calls batched per kernel ----
  k_ndots2b<<<dim3(Nn, 2), 64, 0, stream>>>(proj, h2r_ac, et_ac, xob, xnb, pm, po, nv4);
  k_e2sumb<<<dim3(CB, 2), 256, 0, stream>>>(ei, rel, cih, cit, pm, po, ra1h, ra1e,
                                            es2, csum_p, ccnt_p);
  k_cscanb<<<2, 256, 0, stream>>>(ccnt_p, cstart, ccur_p);
  k_cscatterb<<<dim3(CB, 2), 256, 0, stream>>>(ei, cih, cit, es2, ccur_p, crows, cw);
  k_xclassBb<<<dim3(Cc * XSPL, 2), 192, 0, stream>>>(cstart, crows, cw, csum_p,
                                                     xnb, x_class);
  k_classfinalb<<<2, 256, 0, stream>>>(x_class, h2r_ac, et_ac, nv4, hcls, tcls, outb);
  k_hwgemm<<<dim3(3, cdiv_h(Nn, 64), 2), 256, 0, stream>>>(
      xob, hwwbA, hwwbB, h2r_hwb, et_hwb, outb, proj, x1, x1b);

  // ---- final GAT ----
  k_s12<<<Nn, 64, 0, stream>>>(x1b, gai, gaj, s1v, s2v);
  k_gat4<<<Nn, 256, 0, stream>>>(x1, x1b, csr_ptr, csr_src, s1v, s2v, out);
}

// Round 15
// 482.499 us; speedup vs baseline: 1.6714x; 1.0606x over previous
//
#include <hip/hip_runtime.h>
#include <math.h>

#define Nn 20000
#define Ee 120000
#define EALLe 240000
#define Cc 150
#define Rr 1000
#define EHd 300
#define RHd 100
#define CHd 150
#define CB 128
#define XSPL 16

static inline int cdiv_h(int a, int b){ return (a + b - 1) / b; }

typedef __attribute__((ext_vector_type(8))) short short8;
typedef __attribute__((ext_vector_type(4))) float f32x4;

__device__ __forceinline__ float lrelu01(float x){ return x > 0.f ? x : 0.01f * x; }

__device__ __forceinline__ unsigned short f2b(float f){
  unsigned int u = __float_as_uint(f);
  unsigned int r = (u + 0x7FFFu + ((u >> 16) & 1u)) >> 16;
  return (unsigned short)r;
}
__device__ __forceinline__ float b2f(unsigned short u){
  return __uint_as_float(((unsigned int)u) << 16);
}
__device__ __forceinline__ float b2f_lo(unsigned int u){
  return __uint_as_float(u << 16);
}
__device__ __forceinline__ float b2f_hi(unsigned int u){
  return __uint_as_float(u & 0xFFFF0000u);
}

template<int Kq>
__device__ __forceinline__ void wredsumN(float* v){
#pragma unroll
  for (int m = 32; m >= 1; m >>= 1){
#pragma unroll
    for (int k = 0; k < Kq; k++) v[k] += __shfl_xor(v[k], m, 64);
  }
}

// f32 [rows, ncols] (ld ldsrc) -> bf16 [rows, ldp], zero-padded cols ncols..ldp
__global__ __launch_bounds__(64) void k_f2b(const float* __restrict__ src, int ncols,
    int ldsrc, unsigned short* __restrict__ dst, int ldp){
  int r = blockIdx.x, t = threadIdx.x;
  for (int c = t; c < ldp; c += 64)
    dst[(size_t)r * ldp + c] = (c < ncols) ? f2b(src[(size_t)r * ldsrc + c]) : (unsigned short)0;
}

// batched weight conversion: 8 matrices in one launch via descriptor struct
struct Cvt8 {
  const float* s[8];
  unsigned short* d[8];
  int nc[8]; int lds[8]; int ldp[8]; int r0[9];
};
__global__ __launch_bounds__(64) void k_f2ball(Cvt8 c){
  int b = blockIdx.x, t = threadIdx.x;
  int idx = 0;
#pragma unroll
  for (int q = 1; q < 8; q++) if (b >= c.r0[q]) idx = q;
  int r = b - c.r0[idx];
  const float* src = c.s[idx] + (size_t)r * c.lds[idx];
  unsigned short* dst = c.d[idx] + (size_t)r * c.ldp[idx];
  int nc = c.nc[idx], ldp = c.ldp[idx];
  for (int col = t; col < ldp; col += 64)
    dst[col] = (col < nc) ? f2b(src[col]) : (unsigned short)0;
}

__global__ __launch_bounds__(64) void k_rnorm(const float* __restrict__ rt,
    const float* __restrict__ arh, const float* __restrict__ are,
    float* __restrict__ ra1h, float* __restrict__ ra1e){
  int r = blockIdx.x, lane = threadIdx.x;
  bool m1 = (lane + 64 < RHd);
  float v0 = rt[r * RHd + lane];
  float v1 = m1 ? rt[r * RHd + lane + 64] : 0.f;
  float s[3];
  s[0] = v0 * v0 + v1 * v1;
  s[1] = v0 * arh[RHd + lane] + (m1 ? v1 * arh[RHd + lane + 64] : 0.f);
  s[2] = v0 * are[RHd + lane] + (m1 ? v1 * are[RHd + lane + 64] : 0.f);
  wredsumN<3>(s);
  float inv = 0.5f / fmaxf(sqrtf(s[0]), 1e-12f);
  if (!lane){
    ra1h[r] = s[1] * inv;
    ra1e[r] = s[2] * inv;
  }
}

__global__ void k_count(const int* __restrict__ dst, int* __restrict__ degi){
  int e = blockIdx.x * blockDim.x + threadIdx.x;
  if (e < EALLe) atomicAdd(&degi[dst[e]], 1);
}

// exclusive scan of degi -> csr_ptr + cursor copy + fused dis = deg^-1/2
__global__ __launch_bounds__(1024) void k_scan(const int* __restrict__ degi,
    int* __restrict__ ptr, int* __restrict__ cur, float* __restrict__ dis){
  __shared__ int s[1024];
  int t = threadIdx.x;
  const int per = (Nn + 1023) / 1024;
  int b0 = t * per; if (b0 > Nn) b0 = Nn;
  int b1 = b0 + per; if (b1 > Nn) b1 = Nn;
  int sum = 0;
  for (int i = b0; i < b1; i++) sum += degi[i];
  s[t] = sum;
  __syncthreads();
  for (int off = 1; off < 1024; off <<= 1){
    int v = (t >= off) ? s[t - off] : 0;
    __syncthreads();
    s[t] += v;
    __syncthreads();
  }
  int run = (t > 0) ? s[t - 1] : 0;
  for (int i = b0; i < b1; i++){
    int dg = degi[i];
    ptr[i] = run; cur[i] = run; run += dg;
    dis[i] = dg > 0 ? rsqrtf((float)dg) : 0.f;
  }
  if (t == 1023) ptr[Nn] = s[1023];
}

__global__ void k_scatter(const int* __restrict__ src, const int* __restrict__ dst,
    int* __restrict__ cur, int* __restrict__ csr_src){
  int e = blockIdx.x * blockDim.x + threadIdx.x;
  if (e >= EALLe) return;
  int pos = atomicAdd(&cur[dst[e]], 1);
  csr_src[pos] = src[e];
}

// GCN SpMM + relu, float4 (8xbf16) gathers over padded arena rows (ld 320).
__global__ __launch_bounds__(256) void k_gcn4(const unsigned short* __restrict__ x,
    const int* __restrict__ ptr, const int* __restrict__ src,
    const float* __restrict__ dis, float* __restrict__ out){
  __shared__ float wl[128];
  __shared__ int jl[128];
  __shared__ float red[5][40][8];
  int i = blockIdx.x, t = threadIdx.x;
  int p0 = ptr[i], p1 = ptr[i + 1];
  float* orow = out + (size_t)i * 300;
  if (p0 == p1){
    for (int f = t; f < 300; f += 256) orow[f] = 0.f;
    return;
  }
  int g = t / 40, c = t - g * 40;
  bool act = t < 240;
  float di = dis[i];
  float acc[8] = {};
  for (int base = p0; base < p1; base += 128){
    int k = base + t;
    if (t < 128 && k < p1){
      int j = src[k];
      jl[t] = j;
      wl[t] = di * dis[j];
    }
    __syncthreads();
    int lim = p1 - base; if (lim > 128) lim = 128;
    if (act){
      for (int q = g; q < lim; q += 6){
        float w = wl[q];
        const unsigned short* xr = x + (size_t)jl[q] * 320;
        union { f32x4 f; unsigned int u[4]; } U;
        U.f = *(const f32x4*)&xr[8 * c];
#pragma unroll
        for (int h = 0; h < 4; h++){
          acc[2 * h]     += w * b2f_lo(U.u[h]);
          acc[2 * h + 1] += w * b2f_hi(U.u[h]);
        }
      }
    }
    __syncthreads();
  }
  if (act && g > 0){
#pragma unroll
    for (int h = 0; h < 8; h++) red[g - 1][c][h] = acc[h];
  }
  __syncthreads();
  if (g == 0){
#pragma unroll
    for (int h = 0; h < 8; h++){
      float v = acc[h];
#pragma unroll
      for (int r = 0; r < 5; r++) v += red[r][c][h];
      acc[h] = fmaxf(v, 0.f);
    }
    int col0 = 8 * c;
    if (col0 + 8 <= 300){
      f32x4 o0 = { acc[0], acc[1], acc[2], acc[3] };
      f32x4 o1 = { acc[4], acc[5], acc[6], acc[7] };
      *(f32x4*)&orow[col0] = o0;
      *(f32x4*)&orow[col0 + 4] = o1;
    } else {
      for (int h = 0; h < 8 && col0 + h < 300; h++) orow[col0 + h] = acc[h];
    }
  }
}

// final GAT: fused x-copy + in-LDS edge weights + float4 bf16 gathers.
__global__ __launch_bounds__(256) void k_gat4(const float* __restrict__ x1,
    const unsigned short* __restrict__ x1b,
    const int* __restrict__ ptr, const int* __restrict__ src,
    const float* __restrict__ s1, const float* __restrict__ s2,
    float* __restrict__ dout){
  __shared__ float wl[128];
  __shared__ int jl[128];
  __shared__ float red[2][75][8];
  int i = blockIdx.x, t = threadIdx.x;
  float* orow = dout + (size_t)i * 900;
  const float* xi = x1 + (size_t)i * 600;
  if (t < 75) ((f32x4*)orow)[t] = ((const f32x4*)xi)[t];
  int p0 = ptr[i], p1 = ptr[i + 1];
  if (p0 == p1){
    for (int f = t; f < 600; f += 256) orow[300 + f] = 0.f;
    return;
  }
  float s1i = s1[i];
  int g = t / 75, c = t - g * 75;
  bool act = t < 225;
  float acc[8] = {};
  float den = 0.f;
  for (int base = p0; base < p1; base += 128){
    int k = base + t;
    if (t < 128 && k < p1){
      int j = src[k];
      jl[t] = j;
      wl[t] = expf(lrelu01(s1i + s2[j]));
    }
    __syncthreads();
    int lim = p1 - base; if (lim > 128) lim = 128;
    for (int q = 0; q < lim; q++) den += wl[q];
    if (act){
      for (int q = g; q < lim; q += 3){
        float w = wl[q];
        const unsigned short* xj = x1b + (size_t)jl[q] * 600;
        union { f32x4 f; unsigned int u[4]; } U;
        U.f = *(const f32x4*)&xj[8 * c];
#pragma unroll
        for (int h = 0; h < 4; h++){
          acc[2 * h]     += w * b2f_lo(U.u[h]);
          acc[2 * h + 1] += w * b2f_hi(U.u[h]);
        }
      }
    }
    __syncthreads();
  }
  if (act && g > 0){
#pragma unroll
    for (int h = 0; h < 8; h++) red[g - 1][c][h] = acc[h];
  }
  __syncthreads();
  if (g == 0){
    float invd = 1.f / den;
#pragma unroll
    for (int h = 0; h < 8; h++){
      float v = acc[h] + red[0][c][h] + red[1][c][h];
      acc[h] = fmaxf(v * invd, 0.f);
    }
    f32x4 o0 = { acc[0], acc[1], acc[2], acc[3] };
    f32x4 o1 = { acc[4], acc[5], acc[6], acc[7] };
    ((f32x4*)(orow + 300))[2 * c] = o0;
    ((f32x4*)(orow + 300))[2 * c + 1] = o1;
  }
}

// bf16 MFMA GEMM: out = epi( Xb[nrows,Kp]bf16 @ Wb[M,Kp]bf16^T ).
template<int EPI, int MIR>
__global__ __launch_bounds__(256) void k_gemmb(
    const unsigned short* __restrict__ Xb, int ldxb, int nrows,
    const unsigned short* __restrict__ Wb, int Kp, int M,
    const float* __restrict__ bias,
    const float* __restrict__ X2, int ldx2,
    const float* __restrict__ Xf, int ldxf,
    float* __restrict__ out, int ldo,
    unsigned short* __restrict__ mir, int ldmir){
  __shared__ unsigned short Xs[64][40];
  __shared__ unsigned short Ws[64][40];
  int t = threadIdx.x;
  int wv = t >> 6, lane = t & 63;
  int c0 = blockIdx.x * 64, r0 = blockIdx.y * 64;
  int srow = t >> 2, skoff = (t & 3) * 8;
  int gxr = r0 + srow, gwr = c0 + srow;
  f32x4 acc[4] = {};
  for (int k0 = 0; k0 < Kp; k0 += 32){
    short8 xv = {0,0,0,0,0,0,0,0};
    short8 wv8 = {0,0,0,0,0,0,0,0};
    if (gxr < nrows) xv = *(const short8*)&Xb[(size_t)gxr * ldxb + k0 + skoff];
    if (gwr < M)     wv8 = *(const short8*)&Wb[(size_t)gwr * Kp + k0 + skoff];
    __syncthreads();
    *(short8*)&Xs[srow][skoff] = xv;
    *(short8*)&Ws[srow][skoff] = wv8;
    __syncthreads();
    int arow = wv * 16 + (lane & 15);
    int kk = (lane >> 4) * 8;
    short8 af = *(const short8*)&Xs[arow][kk];
#pragma unroll
    for (int j = 0; j < 4; j++){
      short8 bf = *(const short8*)&Ws[j * 16 + (lane & 15)][kk];
      acc[j] = __builtin_amdgcn_mfma_f32_16x16x32_bf16(af, bf, acc[j], 0, 0, 0);
    }
  }
  int rbase = r0 + wv * 16 + (lane >> 4) * 4;
  int cbase = c0 + (lane & 15);
#pragma unroll
  for (int j = 0; j < 4; j++){
    int c = cbase + j * 16;
    if (c >= M) continue;
#pragma unroll
    for (int r = 0; r < 4; r++){
      int row = rbase + r;
      if (row >= nrows) continue;
      float v = acc[j][r];
      float o;
      if (EPI == 0){
        o = fmaxf(v, 0.f);
      } else {
        float g = 1.f / (1.f + expf(-(v + bias[c])));
        o = g * X2[(size_t)row * ldx2 + c] + (1.f - g) * Xf[(size_t)row * ldxf + c];
      }
      out[(size_t)row * ldo + c] = o;
      if (MIR) mir[(size_t)row * ldmir + c] = f2b(o);
    }
  }
}

// batched gat_e highway GEMM: blockIdx.z = call g
__global__ __launch_bounds__(256) void k_hwgemm(
    const unsigned short* __restrict__ xob,
    const unsigned short* __restrict__ hwwbA, const unsigned short* __restrict__ hwwbB,
    const float* __restrict__ hwbA, const float* __restrict__ hwbB,
    const float* __restrict__ outb, const float* __restrict__ proj,
    float* __restrict__ x1, unsigned short* __restrict__ x1b){
  __shared__ unsigned short Xs[64][40];
  __shared__ unsigned short Ws[64][40];
  int g = blockIdx.z;
  const unsigned short* Xb = xob + (size_t)g * Nn * 160;
  const unsigned short* Wb = g ? hwwbB : hwwbA;
  const float* bias = g ? hwbB : hwbA;
  const float* X2 = outb + (size_t)g * Nn * CHd;
  const float* Xf = proj + (g ? 450 : 0);
  float* outp = x1 + (g ? 450 : 300);
  unsigned short* mir = x1b + (g ? 450 : 300);
  int t = threadIdx.x;
  int wv = t >> 6, lane = t & 63;
  int c0 = blockIdx.x * 64, r0 = blockIdx.y * 64;
  int srow = t >> 2, skoff = (t & 3) * 8;
  int gxr = r0 + srow, gwr = c0 + srow;
  f32x4 acc[4] = {};
  for (int k0 = 0; k0 < 160; k0 += 32){
    short8 xv = {0,0,0,0,0,0,0,0};
    short8 wv8 = {0,0,0,0,0,0,0,0};
    if (gxr < Nn) xv = *(const short8*)&Xb[(size_t)gxr * 160 + k0 + skoff];
    if (gwr < 150) wv8 = *(const short8*)&Wb[(size_t)gwr * 160 + k0 + skoff];
    __syncthreads();
    *(short8*)&Xs[srow][skoff] = xv;
    *(short8*)&Ws[srow][skoff] = wv8;
    __syncthreads();
    int arow = wv * 16 + (lane & 15);
    int kk = (lane >> 4) * 8;
    short8 af = *(const short8*)&Xs[arow][kk];
#pragma unroll
    for (int j = 0; j < 4; j++){
      short8 bf = *(const short8*)&Ws[j * 16 + (lane & 15)][kk];
      acc[j] = __builtin_amdgcn_mfma_f32_16x16x32_bf16(af, bf, acc[j], 0, 0, 0);
    }
  }
  int rbase = r0 + wv * 16 + (lane >> 4) * 4;
  int cbase = c0 + (lane & 15);
#pragma unroll
  for (int j = 0; j < 4; j++){
    int c = cbase + j * 16;
    if (c >= 150) continue;
#pragma unroll
    for (int r = 0; r < 4; r++){
      int row = rbase + r;
      if (row >= Nn) continue;
      float v = acc[j][r];
      float gg = 1.f / (1.f + expf(-(v + bias[c])));
      float o = gg * X2[(size_t)row * CHd + c] + (1.f - gg) * Xf[(size_t)row * 600 + c];
      outp[(size_t)row * 600 + c] = o;
      mir[(size_t)row * 600 + c] = f2b(o);
    }
  }
}

// batched per-node precompute for both gat_e calls + fused xo->bf16 mirror
__global__ __launch_bounds__(64) void k_ndots2b(const float* __restrict__ proj,
    const float* __restrict__ h2r_ac, const float* __restrict__ et_ac,
    unsigned short* __restrict__ xob,
    unsigned short* __restrict__ xnb, float* __restrict__ pm,
    float* __restrict__ po, float* __restrict__ nv4){
  int n = blockIdx.x, g = blockIdx.y, lane = threadIdx.x;
  const float* ac = g ? et_ac : h2r_ac;
  const float* xm = proj + (g ? 300 : 150);
  const float* xo = proj + (g ? 450 : 0);
  const float* v2m = ac + (g ? 1 : 5) * CHd;
  const float* v2o = ac + (g ? 5 : 1) * CHd;
  const float* v3m = ac + (g ? 2 : 6) * CHd;
  const float* v3o = ac + (g ? 6 : 2) * CHd;
  const float* v4  = ac + 3 * CHd;
  bool m2 = lane < (CHd - 128);
  const float* mr = xm + (size_t)n * 600;
  const float* orw = xo + (size_t)n * 600;
  float m0 = mr[lane], m1 = mr[lane + 64], mv2 = m2 ? mr[lane + 128] : 0.f;
  float o0 = orw[lane], o1 = orw[lane + 64], o2 = m2 ? orw[lane + 128] : 0.f;
  unsigned short* xod = xob + (size_t)g * Nn * 160 + (size_t)n * 160;
  xod[lane] = f2b(o0);
  xod[lane + 64] = f2b(o1);
  if (m2) xod[lane + 128] = f2b(o2);
  if (lane < 10) xod[150 + lane] = 0;
  float s[4];
  s[0] = m0 * m0 + m1 * m1 + mv2 * mv2;
  s[1] = o0 * v2o[lane] + o1 * v2o[lane + 64] + (m2 ? o2 * v2o[lane + 128] : 0.f);
  s[2] = o0 * v3o[lane] + o1 * v3o[lane + 64] + (m2 ? o2 * v3o[lane + 128] : 0.f);
  s[3] = o0 * v4[lane]  + o1 * v4[lane + 64]  + (m2 ? o2 * v4[lane + 128]  : 0.f);
  wredsumN<4>(s);
  float inv = 1.f / fmaxf(sqrtf(s[0]), 1e-12f);
  float n0 = m0 * inv, n1 = m1 * inv, n2 = mv2 * inv;
  unsigned short* xr = xnb + (size_t)g * Nn * 152 + (size_t)n * 152;
  xr[lane] = f2b(n0); xr[lane + 64] = f2b(n1);
  if (m2) xr[lane + 128] = f2b(n2);
  float d[2];
  d[0] = n0 * v2m[lane] + n1 * v2m[lane + 64] + (m2 ? n2 * v2m[lane + 128] : 0.f);
  d[1] = n0 * v3m[lane] + n1 * v3m[lane + 64] + (m2 ? n2 * v3m[lane + 128] : 0.f);
  wredsumN<2>(d);
  if (!lane){
    pm[g * Nn + n] = d[0] + 0.25f * d[1];
    po[g * Nn + n] = s[1] + 0.25f * s[2];
    nv4[g * Nn + n] = s[3];
  }
}

// batched per-edge exp-logit + LDS class sums/counts: blockIdx.y = call g
__global__ __launch_bounds__(256) void k_e2sumb(const int* __restrict__ ei,
    const int* __restrict__ rel, const int* __restrict__ cih, const int* __restrict__ cit,
    const float* __restrict__ pm, const float* __restrict__ po,
    const float* __restrict__ ra1h, const float* __restrict__ ra1e,
    float* __restrict__ es2, float* __restrict__ csum_p, int* __restrict__ ccnt_p){
  __shared__ float ls[Cc];
  __shared__ int lc[Cc];
  int t = threadIdx.x, g = blockIdx.y;
  const int* im = ei + (g ? 0 : Ee);
  const int* io = ei + (g ? Ee : 0);
  const int* ci = g ? cit : cih;
  const float* ra1 = g ? ra1e : ra1h;
  const float* pmg = pm + g * Nn;
  const float* pog = po + g * Nn;
  float* es2g = es2 + (size_t)g * Ee;
  float* csg = csum_p + g * Cc * 16;
  int* ccg = ccnt_p + g * Cc * 16;
  for (int c = t; c < Cc; c += 256){ ls[c] = 0.f; lc[c] = 0; }
  __syncthreads();
  for (int e = blockIdx.x * 256 + t; e < Ee; e += gridDim.x * 256){
    float v = lrelu01(pog[io[e]] + pmg[im[e]] + ra1[rel[e]]);
    float s = expf(v);
    es2g[e] = s;
    int c = ci[e];
    atomicAdd(&ls[c], s);
    atomicAdd(&lc[c], 1);
  }
  __syncthreads();
  for (int c = t; c < Cc; c += 256){
    if (lc[c]){
      atomicAdd(&csg[c * 16], ls[c]);
      atomicAdd(&ccg[c * 16], lc[c]);
    }
  }
}

__global__ __launch_bounds__(256) void k_cscanb(const int* __restrict__ ccnt_p,
    int* __restrict__ cstart, int* __restrict__ ccur_p){
  __shared__ int s[Cc + 1];
  int t = threadIdx.x, g = blockIdx.x;
  const int* ccg = ccnt_p + g * Cc * 16;
  int* csg = cstart + g * (Cc + 1);
  int* cug = ccur_p + g * Cc * 16;
  if (t == 0){
    int run = 0;
    for (int c = 0; c < Cc; c++){ s[c] = run; run += ccg[c * 16]; }
    s[Cc] = run;
  }
  __syncthreads();
  if (t <= Cc) csg[t] = s[t];
  if (t < Cc) cug[t * 16] = s[t];
}

__global__ __launch_bounds__(256) void k_cscatterb(const int* __restrict__ ei,
    const int* __restrict__ cih, const int* __restrict__ cit,
    const float* __restrict__ es2,
    int* __restrict__ ccur_p, int* __restrict__ crows, float* __restrict__ cw){
  __shared__ int lcnt[Cc];
  __shared__ int lbase[Cc];
  int t = threadIdx.x, g = blockIdx.y;
  const int* im = ei + (g ? 0 : Ee);
  const int* ci = g ? cit : cih;
  const float* es2g = es2 + (size_t)g * Ee;
  int* cug = ccur_p + g * Cc * 16;
  int* crg = crows + (size_t)g * Ee;
  float* cwg = cw + (size_t)g * Ee;
  int epb = (Ee + gridDim.x - 1) / gridDim.x;
  int e0 = blockIdx.x * epb, e1 = e0 + epb; if (e1 > Ee) e1 = Ee;
  for (int c = t; c < Cc; c += 256) lcnt[c] = 0;
  __syncthreads();
  int myr[4], myc[4], mye[4]; int cnt = 0;
  for (int e = e0 + t; e < e1; e += 256){
    int c = ci[e];
    myr[cnt] = atomicAdd(&lcnt[c], 1);
    myc[cnt] = c; mye[cnt] = e; cnt++;
  }
  __syncthreads();
  for (int c = t; c < Cc; c += 256)
    lbase[c] = lcnt[c] ? atomicAdd(&cug[c * 16], lcnt[c]) : 0;
  __syncthreads();
  for (int q = 0; q < cnt; q++){
    int pos = lbase[myc[q]] + myr[q];
    int e = mye[q];
    crg[pos] = im[im[e]];
    cwg[pos] = es2g[e];
  }
}

__global__ __launch_bounds__(192) void k_xclassBb(
    const int* __restrict__ cstart, const int* __restrict__ crows,
    const float* __restrict__ cw, const float* __restrict__ csum_p,
    const unsigned short* __restrict__ xnb, float* __restrict__ x_class){
  int g = blockIdx.y;
  int c = blockIdx.x / XSPL, sp = blockIdx.x % XSPL;
  int t = threadIdx.x;
  const int* csg = cstart + g * (Cc + 1);
  const int* crg = crows + (size_t)g * Ee;
  const float* cwg = cw + (size_t)g * Ee;
  const unsigned short* xng = xnb + (size_t)g * Nn * 152;
  float* xcg = x_class + g * Cc * CHd;
  int p0 = csg[c], p1 = csg[c + 1];
  int len = p1 - p0;
  if (len <= 0) return;
  int chunk = (len + XSPL - 1) / XSPL;
  int q0 = p0 + sp * chunk;
  int q1 = q0 + chunk; if (q1 > p1) q1 = p1;
  if (q0 >= q1) return;
  bool act = t < CHd;
  float inv = 1.f / csum_p[g * Cc * 16 + c * 16];
  float acc = 0.f;
  int k = q0;
  for (; k + 4 <= q1; k += 4){
    int r0 = crg[k], r1 = crg[k + 1], r2 = crg[k + 2], r3 = crg[k + 3];
    float w0 = cwg[k] * inv, w1 = cwg[k + 1] * inv, w2 = cwg[k + 2] * inv, w3 = cwg[k + 3] * inv;
    if (act){
      acc += w0 * b2f(xng[(size_t)r0 * 152 + t]) + w1 * b2f(xng[(size_t)r1 * 152 + t])
           + w2 * b2f(xng[(size_t)r2 * 152 + t]) + w3 * b2f(xng[(size_t)r3 * 152 + t]);
    }
  }
  for (; k < q1; k++){
    if (act) acc += cwg[k] * inv * b2f(xng[(size_t)crg[k] * 152 + t]);
  }
  if (act) atomicAdd(&xcg[c * CHd + t], acc);
}

// class-final step 1: one wave per (class, call): vv = lrelu(x_class[c].acv + nv4[ce[c]])
__global__ __launch_bounds__(64) void k_ecb(const float* __restrict__ x_class,
    const float* __restrict__ h2r_ac, const float* __restrict__ et_ac,
    const float* __restrict__ nv4,
    const int* __restrict__ hcls, const int* __restrict__ tcls,
    float* __restrict__ vv){
  int c = blockIdx.x, g = blockIdx.y, lane = threadIdx.x;
  const float* xc = x_class + (size_t)g * Cc * CHd + (size_t)c * CHd;
  const float* acv = (g ? et_ac : h2r_ac) + 7 * CHd;
  bool m2 = lane < (CHd - 128);
  float s[1];
  s[0] = xc[lane] * acv[lane] + xc[lane + 64] * acv[lane + 64]
       + (m2 ? xc[lane + 128] * acv[lane + 128] : 0.f);
  wredsumN<1>(s);
  if (!lane){
    int ce = (g ? tcls : hcls)[c];
    vv[g * Cc + c] = lrelu01(s[0] + nv4[g * Nn + ce]);
  }
}

// class-final step 2: per call g, segment softmax over cls_ent -> gmv
__global__ __launch_bounds__(256) void k_gammab(const float* __restrict__ vv,
    const int* __restrict__ hcls, const int* __restrict__ tcls,
    float* __restrict__ gmv){
  __shared__ float v[Cc];
  __shared__ int ce[Cc];
  int t = threadIdx.x, g = blockIdx.x;
  const int* cls_ent = g ? tcls : hcls;
  if (t < Cc){
    v[t] = vv[g * Cc + t];
    ce[t] = cls_ent[t];
  }
  __syncthreads();
  if (t < Cc){
    int sgm = ce[t];
    float m = -3.0e38f;
    for (int c2 = 0; c2 < Cc; c2++) if (ce[c2] == sgm) m = fmaxf(m, v[c2]);
    float sum = 0.f;
    for (int c2 = 0; c2 < Cc; c2++) if (ce[c2] == sgm) sum += expf(v[c2] - m);
    gmv[g * Cc + t] = expf(v[t] - m) / sum;
  }
}

// class-final step 3: parallel scatter outb[ce[c]] += gm[c] * x_class[c]
__global__ __launch_bounds__(256) void k_cfscatter(const float* __restrict__ x_class,
    const float* __restrict__ gmv,
    const int* __restrict__ hcls, const int* __restrict__ tcls,
    float* __restrict__ outb){
  int g = blockIdx.y;
  int idx = blockIdx.x * 256 + threadIdx.x;
  if (idx >= Cc * CHd) return;
  int c = idx / CHd, f = idx - c * CHd;
  int ce = (g ? tcls : hcls)[c];
  float val = gmv[g * Cc + c] * x_class[(size_t)g * Cc * CHd + idx];
  atomicAdd(&outb[(size_t)g * Nn * CHd + (size_t)ce * CHd + f], val);
}

// per node dot of x1b row with gat_ai / gat_aj — dword loads
__global__ __launch_bounds__(64) void k_s12(const unsigned short* __restrict__ x1b,
    const float* __restrict__ ai, const float* __restrict__ aj,
    float* __restrict__ s1, float* __restrict__ s2){
  int n = blockIdx.x, lane = threadIdx.x;
  const unsigned int* xr = (const unsigned int*)(x1b + (size_t)n * 600);
  float sa = 0.f, sb = 0.f;
#pragma unroll
  for (int u = 0; u < 5; u++){
    int d = lane + u * 64;
    if (d < 300){
      unsigned int w = xr[d];
      float xlo = b2f_lo(w), xhi = b2f_hi(w);
      sa += xlo * ai[2 * d] + xhi * ai[2 * d + 1];
      sb += xlo * aj[2 * d] + xhi * aj[2 * d + 1];
    }
  }
  float s[2] = { sa, sb };
  wredsumN<2>(s);
  if (!lane){ s1[n] = s[0]; s2[n] = s[1]; }
}

extern "C" void kernel_launch(void* const* d_in, const int* in_sizes, int n_in,
                              void* d_out, int out_size, void* d_ws, size_t ws_size,
                              hipStream_t stream) {
  const float* x_e    = (const float*)d_in[0];
  const int*   ei     = (const int*)d_in[1];
  const int*   rel    = (const int*)d_in[2];
  const int*   eall   = (const int*)d_in[3];
  const int*   cih    = (const int*)d_in[5];
  const int*   hcls   = (const int*)d_in[6];
  const int*   cit    = (const int*)d_in[7];
  const int*   tcls   = (const int*)d_in[8];
  const float* remb   = (const float*)d_in[9];
  const float* hw1w   = (const float*)d_in[10];
  const float* hw1b   = (const float*)d_in[11];
  const float* hw2w   = (const float*)d_in[12];
  const float* hw2b   = (const float*)d_in[13];
  const float* h2r_ac = (const float*)d_in[14];
  const float* h2r_ar = (const float*)d_in[15];
  const float* h2r_wh = (const float*)d_in[16];
  const float* h2r_wt = (const float*)d_in[17];
  const float* h2r_hww= (const float*)d_in[18];
  const float* h2r_hwb= (const float*)d_in[19];
  const float* et_ac  = (const float*)d_in[20];
  const float* et_ar  = (const float*)d_in[21];
  const float* et_wh  = (const float*)d_in[22];
  const float* et_wt  = (const float*)d_in[23];
  const float* et_hww = (const float*)d_in[24];
  const float* et_hwb = (const float*)d_in[25];
  const float* gai    = (const float*)d_in[26];
  const float* gaj    = (const float*)d_in[27];
  float* out = (float*)d_out;

  // ---- workspace allocator ----
  char* wsp = (char*)d_ws;
  auto alloc = [&](size_t nbytes) -> void* {
    void* p = (void*)wsp;
    wsp += (nbytes + 255) & ~(size_t)255;
    return p;
  };
  float* ra1h = (float*)alloc(Rr * 4);
  float* ra1e = (float*)alloc(Rr * 4);
  float* dis  = (float*)alloc(Nn * 4);
  int* degi    = (int*)alloc(Nn * 4);
  int* csr_ptr = (int*)alloc((Nn + 1) * 4);
  int* csr_cur = (int*)alloc(Nn * 4);
  int* csr_src = (int*)alloc((size_t)EALLe * 4);
  float* x1  = (float*)alloc((size_t)Nn * 600 * 4);
  float* es2 = (float*)alloc((size_t)2 * Ee * 4);
  float* pm  = (float*)alloc(2 * Nn * 4);
  float* po  = (float*)alloc(2 * Nn * 4);
  float* nv4 = (float*)alloc(2 * Nn * 4);
  float* csum_p = (float*)alloc(2 * Cc * 16 * 4);
  int*   ccnt_p = (int*)alloc(2 * Cc * 16 * 4);
  float* x_class = (float*)alloc(2 * Cc * CHd * 4);
  size_t zregion = (size_t)((char*)x_class + ((2 * Cc * CHd * 4 + 255) & ~255)) - (size_t)(char*)csum_p;
  int*   ccur_p = (int*)alloc(2 * Cc * 16 * 4);
  int*   cstart = (int*)alloc(2 * (Cc + 1) * 4);
  int*   crows  = (int*)alloc((size_t)2 * Ee * 4);
  float* cw     = (float*)alloc((size_t)2 * Ee * 4);
  float* s1v = (float*)alloc(Nn * 4);
  float* s2v = (float*)alloc(Nn * 4);
  float* vv  = (float*)alloc(2 * Cc * 4);
  float* gmv = (float*)alloc(2 * Cc * 4);
  unsigned short* arenaA = (unsigned short*)alloc((size_t)Nn * 320 * 2);
  unsigned short* arenaB = (unsigned short*)alloc((size_t)Nn * 320 * 2);
  unsigned short* x1b    = (unsigned short*)alloc(((size_t)Nn * 600 + 64) * 2);
  unsigned short* w1b    = (unsigned short*)alloc((size_t)300 * 320 * 2);
  unsigned short* w2b    = (unsigned short*)alloc((size_t)300 * 320 * 2);
  unsigned short* wcatb  = (unsigned short*)alloc((size_t)600 * 320 * 2);
  unsigned short* hwwbA  = (unsigned short*)alloc((size_t)150 * 160 * 2);
  unsigned short* hwwbB  = (unsigned short*)alloc((size_t)150 * 160 * 2);
  unsigned short* xob = arenaA;   // 2 x Nn x 160 bf16
  unsigned short* xnb = arenaB;   // 2 x Nn x 152 bf16

  // d_out staging layout (all dead before k_gat4 rewrites d_out)
  float* h1   = out;
  float* gbuf = out + (size_t)Nn * EHd;
  float* proj = out;
  float* outb = out + (size_t)Nn * 600;

  // ---- prologue ----
  hipMemsetAsync(degi, 0, Nn * 4, stream);
  hipMemsetAsync(csum_p, 0, zregion, stream);
  hipMemsetAsync(outb, 0, (size_t)2 * Nn * CHd * 4, stream);
  k_rnorm<<<Rr, 64, 0, stream>>>(remb, h2r_ar, et_ar, ra1h, ra1e);
  k_count<<<cdiv_h(EALLe, 256), 256, 0, stream>>>(eall + EALLe, degi);
  k_scan<<<1, 1024, 0, stream>>>(degi, csr_ptr, csr_cur, dis);
  k_scatter<<<cdiv_h(EALLe, 256), 256, 0, stream>>>(eall, eall + EALLe, csr_cur, csr_src);
  {
    Cvt8 cv;
    cv.s[0] = hw1w;    cv.d[0] = w1b;                         cv.nc[0] = 300; cv.lds[0] = 300; cv.ldp[0] = 320;
    cv.s[1] = hw2w;    cv.d[1] = w2b;                         cv.nc[1] = 300; cv.lds[1] = 300; cv.ldp[1] = 320;
    cv.s[2] = h2r_wh;  cv.d[2] = wcatb + (size_t)0   * 320;   cv.nc[2] = 300; cv.lds[2] = 300; cv.ldp[2] = 320;
    cv.s[3] = h2r_wt;  cv.d[3] = wcatb + (size_t)150 * 320;   cv.nc[3] = 300; cv.lds[3] = 300; cv.ldp[3] = 320;
    cv.s[4] = et_wh;   cv.d[4] = wcatb + (size_t)300 * 320;   cv.nc[4] = 300; cv.lds[4] = 300; cv.ldp[4] = 320;
    cv.s[5] = et_wt;   cv.d[5] = wcatb + (size_t)450 * 320;   cv.nc[5] = 300; cv.lds[5] = 300; cv.ldp[5] = 320;
    cv.s[6] = h2r_hww; cv.d[6] = hwwbA;                       cv.nc[6] = 150; cv.lds[6] = 150; cv.ldp[6] = 160;
    cv.s[7] = et_hww;  cv.d[7] = hwwbB;                       cv.nc[7] = 150; cv.lds[7] = 150; cv.ldp[7] = 160;
    cv.r0[0] = 0;    cv.r0[1] = 300;  cv.r0[2] = 600;  cv.r0[3] = 750;
    cv.r0[4] = 900;  cv.r0[5] = 1050; cv.r0[6] = 1200; cv.r0[7] = 1350; cv.r0[8] = 1500;
    k_f2ball<<<1500, 64, 0, stream>>>(cv);
  }
  k_f2b<<<Nn, 64, 0, stream>>>(x_e, 300, 300, arenaA, 320);

  // ---- GCN + highway x2 ----
  k_gcn4<<<Nn, 256, 0, stream>>>(arenaA, csr_ptr, csr_src, dis, gbuf);
  k_gemmb<1,1><<<dim3(5, cdiv_h(Nn, 64)), 256, 0, stream>>>(
      arenaA, 320, Nn, w1b, 320, 300, hw1b, gbuf, 300, x_e, 300, h1, 300, arenaB, 320);
  k_gcn4<<<Nn, 256, 0, stream>>>(arenaB, csr_ptr, csr_src, dis, gbuf);
  k_gemmb<1,1><<<dim3(5, cdiv_h(Nn, 64)), 256, 0, stream>>>(
      arenaB, 320, Nn, w2b, 320, 300, hw2b, gbuf, 300, h1, 300, x1, 600, x1b, 600);

  // ---- batched projections ----
  k_gemmb<0,0><<<dim3(10, cdiv_h(Nn, 64)), 256, 0, stream>>>(
      x1b, 600, Nn, wcatb, 320, 600, nullptr, nullptr, 0, nullptr, 0, proj, 600,
      nullptr, 0);

  // ---- gat_e: both calls batched per kernel ----
  k_ndots2b<<<dim3(Nn, 2), 64, 0, stream>>>(proj, h2r_ac, et_ac, xob, xnb, pm, po, nv4);
  k_e2sumb<<<dim3(CB, 2), 256, 0, stream>>>(ei, rel, cih, cit, pm, po, ra1h, ra1e,
                                            es2, csum_p, ccnt_p);
  k_cscanb<<<2, 256, 0, stream>>>(ccnt_p, cstart, ccur_p);
  k_cscatterb<<<dim3(CB, 2), 256, 0, stream>>>(ei, cih, cit, es2, ccur_p, crows, cw);
  k_xclassBb<<<dim3(Cc * XSPL, 2), 192, 0, stream>>>(cstart, crows, cw, csum_p,
                                                     xnb, x_class);
  // class-final: parallel 3-stage (wave-dot -> segment softmax -> scatter)
  k_ecb<<<dim3(Cc, 2), 64, 0, stream>>>(x_class, h2r_ac, et_ac, nv4, hcls, tcls, vv);
  k_gammab<<<2, 256, 0, stream>>>(vv, hcls, tcls, gmv);
  k_cfscatter<<<dim3(cdiv_h(Cc * CHd, 256), 2), 256, 0, stream>>>(
      x_class, gmv, hcls, tcls, outb);
  k_hwgemm<<<dim3(3, cdiv_h(Nn, 64), 2), 256, 0, stream>>>(
      xob, hwwbA, hwwbB, h2r_hwb, et_hwb, outb, proj, x1, x1b);

  // ---- final GAT ----
  k_s12<<<Nn, 64, 0, stream>>>(x1b, gai, gaj, s1v, s2v);
  k_gat4<<<Nn, 256, 0, stream>>>(x1, x1b, csr_ptr, csr_src, s1v, s2v, out);
}